// Round 1
// baseline (2398.448 us; speedup 1.0000x reference)
//
#include <hip/hip_runtime.h>
#include <math.h>

// ---------------------------------------------------------------------------
// RFDN panet attention block, MI355X.
// Decomposition: per batch b:
//   S[p,l]   = Q[p,:] . KT[:,l]        (Q: 2304x240, KT: 240x7488)  GEMM1
//   A[p,l]   = softmax_l(S[p,l])       (SM_SCALE and 1/norm folded into KT)
//   Z[p,j]   = A[p,:] . V[:,j]         (V: 7488x512, j = c*9+ky*3+kx) GEMM2 (split-K)
//   out[c,p] = x + 0.25 * sum_{ky,kx} Z[p_neighbor, c*9 + (2-ky)*3 + (2-kx)]
// ---------------------------------------------------------------------------

#define L_TOT 7470
#define L_PAD 7488
#define KD    240   // padded 225 = 25*3*3
#define JD    512   // padded 450 = 50*3*3
#define HW    2304  // 48*48
#define NSPLIT 4

__constant__ int c_hs[5]     = {48, 43, 38, 33, 28};
__constant__ int c_loff[6]   = {0, 2304, 4153, 5597, 6686, 7470};

__device__ inline void decode_l(int l, int& si, int& hs, int& pos) {
    si = 0;
#pragma unroll
    for (int s = 0; s < 4; ++s)
        if (l >= c_loff[s + 1]) si = s + 1;
    pos = l - c_loff[si];
    hs = c_hs[si];
}

// --------------------------- bicubic resize weights ------------------------
// jax.image.resize(method='cubic', antialias=True): Keys kernel a=-0.5,
// kernel_scale = in/out (downsample), weights normalized per output sample.
__global__ void resize_weights_kernel(float* __restrict__ wmall) {
    int r = blockIdx.x * blockDim.x + threadIdx.x;
    if (r >= 142) return;  // 43+38+33+28 output rows
    int sizes[4] = {43, 38, 33, 28};
    int si = 0, i = r, woffs = 0;
    for (si = 0; si < 4; ++si) {
        if (i < sizes[si]) break;
        i -= sizes[si];
        woffs += sizes[si] * 48;
    }
    int osz = sizes[si];
    float inv_scale = 48.0f / (float)osz;       // 1/scale, scale = out/in
    float kscale = inv_scale;                   // antialias, inv_scale > 1
    float sample_f = ((float)i + 0.5f) * inv_scale - 0.5f;
    float w[48];
    float tot = 0.f;
    for (int j = 0; j < 48; ++j) {
        float t = fabsf(sample_f - (float)j) / kscale;
        float v;
        if (t >= 2.f)       v = 0.f;
        else if (t >= 1.f)  v = ((-0.5f * t + 2.5f) * t - 4.f) * t + 2.f;
        else                v = ((1.5f * t - 2.5f) * t) * t + 1.f;
        w[j] = v;
        tot += v;
    }
    float invt = 1.f / tot;
    for (int j = 0; j < 48; ++j) wmall[woffs + i * 48 + j] = w[j] * invt;
}

// separable resize: H pass then W pass. bc in [0, 200) = b*50 + c
__global__ void resize_h(const float* __restrict__ in, const float* __restrict__ wm,
                         float* __restrict__ tmp, int osz) {
    int idx = blockIdx.x * 256 + threadIdx.x;
    int total = 200 * osz * 48;
    if (idx >= total) return;
    int xi = idx % 48;
    int t = idx / 48;
    int yo = t % osz;
    int bc = t / osz;
    const float* wr = wm + yo * 48;
    const float* ip = in + (size_t)bc * 2304 + xi;
    float s = 0.f;
#pragma unroll
    for (int yi = 0; yi < 48; ++yi) s += wr[yi] * ip[yi * 48];
    tmp[idx] = s;
}

__global__ void resize_w(const float* __restrict__ tmp, const float* __restrict__ wm,
                         float* __restrict__ refout, int osz) {
    int idx = blockIdx.x * 256 + threadIdx.x;
    int total = 200 * osz * osz;
    if (idx >= total) return;
    int xo = idx % osz;
    int t = idx / osz;
    int yo = t % osz;
    int bc = t / osz;
    const float* wr = wm + xo * 48;
    const float* ip = tmp + ((size_t)bc * osz + yo) * 48;
    float s = 0.f;
#pragma unroll
    for (int xi = 0; xi < 48; ++xi) s += wr[xi] * ip[xi];
    refout[idx] = s;
}

// --------------------------- 1x1 conv + PReLU ------------------------------
// in: [(b*50+ci)*P + p], out: [(b*Co+co)*P + p]
__global__ void conv1x1_prelu(const float* __restrict__ in, const float* __restrict__ w,
                              const float* __restrict__ bias, const float* __restrict__ a,
                              float* __restrict__ outp, int P, int Co) {
    int idx = blockIdx.x * 256 + threadIdx.x;
    int total = 4 * Co * P;
    if (idx >= total) return;
    int p = idx % P;
    int t = idx / P;
    int co = t % Co;
    int b = t / Co;
    const float* ip = in + (size_t)b * 50 * P + p;
    const float* wr = w + co * 50;
    float s = bias[co];
#pragma unroll
    for (int ci = 0; ci < 50; ++ci) s += wr[ci] * ip[(size_t)ci * P];
    float av = a[0];
    outp[idx] = (s >= 0.f) ? s : av * s;
}

// --------------------------- Q / K / V builders ----------------------------
__global__ void q_build(const float* __restrict__ mb, float* __restrict__ Q, int b) {
    int idx = blockIdx.x * 256 + threadIdx.x;
    if (idx >= HW * KD) return;
    int k = idx % KD;
    int p = idx / KD;
    float v = 0.f;
    if (k < 225) {
        int c = k / 9, r = k % 9, ky = r / 3, kx = r % 3;
        int y = p / 48, xx = p % 48;
        int yy = y + ky - 1, xv = xx + kx - 1;
        if (yy >= 0 && yy < 48 && xv >= 0 && xv < 48)
            v = mb[((size_t)(b * 25 + c)) * HW + yy * 48 + xv];
    }
    Q[idx] = v;
}

__global__ void norms_kernel(const float* __restrict__ refm_all, float* __restrict__ norms, int b) {
    int l = blockIdx.x * 256 + threadIdx.x;
    if (l >= L_TOT) return;
    int si, hs, pos;
    decode_l(l, si, hs, pos);
    int P = hs * hs;
    int ly = pos / hs, lx = pos % hs;
    const float* rb = refm_all + (size_t)100 * c_loff[si] + (size_t)(b * 25) * P;
    float ss = 0.f;
    for (int c = 0; c < 25; ++c) {
        const float* rc = rb + (size_t)c * P;
#pragma unroll
        for (int ky = 0; ky < 3; ++ky) {
#pragma unroll
            for (int kx = 0; kx < 3; ++kx) {
                int yy = ly + ky - 1, xv = lx + kx - 1;
                if (yy >= 0 && yy < hs && xv >= 0 && xv < hs) {
                    float v = rc[yy * hs + xv];
                    ss += v * v;
                }
            }
        }
    }
    norms[l] = 10.0f / fmaxf(sqrtf(ss), 1e-4f);  // SM_SCALE folded in
}

__global__ void kt_build(const float* __restrict__ refm_all, const float* __restrict__ norms,
                         float* __restrict__ KT, int b) {
    int idx = blockIdx.x * 256 + threadIdx.x;
    if (idx >= KD * L_PAD) return;
    int l = idx % L_PAD;
    int k = idx / L_PAD;
    float v = 0.f;
    if (k < 225 && l < L_TOT) {
        int si, hs, pos;
        decode_l(l, si, hs, pos);
        int P = hs * hs;
        int ly = pos / hs, lx = pos % hs;
        int c = k / 9, r = k % 9, ky = r / 3, kx = r % 3;
        int yy = ly + ky - 1, xv = lx + kx - 1;
        if (yy >= 0 && yy < hs && xv >= 0 && xv < hs)
            v = refm_all[(size_t)100 * c_loff[si] + ((size_t)(b * 25 + c)) * P + yy * hs + xv] * norms[l];
    }
    KT[idx] = v;
}

__global__ void v_build(const float* __restrict__ base_all, float* __restrict__ V, int b) {
    int idx = blockIdx.x * 256 + threadIdx.x;
    if (idx >= L_PAD * JD) return;
    int j = idx % JD;
    int l = idx / JD;
    float v = 0.f;
    if (j < 450 && l < L_TOT) {
        int si, hs, pos;
        decode_l(l, si, hs, pos);
        int P = hs * hs;
        int ly = pos / hs, lx = pos % hs;
        int c = j / 9, r = j % 9, ky = r / 3, kx = r % 3;
        int yy = ly + ky - 1, xv = lx + kx - 1;
        if (yy >= 0 && yy < hs && xv >= 0 && xv < hs)
            v = base_all[(size_t)200 * c_loff[si] + ((size_t)(b * 50 + c)) * P + yy * hs + xv];
    }
    V[idx] = v;
}

// --------------------------- tiled fp32 GEMM -------------------------------
// C[M x N] = A[M x K] * B[K x N], row-major, all tile dims exact multiples.
// grid: (N/64, M/64, nsplit). Each z handles ksplit of K, writes C + z*c_zstride.
__global__ __launch_bounds__(256) void gemm_kernel(
    const float* __restrict__ A, const float* __restrict__ B, float* __restrict__ C,
    int lda, int ldb, int ldc, int ksplit, int c_zstride) {
    __shared__ float As[16][64];
    __shared__ float Bs[16][64];
    const int tid = threadIdx.x;
    const int bn = blockIdx.x * 64;
    const int bm = blockIdx.y * 64;
    const int kz0 = blockIdx.z * ksplit;
    C += (size_t)blockIdx.z * c_zstride;
    const int tx = tid & 15, ty = tid >> 4;
    const int ar = tid >> 2;           // A tile row 0..63
    const int ac = (tid & 3) * 4;      // A tile col group
    const int brow = tid >> 4;         // B tile row 0..15
    const int bcol = (tid & 15) * 4;   // B tile col group
    float acc[4][4] = {};
    for (int kk = 0; kk < ksplit; kk += 16) {
        const int kbase = kz0 + kk;
        float4 av = *(const float4*)(A + (size_t)(bm + ar) * lda + kbase + ac);
        float4 bv = *(const float4*)(B + (size_t)(kbase + brow) * ldb + bn + bcol);
        __syncthreads();
        As[ac + 0][ar] = av.x;
        As[ac + 1][ar] = av.y;
        As[ac + 2][ar] = av.z;
        As[ac + 3][ar] = av.w;
        *(float4*)&Bs[brow][bcol] = bv;
        __syncthreads();
#pragma unroll
        for (int k2 = 0; k2 < 16; ++k2) {
            float a[4], bb[4];
#pragma unroll
            for (int i = 0; i < 4; ++i) a[i] = As[k2][ty * 4 + i];
#pragma unroll
            for (int j = 0; j < 4; ++j) bb[j] = Bs[k2][tx * 4 + j];
#pragma unroll
            for (int i = 0; i < 4; ++i)
#pragma unroll
                for (int j = 0; j < 4; ++j) acc[i][j] += a[i] * bb[j];
        }
    }
#pragma unroll
    for (int i = 0; i < 4; ++i) {
        float4 v = make_float4(acc[i][0], acc[i][1], acc[i][2], acc[i][3]);
        *(float4*)(C + (size_t)(bm + ty * 4 + i) * ldc + bn + tx * 4) = v;
    }
}

// --------------------------- row softmax -----------------------------------
__global__ __launch_bounds__(256) void softmax_rows(float* __restrict__ S) {
    __shared__ float red[256];
    const int p = blockIdx.x;
    float* row = S + (size_t)p * L_PAD;
    const int tid = threadIdx.x;
    float m = -1e30f;
    for (int l = tid; l < L_TOT; l += 256) m = fmaxf(m, row[l]);
    red[tid] = m;
    __syncthreads();
    for (int s = 128; s > 0; s >>= 1) {
        if (tid < s) red[tid] = fmaxf(red[tid], red[tid + s]);
        __syncthreads();
    }
    m = red[0];
    __syncthreads();
    float sum = 0.f;
    for (int l = tid; l < L_TOT; l += 256) {
        float e = __expf(row[l] - m);
        row[l] = e;
        sum += e;
    }
    red[tid] = sum;
    __syncthreads();
    for (int s = 128; s > 0; s >>= 1) {
        if (tid < s) red[tid] += red[tid + s];
        __syncthreads();
    }
    float inv = 1.0f / red[0];
    for (int l = tid; l < L_TOT; l += 256) row[l] *= inv;
    for (int l = L_TOT + tid; l < L_PAD; l += 256) row[l] = 0.f;
}

// --------------------------- final gather + residual -----------------------
__global__ void final_kernel(const float* __restrict__ Zpart, const float* __restrict__ x,
                             float* __restrict__ out, int b) {
    int idx = blockIdx.x * 256 + threadIdx.x;
    if (idx >= 50 * HW) return;
    int c = idx / HW, p = idx % HW;
    int y = p / 48, xx = p % 48;
    float s = 0.f;
#pragma unroll
    for (int ky = 0; ky < 3; ++ky) {
#pragma unroll
        for (int kx = 0; kx < 3; ++kx) {
            int yy = y + ky - 1, xv = xx + kx - 1;
            if (yy < 0 || yy >= 48 || xv < 0 || xv >= 48) continue;
            int pp = yy * 48 + xv;
            int j = c * 9 + (2 - ky) * 3 + (2 - kx);
#pragma unroll
            for (int z = 0; z < NSPLIT; ++z)
                s += Zpart[((size_t)z * HW + pp) * JD + j];
        }
    }
    size_t o = ((size_t)b * 50 + c) * HW + p;
    out[o] = x[o] + 0.25f * s;
}

// ---------------------------------------------------------------------------
extern "C" void kernel_launch(void* const* d_in, const int* in_sizes, int n_in,
                              void* d_out, int out_size, void* d_ws, size_t ws_size,
                              hipStream_t stream) {
    const float* x       = (const float*)d_in[0];
    const float* w_base  = (const float*)d_in[1];
    const float* b_base  = (const float*)d_in[2];
    const float* a_base  = (const float*)d_in[3];
    const float* w_match = (const float*)d_in[4];
    const float* b_match = (const float*)d_in[5];
    const float* a_match = (const float*)d_in[6];
    const float* w_asm   = (const float*)d_in[7];
    const float* b_asm   = (const float*)d_in[8];
    const float* a_asm   = (const float*)d_in[9];
    float* out = (float*)d_out;
    float* ws = (float*)d_ws;

    const int hs[5] = {48, 43, 38, 33, 28};
    const int loff[6] = {0, 2304, 4153, 5597, 6686, 7470};

    size_t off = 0;
    auto alloc = [&](size_t n) { size_t o = off; off += (n + 63) & ~(size_t)63; return o; };
    size_t o_wm = alloc(142 * 48);
    size_t o_rtmp = alloc((size_t)200 * 43 * 48);
    size_t o_ref[5];
    o_ref[0] = 0;
    for (int si = 1; si < 5; ++si) o_ref[si] = alloc((size_t)200 * hs[si] * hs[si]);
    size_t o_base = alloc((size_t)200 * L_TOT);
    size_t o_refm = alloc((size_t)100 * L_TOT);
    size_t o_mb = alloc((size_t)100 * HW);
    size_t o_norms = alloc(L_TOT);
    size_t o_Q = alloc((size_t)HW * KD);
    size_t o_KT = alloc((size_t)KD * L_PAD);
    size_t o_V = alloc((size_t)L_PAD * JD);
    size_t o_S = alloc((size_t)HW * L_PAD);
    size_t o_Z = alloc((size_t)NSPLIT * HW * JD);
    (void)ws_size; (void)in_sizes; (void)n_in; (void)out_size;

    // resize weights + per-scale resized inputs
    resize_weights_kernel<<<1, 256, 0, stream>>>(ws + o_wm);
    const int woff[5] = {0, 0, 43 * 48, (43 + 38) * 48, (43 + 38 + 33) * 48};
    for (int si = 1; si < 5; ++si) {
        int osz = hs[si];
        int n1 = 200 * osz * 48;
        resize_h<<<(n1 + 255) / 256, 256, 0, stream>>>(x, ws + o_wm + woff[si], ws + o_rtmp, osz);
        int n2 = 200 * osz * osz;
        resize_w<<<(n2 + 255) / 256, 256, 0, stream>>>(ws + o_rtmp, ws + o_wm + woff[si],
                                                       ws + o_ref[si], osz);
    }
    // per-scale convs (assembly 50ch, match 25ch)
    for (int si = 0; si < 5; ++si) {
        int P = hs[si] * hs[si];
        const float* in = (si == 0) ? x : ws + o_ref[si];
        int nb = 4 * 50 * P;
        conv1x1_prelu<<<(nb + 255) / 256, 256, 0, stream>>>(
            in, w_asm, b_asm, a_asm, ws + o_base + (size_t)200 * loff[si], P, 50);
        int nm = 4 * 25 * P;
        conv1x1_prelu<<<(nm + 255) / 256, 256, 0, stream>>>(
            in, w_match, b_match, a_match, ws + o_refm + (size_t)100 * loff[si], P, 25);
    }
    // match_base on full-res x
    {
        int nmb = 4 * 25 * HW;
        conv1x1_prelu<<<(nmb + 255) / 256, 256, 0, stream>>>(x, w_base, b_base, a_base,
                                                             ws + o_mb, HW, 25);
    }

    for (int b = 0; b < 4; ++b) {
        q_build<<<(HW * KD + 255) / 256, 256, 0, stream>>>(ws + o_mb, ws + o_Q, b);
        norms_kernel<<<(L_TOT + 255) / 256, 256, 0, stream>>>(ws + o_refm, ws + o_norms, b);
        kt_build<<<(KD * L_PAD + 255) / 256, 256, 0, stream>>>(ws + o_refm, ws + o_norms,
                                                               ws + o_KT, b);
        v_build<<<(L_PAD * JD + 255) / 256, 256, 0, stream>>>(ws + o_base, ws + o_V, b);

        dim3 g1(L_PAD / 64, HW / 64, 1);
        gemm_kernel<<<g1, 256, 0, stream>>>(ws + o_Q, ws + o_KT, ws + o_S, KD, L_PAD, L_PAD,
                                            KD, 0);
        softmax_rows<<<HW, 256, 0, stream>>>(ws + o_S);
        dim3 g2(JD / 64, HW / 64, NSPLIT);
        gemm_kernel<<<g2, 256, 0, stream>>>(ws + o_S, ws + o_V, ws + o_Z, L_PAD, JD, JD,
                                            L_PAD / NSPLIT, HW * JD);
        final_kernel<<<(50 * HW + 255) / 256, 256, 0, stream>>>(ws + o_Z, x, out, b);
    }
}

// Round 2
// 883.572 us; speedup vs baseline: 2.7145x; 2.7145x over previous
//
#include <hip/hip_runtime.h>
#include <hip/hip_bf16.h>
#include <math.h>

// ---------------------------------------------------------------------------
// RFDN panet attention, MI355X.  Round 2: bf16 MFMA GEMMs (C = A * B^T form).
//   GEMM1: S[2304 x 7552] = Q[2304 x 256] . K[7552 x 256]^T   (per batch)
//   softmax rows -> A_attn bf16 (all batches)
//   GEMM2: Z[2304 x 512]  = A_attn[2304 x 7552] . VT[512 x 7552]^T
//          (batched over z = batch*2 + ksplit)
// ---------------------------------------------------------------------------

#define L_TOT 7470
#define L_PAD 7552   // 128 * 59
#define KD    256    // padded 225
#define JD    512    // padded 450 = 50*3*3
#define HW    2304   // 48*48
#define NS2   2      // split-K for GEMM2

typedef unsigned short u16;
typedef __attribute__((ext_vector_type(8))) short bf16x8;
typedef __attribute__((ext_vector_type(4))) float f32x4;

__device__ inline u16 f2b(float f) {
    __hip_bfloat16 h = __float2bfloat16(f);
    return __builtin_bit_cast(u16, h);
}

__constant__ int c_hs[5]   = {48, 43, 38, 33, 28};
__constant__ int c_loff[6] = {0, 2304, 4153, 5597, 6686, 7470};

__device__ inline void decode_l(int l, int& si, int& hs, int& pos) {
    si = 0;
#pragma unroll
    for (int s = 0; s < 4; ++s)
        if (l >= c_loff[s + 1]) si = s + 1;
    pos = l - c_loff[si];
    hs = c_hs[si];
}

// --------------------------- bicubic resize --------------------------------
__global__ void resize_weights_kernel(float* __restrict__ wmall) {
    int r = blockIdx.x * blockDim.x + threadIdx.x;
    if (r >= 142) return;
    int sizes[4] = {43, 38, 33, 28};
    int si = 0, i = r, woffs = 0;
    for (si = 0; si < 4; ++si) {
        if (i < sizes[si]) break;
        i -= sizes[si];
        woffs += sizes[si] * 48;
    }
    int osz = sizes[si];
    float inv_scale = 48.0f / (float)osz;
    float kscale = inv_scale;
    float sample_f = ((float)i + 0.5f) * inv_scale - 0.5f;
    float w[48];
    float tot = 0.f;
    for (int j = 0; j < 48; ++j) {
        float t = fabsf(sample_f - (float)j) / kscale;
        float v;
        if (t >= 2.f)       v = 0.f;
        else if (t >= 1.f)  v = ((-0.5f * t + 2.5f) * t - 4.f) * t + 2.f;
        else                v = ((1.5f * t - 2.5f) * t) * t + 1.f;
        w[j] = v;
        tot += v;
    }
    float invt = 1.f / tot;
    for (int j = 0; j < 48; ++j) wmall[woffs + i * 48 + j] = w[j] * invt;
}

__global__ void resize_h(const float* __restrict__ in, const float* __restrict__ wm,
                         float* __restrict__ tmp, int osz) {
    int idx = blockIdx.x * 256 + threadIdx.x;
    int total = 200 * osz * 48;
    if (idx >= total) return;
    int xi = idx % 48;
    int t = idx / 48;
    int yo = t % osz;
    int bc = t / osz;
    const float* wr = wm + yo * 48;
    const float* ip = in + (size_t)bc * 2304 + xi;
    float s = 0.f;
#pragma unroll
    for (int yi = 0; yi < 48; ++yi) s += wr[yi] * ip[yi * 48];
    tmp[idx] = s;
}

__global__ void resize_w(const float* __restrict__ tmp, const float* __restrict__ wm,
                         float* __restrict__ refout, int osz) {
    int idx = blockIdx.x * 256 + threadIdx.x;
    int total = 200 * osz * osz;
    if (idx >= total) return;
    int xo = idx % osz;
    int t = idx / osz;
    int yo = t % osz;
    int bc = t / osz;
    const float* wr = wm + xo * 48;
    const float* ip = tmp + ((size_t)bc * osz + yo) * 48;
    float s = 0.f;
#pragma unroll
    for (int xi = 0; xi < 48; ++xi) s += wr[xi] * ip[xi];
    refout[idx] = s;
}

// --------------------------- 1x1 conv + PReLU ------------------------------
__global__ void conv1x1_prelu(const float* __restrict__ in, const float* __restrict__ w,
                              const float* __restrict__ bias, const float* __restrict__ a,
                              float* __restrict__ outp, int P, int Co) {
    int idx = blockIdx.x * 256 + threadIdx.x;
    int total = 4 * Co * P;
    if (idx >= total) return;
    int p = idx % P;
    int t = idx / P;
    int co = t % Co;
    int b = t / Co;
    const float* ip = in + (size_t)b * 50 * P + p;
    const float* wr = w + co * 50;
    float s = bias[co];
#pragma unroll
    for (int ci = 0; ci < 50; ++ci) s += wr[ci] * ip[(size_t)ci * P];
    float av = a[0];
    outp[idx] = (s >= 0.f) ? s : av * s;
}

// --------------------------- builders (bf16) -------------------------------
// Q[(b*HW + p)*KD + k]
__global__ void q_build(const float* __restrict__ mb, u16* __restrict__ Q) {
    int idx = blockIdx.x * 256 + threadIdx.x;
    if (idx >= 4 * HW * KD) return;
    int k = idx % KD;
    int t = idx / KD;
    int p = t % HW;
    int b = t / HW;
    float v = 0.f;
    if (k < 225) {
        int c = k / 9, r = k % 9, ky = r / 3, kx = r % 3;
        int y = p / 48, xx = p % 48;
        int yy = y + ky - 1, xv = xx + kx - 1;
        if (yy >= 0 && yy < 48 && xv >= 0 && xv < 48)
            v = mb[((size_t)(b * 25 + c)) * HW + yy * 48 + xv];
    }
    Q[idx] = f2b(v);
}

__global__ void norms_kernel(const float* __restrict__ refm_all, float* __restrict__ norms) {
    int idx = blockIdx.x * 256 + threadIdx.x;
    if (idx >= 4 * L_TOT) return;
    int l = idx % L_TOT;
    int b = idx / L_TOT;
    int si, hs, pos;
    decode_l(l, si, hs, pos);
    int P = hs * hs;
    int ly = pos / hs, lx = pos % hs;
    const float* rb = refm_all + (size_t)100 * c_loff[si] + (size_t)(b * 25) * P;
    float ss = 0.f;
    for (int c = 0; c < 25; ++c) {
        const float* rc = rb + (size_t)c * P;
#pragma unroll
        for (int ky = 0; ky < 3; ++ky) {
#pragma unroll
            for (int kx = 0; kx < 3; ++kx) {
                int yy = ly + ky - 1, xv = lx + kx - 1;
                if (yy >= 0 && yy < hs && xv >= 0 && xv < hs) {
                    float v = rc[yy * hs + xv];
                    ss += v * v;
                }
            }
        }
    }
    norms[idx] = 10.0f / fmaxf(sqrtf(ss), 1e-4f);  // SM_SCALE folded
}

// K[(b*L_PAD + l)*KD + k]  (K-major per key l)
__global__ void kt_build(const float* __restrict__ refm_all, const float* __restrict__ norms,
                         u16* __restrict__ K) {
    int idx = blockIdx.x * 256 + threadIdx.x;
    if (idx >= 4 * L_PAD * KD) return;
    int k = idx % KD;
    int t = idx / KD;
    int l = t % L_PAD;
    int b = t / L_PAD;
    float v = 0.f;
    if (k < 225 && l < L_TOT) {
        int si, hs, pos;
        decode_l(l, si, hs, pos);
        int P = hs * hs;
        int ly = pos / hs, lx = pos % hs;
        int c = k / 9, r = k % 9, ky = r / 3, kx = r % 3;
        int yy = ly + ky - 1, xv = lx + kx - 1;
        if (yy >= 0 && yy < hs && xv >= 0 && xv < hs)
            v = refm_all[(size_t)100 * c_loff[si] + ((size_t)(b * 25 + c)) * P + yy * hs + xv]
                * norms[(size_t)b * L_TOT + l];
    }
    K[idx] = f2b(v);
}

// VT[(b*JD + j)*L_PAD + l]  (V transposed: key l contiguous)
__global__ void v_build(const float* __restrict__ base_all, u16* __restrict__ VT) {
    int idx = blockIdx.x * 256 + threadIdx.x;
    if (idx >= 4 * JD * L_PAD) return;
    int l = idx % L_PAD;
    int t = idx / L_PAD;
    int j = t % JD;
    int b = t / JD;
    float v = 0.f;
    if (j < 450 && l < L_TOT) {
        int si, hs, pos;
        decode_l(l, si, hs, pos);
        int P = hs * hs;
        int ly = pos / hs, lx = pos % hs;
        int c = j / 9, r = j % 9, ky = r / 3, kx = r % 3;
        int yy = ly + ky - 1, xv = lx + kx - 1;
        if (yy >= 0 && yy < hs && xv >= 0 && xv < hs)
            v = base_all[(size_t)200 * c_loff[si] + ((size_t)(b * 50 + c)) * P + yy * hs + xv];
    }
    VT[idx] = f2b(v);
}

// --------------------------- bf16 MFMA GEMM, C = A * B^T -------------------
// A: [M x ld] bf16 row-major, B: [N x ld] bf16 row-major, C: [M x ldc] fp32.
// 128x128 tile, BK=64, 4 waves; blockIdx.z = batch*nsplit + split.
#define GLOAD16(g, l) __builtin_amdgcn_global_load_lds(                          \
        (__attribute__((address_space(1))) const void*)(g),                      \
        (__attribute__((address_space(3))) void*)(l), 16, 0, 0)

__global__ __launch_bounds__(256) void gemm_bt(
    const u16* __restrict__ A, const u16* __restrict__ B, float* __restrict__ C,
    int ld, int ksteps, int nsplit, long aBatch, long bBatch, long cZ, int ldc) {
    __shared__ u16 As[128 * 64];
    __shared__ u16 Bs[128 * 64];
    const int z = blockIdx.z, batch = z / nsplit, split = z % nsplit;
    A += (long)batch * aBatch + (long)split * ksteps * 64;
    B += (long)batch * bBatch + (long)split * ksteps * 64;
    C += (long)z * cZ;
    const int bm = blockIdx.y * 128, bn = blockIdx.x * 128;
    const int tid = threadIdx.x, lane = tid & 63, wid = tid >> 6;
    const int wr = wid >> 1, wc = wid & 1;
    const int srow = lane >> 3;          // 0..7 within 8-row chunk
    const int scol = (lane & 7) * 8;     // element col within BK

    f32x4 acc[4][4];
#pragma unroll
    for (int i = 0; i < 4; ++i)
#pragma unroll
        for (int j = 0; j < 4; ++j) acc[i][j] = (f32x4){0.f, 0.f, 0.f, 0.f};

    const u16* aG = A + (size_t)(bm + wid * 32 + srow) * ld + scol;
    const u16* bG = B + (size_t)(bn + wid * 32 + srow) * ld + scol;
    u16* aL = As + wid * 32 * 64;
    u16* bL = Bs + wid * 32 * 64;

    for (int t = 0; t < ksteps; ++t) {
#pragma unroll
        for (int q = 0; q < 4; ++q) {
            GLOAD16(aG + (size_t)q * 8 * ld, aL + q * 8 * 64);
            GLOAD16(bG + (size_t)q * 8 * ld, bL + q * 8 * 64);
        }
        aG += 64;
        bG += 64;
        __syncthreads();
#pragma unroll
        for (int kc = 0; kc < 64; kc += 32) {
            bf16x8 af[4], bf[4];
#pragma unroll
            for (int m = 0; m < 4; ++m)
                af[m] = *(const bf16x8*)&As[(wr * 64 + m * 16 + (lane & 15)) * 64 + kc + (lane >> 4) * 8];
#pragma unroll
            for (int n = 0; n < 4; ++n)
                bf[n] = *(const bf16x8*)&Bs[(wc * 64 + n * 16 + (lane & 15)) * 64 + kc + (lane >> 4) * 8];
#pragma unroll
            for (int m = 0; m < 4; ++m)
#pragma unroll
                for (int n = 0; n < 4; ++n)
                    acc[m][n] = __builtin_amdgcn_mfma_f32_16x16x32_bf16(af[m], bf[n], acc[m][n], 0, 0, 0);
        }
        __syncthreads();
    }
    const int crow0 = bm + wr * 64 + (lane >> 4) * 4;
    const int ccol = bn + wc * 64 + (lane & 15);
#pragma unroll
    for (int m = 0; m < 4; ++m)
#pragma unroll
        for (int n = 0; n < 4; ++n)
#pragma unroll
            for (int r = 0; r < 4; ++r)
                C[(size_t)(crow0 + m * 16 + r) * ldc + ccol + n * 16] = acc[m][n][r];
}

// --------------------------- softmax rows -> bf16 A ------------------------
__global__ __launch_bounds__(256) void softmax_rows(float* __restrict__ S, u16* __restrict__ Arow0) {
    __shared__ float red[256];
    const int p = blockIdx.x;
    float* row = S + (size_t)p * L_PAD;
    u16* arow = Arow0 + (size_t)p * L_PAD;
    const int tid = threadIdx.x;
    float m = -1e30f;
    for (int l = tid; l < L_TOT; l += 256) m = fmaxf(m, row[l]);
    red[tid] = m;
    __syncthreads();
    for (int s = 128; s > 0; s >>= 1) {
        if (tid < s) red[tid] = fmaxf(red[tid], red[tid + s]);
        __syncthreads();
    }
    m = red[0];
    __syncthreads();
    float sum = 0.f;
    for (int l = tid; l < L_TOT; l += 256) {
        float e = __expf(row[l] - m);
        row[l] = e;
        sum += e;
    }
    red[tid] = sum;
    __syncthreads();
    for (int s = 128; s > 0; s >>= 1) {
        if (tid < s) red[tid] += red[tid + s];
        __syncthreads();
    }
    float inv = 1.0f / red[0];
    for (int l = tid; l < L_TOT; l += 256) arow[l] = f2b(row[l] * inv);
    for (int l = L_TOT + tid; l < L_PAD; l += 256) arow[l] = 0;
}

// --------------------------- final gather + residual -----------------------
__global__ void final_kernel(const float* __restrict__ Zpart, const float* __restrict__ x,
                             float* __restrict__ out) {
    int idx = blockIdx.x * 256 + threadIdx.x;
    if (idx >= 4 * 50 * HW) return;
    int p = idx % HW;
    int t = idx / HW;
    int c = t % 50;
    int b = t / 50;
    int y = p / 48, xx = p % 48;
    float s = 0.f;
#pragma unroll
    for (int ky = 0; ky < 3; ++ky) {
#pragma unroll
        for (int kx = 0; kx < 3; ++kx) {
            int yy = y + ky - 1, xv = xx + kx - 1;
            if (yy < 0 || yy >= 48 || xv < 0 || xv >= 48) continue;
            int pp = yy * 48 + xv;
            int j = c * 9 + (2 - ky) * 3 + (2 - kx);
#pragma unroll
            for (int sp = 0; sp < NS2; ++sp)
                s += Zpart[((size_t)(b * NS2 + sp) * HW + pp) * JD + j];
        }
    }
    size_t o = ((size_t)b * 50 + c) * HW + p;
    out[o] = x[o] + 0.25f * s;
}

// ---------------------------------------------------------------------------
extern "C" void kernel_launch(void* const* d_in, const int* in_sizes, int n_in,
                              void* d_out, int out_size, void* d_ws, size_t ws_size,
                              hipStream_t stream) {
    const float* x       = (const float*)d_in[0];
    const float* w_base  = (const float*)d_in[1];
    const float* b_base  = (const float*)d_in[2];
    const float* a_base  = (const float*)d_in[3];
    const float* w_match = (const float*)d_in[4];
    const float* b_match = (const float*)d_in[5];
    const float* a_match = (const float*)d_in[6];
    const float* w_asm   = (const float*)d_in[7];
    const float* b_asm   = (const float*)d_in[8];
    const float* a_asm   = (const float*)d_in[9];
    float* out = (float*)d_out;
    float* ws = (float*)d_ws;
    (void)in_sizes; (void)n_in; (void)out_size; (void)ws_size;

    const int hs[5] = {48, 43, 38, 33, 28};
    const int loff[6] = {0, 2304, 4153, 5597, 6686, 7470};

    // ---- layout (floats). Builder scratch aliases the head of A_attn. ----
    size_t off = 0;
    auto alloc = [&](size_t n) { size_t o = off; off += (n + 63) & ~(size_t)63; return o; };
    size_t o_wm = alloc(142 * 48);
    size_t o_rtmp = alloc((size_t)200 * 43 * 48);
    size_t o_ref[5];
    o_ref[0] = 0;
    for (int si = 1; si < 5; ++si) o_ref[si] = alloc((size_t)200 * hs[si] * hs[si]);
    size_t o_base = alloc((size_t)200 * L_TOT);
    size_t o_refm = alloc((size_t)100 * L_TOT);
    size_t o_mb = alloc((size_t)100 * HW);
    size_t o_norms = alloc((size_t)4 * L_TOT);
    // A_attn bf16 all-batch, starts at 0 (aliases the scratch above; scratch is
    // dead before the first softmax writes A).
    size_t o_A = 0;
    size_t after_A = ((size_t)4 * HW * L_PAD * 2 + 3) / 4;   // in floats
    after_A = (after_A + 63) & ~(size_t)63;
    size_t o_S = after_A;                                    // fp32, single batch
    size_t o_Z = o_S;                                        // aliases S (dead by GEMM2)
    size_t o_Q = o_S + (((size_t)HW * L_PAD + 63) & ~(size_t)63);
    size_t o_K = o_Q + ((size_t)4 * HW * KD * 2 / 4);
    size_t o_VT = o_K + ((size_t)4 * L_PAD * KD * 2 / 4);

    u16* Qb = (u16*)(ws + o_Q);
    u16* Kb = (u16*)(ws + o_K);
    u16* VTb = (u16*)(ws + o_VT);
    u16* Ab = (u16*)(ws + o_A);
    float* Sb = ws + o_S;
    float* Zb = ws + o_Z;

    // ---- resizes ----
    resize_weights_kernel<<<1, 256, 0, stream>>>(ws + o_wm);
    const int woff[5] = {0, 0, 43 * 48, (43 + 38) * 48, (43 + 38 + 33) * 48};
    for (int si = 1; si < 5; ++si) {
        int osz = hs[si];
        int n1 = 200 * osz * 48;
        resize_h<<<(n1 + 255) / 256, 256, 0, stream>>>(x, ws + o_wm + woff[si], ws + o_rtmp, osz);
        int n2 = 200 * osz * osz;
        resize_w<<<(n2 + 255) / 256, 256, 0, stream>>>(ws + o_rtmp, ws + o_wm + woff[si],
                                                       ws + o_ref[si], osz);
    }
    // ---- convs ----
    for (int si = 0; si < 5; ++si) {
        int P = hs[si] * hs[si];
        const float* in = (si == 0) ? x : ws + o_ref[si];
        int nb = 4 * 50 * P;
        conv1x1_prelu<<<(nb + 255) / 256, 256, 0, stream>>>(
            in, w_asm, b_asm, a_asm, ws + o_base + (size_t)200 * loff[si], P, 50);
        int nm = 4 * 25 * P;
        conv1x1_prelu<<<(nm + 255) / 256, 256, 0, stream>>>(
            in, w_match, b_match, a_match, ws + o_refm + (size_t)100 * loff[si], P, 25);
    }
    {
        int nmb = 4 * 25 * HW;
        conv1x1_prelu<<<(nmb + 255) / 256, 256, 0, stream>>>(x, w_base, b_base, a_base,
                                                             ws + o_mb, HW, 25);
    }
    // ---- operand builders (bf16, all batches) ----
    {
        int n = 4 * HW * KD;
        q_build<<<(n + 255) / 256, 256, 0, stream>>>(ws + o_mb, Qb);
    }
    {
        int n = 4 * L_TOT;
        norms_kernel<<<(n + 255) / 256, 256, 0, stream>>>(ws + o_refm, ws + o_norms);
    }
    {
        int n = 4 * L_PAD * KD;
        kt_build<<<(n + 255) / 256, 256, 0, stream>>>(ws + o_refm, ws + o_norms, Kb);
    }
    {
        int n = 4 * JD * L_PAD;
        v_build<<<(n + 255) / 256, 256, 0, stream>>>(ws + o_base, VTb);
    }

    // ---- per-batch GEMM1 + softmax (S reused; A accumulated per batch) ----
    for (int b = 0; b < 4; ++b) {
        dim3 g1(L_PAD / 128, HW / 128, 1);
        gemm_bt<<<g1, 256, 0, stream>>>(Qb + (size_t)b * HW * KD,
                                        Kb + (size_t)b * L_PAD * KD,
                                        Sb, KD, KD / 64, 1, 0, 0, 0, L_PAD);
        softmax_rows<<<HW, 256, 0, stream>>>(Sb, Ab + (size_t)b * HW * L_PAD);
    }

    // ---- batched split-K GEMM2 (Z aliases S) ----
    {
        dim3 g2(JD / 128, HW / 128, 4 * NS2);
        gemm_bt<<<g2, 256, 0, stream>>>(Ab, VTb, Zb, L_PAD, (L_PAD / 64) / NS2, NS2,
                                        (long)HW * L_PAD, (long)JD * L_PAD,
                                        (long)HW * JD, JD);
    }
    final_kernel<<<(4 * 50 * HW + 255) / 256, 256, 0, stream>>>(Zb, x, out);
}

// Round 3
// 863.202 us; speedup vs baseline: 2.7785x; 1.0236x over previous
//
#include <hip/hip_runtime.h>
#include <hip/hip_bf16.h>
#include <math.h>

// ---------------------------------------------------------------------------
// RFDN panet attention, MI355X.  Round 3:
//   - fused score+softmax (chunked, 2-pass recompute, bf16 A out, stats m/d)
//   - GEMM2 bf16 MFMA with chunk-aligned split-K + XCD swizzle, bf16 Z
//   - final: combine chunk stats (softmax denom folded here) + 3x3 gather
// ---------------------------------------------------------------------------

#define L_TOT 7470
#define L_PAD 7680   // 64 * 120, 4 chunks of 1920
#define NCHUNK 4
#define CHUNK_TILES 30   // 64-key tiles per chunk
#define KD    256    // padded 225
#define JD    512    // padded 450 = 50*3*3
#define HW    2304   // 48*48

typedef unsigned short u16;
typedef __attribute__((ext_vector_type(8))) short bf16x8;
typedef __attribute__((ext_vector_type(4))) float f32x4;

__device__ inline u16 f2b(float f) {
    __hip_bfloat16 h = __float2bfloat16(f);
    return __builtin_bit_cast(u16, h);
}
__device__ inline float b2f(u16 u) {
    __hip_bfloat16 h = __builtin_bit_cast(__hip_bfloat16, u);
    return __bfloat162float(h);
}

__constant__ int c_hs[5]   = {48, 43, 38, 33, 28};
__constant__ int c_loff[6] = {0, 2304, 4153, 5597, 6686, 7470};

__device__ inline void decode_l(int l, int& si, int& hs, int& pos) {
    si = 0;
#pragma unroll
    for (int s = 0; s < 4; ++s)
        if (l >= c_loff[s + 1]) si = s + 1;
    pos = l - c_loff[si];
    hs = c_hs[si];
}

#define GLOAD16(g, l) __builtin_amdgcn_global_load_lds(                          \
        (__attribute__((address_space(1))) const void*)(g),                      \
        (__attribute__((address_space(3))) void*)(l), 16, 0, 0)

// --------------------------- bicubic resize --------------------------------
__global__ void resize_weights_kernel(float* __restrict__ wmall) {
    int r = blockIdx.x * blockDim.x + threadIdx.x;
    if (r >= 142) return;
    int sizes[4] = {43, 38, 33, 28};
    int si = 0, i = r, woffs = 0;
    for (si = 0; si < 4; ++si) {
        if (i < sizes[si]) break;
        i -= sizes[si];
        woffs += sizes[si] * 48;
    }
    int osz = sizes[si];
    float inv_scale = 48.0f / (float)osz;
    float kscale = inv_scale;
    float sample_f = ((float)i + 0.5f) * inv_scale - 0.5f;
    float w[48];
    float tot = 0.f;
    for (int j = 0; j < 48; ++j) {
        float t = fabsf(sample_f - (float)j) / kscale;
        float v;
        if (t >= 2.f)       v = 0.f;
        else if (t >= 1.f)  v = ((-0.5f * t + 2.5f) * t - 4.f) * t + 2.f;
        else                v = ((1.5f * t - 2.5f) * t) * t + 1.f;
        w[j] = v;
        tot += v;
    }
    float invt = 1.f / tot;
    for (int j = 0; j < 48; ++j) wmall[woffs + i * 48 + j] = w[j] * invt;
}

__global__ void resize_h(const float* __restrict__ in, const float* __restrict__ wm,
                         float* __restrict__ tmp, int osz) {
    int idx = blockIdx.x * 256 + threadIdx.x;
    int total = 200 * osz * 48;
    if (idx >= total) return;
    int xi = idx % 48;
    int t = idx / 48;
    int yo = t % osz;
    int bc = t / osz;
    const float* wr = wm + yo * 48;
    const float* ip = in + (size_t)bc * 2304 + xi;
    float s = 0.f;
#pragma unroll
    for (int yi = 0; yi < 48; ++yi) s += wr[yi] * ip[yi * 48];
    tmp[idx] = s;
}

__global__ void resize_w(const float* __restrict__ tmp, const float* __restrict__ wm,
                         float* __restrict__ refout, int osz) {
    int idx = blockIdx.x * 256 + threadIdx.x;
    int total = 200 * osz * osz;
    if (idx >= total) return;
    int xo = idx % osz;
    int t = idx / osz;
    int yo = t % osz;
    int bc = t / osz;
    const float* wr = wm + xo * 48;
    const float* ip = tmp + ((size_t)bc * osz + yo) * 48;
    float s = 0.f;
#pragma unroll
    for (int xi = 0; xi < 48; ++xi) s += wr[xi] * ip[xi];
    refout[idx] = s;
}

// --------------------------- 1x1 conv + PReLU ------------------------------
__global__ void conv1x1_prelu(const float* __restrict__ in, const float* __restrict__ w,
                              const float* __restrict__ bias, const float* __restrict__ a,
                              float* __restrict__ outp, int P, int Co) {
    int idx = blockIdx.x * 256 + threadIdx.x;
    int total = 4 * Co * P;
    if (idx >= total) return;
    int p = idx % P;
    int t = idx / P;
    int co = t % Co;
    int b = t / Co;
    const float* ip = in + (size_t)b * 50 * P + p;
    const float* wr = w + co * 50;
    float s = bias[co];
#pragma unroll
    for (int ci = 0; ci < 50; ++ci) s += wr[ci] * ip[(size_t)ci * P];
    float av = a[0];
    outp[idx] = (s >= 0.f) ? s : av * s;
}

// --------------------------- builders (bf16) -------------------------------
__global__ void q_build(const float* __restrict__ mb, u16* __restrict__ Q) {
    int idx = blockIdx.x * 256 + threadIdx.x;
    if (idx >= 4 * HW * KD) return;
    int k = idx % KD;
    int t = idx / KD;
    int p = t % HW;
    int b = t / HW;
    float v = 0.f;
    if (k < 225) {
        int c = k / 9, r = k % 9, ky = r / 3, kx = r % 3;
        int y = p / 48, xx = p % 48;
        int yy = y + ky - 1, xv = xx + kx - 1;
        if (yy >= 0 && yy < 48 && xv >= 0 && xv < 48)
            v = mb[((size_t)(b * 25 + c)) * HW + yy * 48 + xv];
    }
    Q[idx] = f2b(v);
}

__global__ void norms_kernel(const float* __restrict__ refm_all, float* __restrict__ norms) {
    int idx = blockIdx.x * 256 + threadIdx.x;
    if (idx >= 4 * L_TOT) return;
    int l = idx % L_TOT;
    int b = idx / L_TOT;
    int si, hs, pos;
    decode_l(l, si, hs, pos);
    int P = hs * hs;
    int ly = pos / hs, lx = pos % hs;
    const float* rb = refm_all + (size_t)100 * c_loff[si] + (size_t)(b * 25) * P;
    float ss = 0.f;
    for (int c = 0; c < 25; ++c) {
        const float* rc = rb + (size_t)c * P;
#pragma unroll
        for (int ky = 0; ky < 3; ++ky) {
#pragma unroll
            for (int kx = 0; kx < 3; ++kx) {
                int yy = ly + ky - 1, xv = lx + kx - 1;
                if (yy >= 0 && yy < hs && xv >= 0 && xv < hs) {
                    float v = rc[yy * hs + xv];
                    ss += v * v;
                }
            }
        }
    }
    norms[idx] = 10.0f / fmaxf(sqrtf(ss), 1e-4f);  // SM_SCALE folded
}

__global__ void kt_build(const float* __restrict__ refm_all, const float* __restrict__ norms,
                         u16* __restrict__ K) {
    int idx = blockIdx.x * 256 + threadIdx.x;
    if (idx >= 4 * L_PAD * KD) return;
    int k = idx % KD;
    int t = idx / KD;
    int l = t % L_PAD;
    int b = t / L_PAD;
    float v = 0.f;
    if (k < 225 && l < L_TOT) {
        int si, hs, pos;
        decode_l(l, si, hs, pos);
        int P = hs * hs;
        int ly = pos / hs, lx = pos % hs;
        int c = k / 9, r = k % 9, ky = r / 3, kx = r % 3;
        int yy = ly + ky - 1, xv = lx + kx - 1;
        if (yy >= 0 && yy < hs && xv >= 0 && xv < hs)
            v = refm_all[(size_t)100 * c_loff[si] + ((size_t)(b * 25 + c)) * P + yy * hs + xv]
                * norms[(size_t)b * L_TOT + l];
    }
    K[idx] = f2b(v);
}

__global__ void v_build(const float* __restrict__ base_all, u16* __restrict__ VT) {
    int idx = blockIdx.x * 256 + threadIdx.x;
    if (idx >= 4 * JD * L_PAD) return;
    int l = idx % L_PAD;
    int t = idx / L_PAD;
    int j = t % JD;
    int b = t / JD;
    float v = 0.f;
    if (j < 450 && l < L_TOT) {
        int si, hs, pos;
        decode_l(l, si, hs, pos);
        int P = hs * hs;
        int ly = pos / hs, lx = pos % hs;
        int c = j / 9, r = j % 9, ky = r / 3, kx = r % 3;
        int yy = ly + ky - 1, xv = lx + kx - 1;
        if (yy >= 0 && yy < hs && xv >= 0 && xv < hs)
            v = base_all[(size_t)200 * c_loff[si] + ((size_t)(b * 50 + c)) * P + yy * hs + xv];
    }
    VT[idx] = f2b(v);
}

// --------------------------- fused score + softmax -------------------------
// grid (8, 36): bx in 0..7, by in 0..35
//   b = bx>>1, chunk = (bx&1) + 2*(by&1), Mtile = by>>1  (XCD ~ batch affinity)
// Block: 256 thr, 4 waves (wr = row half of 128, wc = key half of 64-key tile).
// Q tile (128x256) persistent in registers. K tiles streamed through LDS.
// Pass1: per-lane online max/denom; butterfly+cross-wave combine; write m_c,d_c.
// Pass2: recompute S, write A = exp(S - m_c) bf16 (masked cols -> 0).
__global__ __launch_bounds__(256, 2) void attn_score(
    const u16* __restrict__ Qg, const u16* __restrict__ Kg,
    u16* __restrict__ Ag, float* __restrict__ mC, float* __restrict__ dC) {
    __shared__ u16 smem[128 * KD];        // 64 KB: Q staging, then K tiles
    __shared__ float sm_m[2][128], sm_d[2][128];
    const int bx = blockIdx.x, by = blockIdx.y;
    const int b = bx >> 1;
    const int chunk = (bx & 1) + 2 * (by & 1);
    const int bm = (by >> 1) * 128;
    const u16* Q = Qg + (size_t)b * HW * KD;
    const u16* K = Kg + (size_t)b * L_PAD * KD;
    u16* A = Ag + (size_t)b * HW * L_PAD;
    const int tid = threadIdx.x, lane = tid & 63, wid = tid >> 6;
    const int wr = wid >> 1, wc = wid & 1;
    const int l15 = lane & 15, l16 = lane >> 4;

    // ---- stage Q tile once, load persistent fragments ----
    {
        const u16* qsrc = Q + (size_t)(bm + wid * 32 + (lane >> 5)) * KD + (lane & 31) * 8;
        u16* qdst = smem + (size_t)(wid * 32) * KD;   // wave-uniform base
#pragma unroll
        for (int q = 0; q < 16; ++q)
            GLOAD16(qsrc + (size_t)(q * 2) * KD, qdst + (q * 2) * KD);
    }
    __syncthreads();
    bf16x8 qf[4][8];
#pragma unroll
    for (int m = 0; m < 4; ++m)
#pragma unroll
        for (int k = 0; k < 8; ++k)
            qf[m][k] = *(const bf16x8*)&smem[(size_t)(wr * 64 + m * 16 + l15) * KD + k * 32 + l16 * 8];
    __syncthreads();

    float mrun[4][4], drun[4][4];
#pragma unroll
    for (int m = 0; m < 4; ++m)
#pragma unroll
        for (int r = 0; r < 4; ++r) { mrun[m][r] = -3e38f; drun[m][r] = 0.f; }

    const int t0 = chunk * CHUNK_TILES;
    const int colb_base = wc * 32 + l15;

    // ================= pass 1: stats =================
    for (int t = t0; t < t0 + CHUNK_TILES; ++t) {
        {
            const u16* ksrc = K + (size_t)(t * 64 + wid * 16 + (lane >> 5)) * KD + (lane & 31) * 8;
            u16* kdst = smem + (size_t)(wid * 16) * KD;
#pragma unroll
            for (int q = 0; q < 8; ++q)
                GLOAD16(ksrc + (size_t)(q * 2) * KD, kdst + (q * 2) * KD);
        }
        __syncthreads();
        f32x4 acc[4][2];
#pragma unroll
        for (int m = 0; m < 4; ++m)
#pragma unroll
            for (int n = 0; n < 2; ++n) acc[m][n] = (f32x4){0.f, 0.f, 0.f, 0.f};
#pragma unroll
        for (int k = 0; k < 8; ++k) {
            bf16x8 bfr[2];
#pragma unroll
            for (int n = 0; n < 2; ++n)
                bfr[n] = *(const bf16x8*)&smem[(size_t)(wc * 32 + n * 16 + l15) * KD + k * 32 + l16 * 8];
#pragma unroll
            for (int m = 0; m < 4; ++m)
#pragma unroll
                for (int n = 0; n < 2; ++n)
                    acc[m][n] = __builtin_amdgcn_mfma_f32_16x16x32_bf16(qf[m][k], bfr[n], acc[m][n], 0, 0, 0);
        }
        const int col0 = t * 64 + colb_base;
        const bool v0 = col0 < L_TOT, v1 = col0 + 16 < L_TOT;
#pragma unroll
        for (int m = 0; m < 4; ++m)
#pragma unroll
            for (int r = 0; r < 4; ++r) {
                float s0 = v0 ? acc[m][0][r] : -3e38f;
                float s1 = v1 ? acc[m][1][r] : -3e38f;
                float tmx = fmaxf(s0, s1);
                float mnew = fmaxf(mrun[m][r], tmx);
                float sc = __expf(mrun[m][r] - mnew);
                float ss = (v0 ? __expf(acc[m][0][r] - mnew) : 0.f)
                         + (v1 ? __expf(acc[m][1][r] - mnew) : 0.f);
                drun[m][r] = drun[m][r] * sc + ss;
                mrun[m][r] = mnew;
            }
        __syncthreads();
    }

    // ---- combine the 16 lane-columns (butterfly over lane&15) ----
#pragma unroll
    for (int m = 0; m < 4; ++m)
#pragma unroll
        for (int r = 0; r < 4; ++r) {
            float mv = mrun[m][r], dv = drun[m][r];
#pragma unroll
            for (int st = 1; st <= 8; st <<= 1) {
                float mo = __shfl_xor(mv, st);
                float dn = __shfl_xor(dv, st);
                float mn = fmaxf(mv, mo);
                dv = dv * __expf(mv - mn) + dn * __expf(mo - mn);
                mv = mn;
            }
            mrun[m][r] = mv; drun[m][r] = dv;
        }
    // ---- combine the two wc halves via LDS ----
    if (l15 == 0) {
#pragma unroll
        for (int m = 0; m < 4; ++m)
#pragma unroll
            for (int r = 0; r < 4; ++r) {
                int row = wr * 64 + m * 16 + l16 * 4 + r;
                sm_m[wc][row] = mrun[m][r];
                sm_d[wc][row] = drun[m][r];
            }
    }
    __syncthreads();
#pragma unroll
    for (int m = 0; m < 4; ++m)
#pragma unroll
        for (int r = 0; r < 4; ++r) {
            int row = wr * 64 + m * 16 + l16 * 4 + r;
            float m0 = sm_m[0][row], m1 = sm_m[1][row];
            float d0 = sm_d[0][row], d1 = sm_d[1][row];
            float mf = fmaxf(m0, m1);
            mrun[m][r] = mf;
            drun[m][r] = d0 * __expf(m0 - mf) + d1 * __expf(m1 - mf);
        }
    if (wc == 0 && l15 == 0) {
#pragma unroll
        for (int m = 0; m < 4; ++m)
#pragma unroll
            for (int r = 0; r < 4; ++r) {
                int row = wr * 64 + m * 16 + l16 * 4 + r;
                size_t o = (size_t)(chunk * 4 + b) * HW + bm + row;
                mC[o] = mrun[m][r];
                dC[o] = drun[m][r];
            }
    }
    __syncthreads();

    // ================= pass 2: recompute + write A =================
    for (int t = t0; t < t0 + CHUNK_TILES; ++t) {
        {
            const u16* ksrc = K + (size_t)(t * 64 + wid * 16 + (lane >> 5)) * KD + (lane & 31) * 8;
            u16* kdst = smem + (size_t)(wid * 16) * KD;
#pragma unroll
            for (int q = 0; q < 8; ++q)
                GLOAD16(ksrc + (size_t)(q * 2) * KD, kdst + (q * 2) * KD);
        }
        __syncthreads();
        f32x4 acc[4][2];
#pragma unroll
        for (int m = 0; m < 4; ++m)
#pragma unroll
            for (int n = 0; n < 2; ++n) acc[m][n] = (f32x4){0.f, 0.f, 0.f, 0.f};
#pragma unroll
        for (int k = 0; k < 8; ++k) {
            bf16x8 bfr[2];
#pragma unroll
            for (int n = 0; n < 2; ++n)
                bfr[n] = *(const bf16x8*)&smem[(size_t)(wc * 32 + n * 16 + l15) * KD + k * 32 + l16 * 8];
#pragma unroll
            for (int m = 0; m < 4; ++m)
#pragma unroll
                for (int n = 0; n < 2; ++n)
                    acc[m][n] = __builtin_amdgcn_mfma_f32_16x16x32_bf16(qf[m][k], bfr[n], acc[m][n], 0, 0, 0);
        }
        const int col0 = t * 64 + colb_base;
#pragma unroll
        for (int m = 0; m < 4; ++m) {
            const int row = bm + wr * 64 + m * 16 + l16 * 4;
#pragma unroll
            for (int n = 0; n < 2; ++n) {
                const int col = col0 + n * 16;
                const bool vld = col < L_TOT;
#pragma unroll
                for (int r = 0; r < 4; ++r) {
                    float w = vld ? __expf(acc[m][n][r] - mrun[m][r]) : 0.f;
                    A[(size_t)(row + r) * L_PAD + col] = f2b(w);
                }
            }
        }
        __syncthreads();
    }
}

// --------------------------- combine chunk stats ---------------------------
// fac[c][b][p] = exp(m_c - m_f) / d_f
__global__ void combine_stats(const float* __restrict__ mC, const float* __restrict__ dC,
                              float* __restrict__ fac) {
    int idx = blockIdx.x * 256 + threadIdx.x;
    if (idx >= 4 * HW) return;
    int b = idx / HW, p = idx % HW;
    float m[NCHUNK], d[NCHUNK];
#pragma unroll
    for (int c = 0; c < NCHUNK; ++c) {
        size_t o = (size_t)(c * 4 + b) * HW + p;
        m[c] = mC[o]; d[c] = dC[o];
    }
    float mf = m[0];
#pragma unroll
    for (int c = 1; c < NCHUNK; ++c) mf = fmaxf(mf, m[c]);
    float w[NCHUNK], df = 0.f;
#pragma unroll
    for (int c = 0; c < NCHUNK; ++c) { w[c] = __expf(m[c] - mf); df += d[c] * w[c]; }
    float inv = 1.0f / df;
#pragma unroll
    for (int c = 0; c < NCHUNK; ++c) fac[(size_t)(c * 4 + b) * HW + p] = w[c] * inv;
}

// --------------------------- GEMM2: Z_z = A_chunk * VT_chunk^T -------------
// grid (8, 144): bx = XCD slot, by -> (xt, yt, zq); z = bx + 8*zq in 0..15.
// z = batch*4 + chunk. C bf16 [16][HW][JD].
__global__ __launch_bounds__(256) void gemm2_kernel(
    const u16* __restrict__ A0, const u16* __restrict__ B0, u16* __restrict__ C0) {
    __shared__ u16 As[128 * 64];
    __shared__ u16 Bs[128 * 64];
    const int bx = blockIdx.x, by = blockIdx.y;
    const int xt = by & 3, yt = (by >> 2) % 18, zq = by / 72;
    const int z = bx + 8 * zq;
    const int batch = z >> 2, chunk = z & 3;
    const u16* A = A0 + (size_t)batch * HW * L_PAD + chunk * (CHUNK_TILES * 64);
    const u16* B = B0 + (size_t)batch * JD * L_PAD + chunk * (CHUNK_TILES * 64);
    u16* C = C0 + (size_t)z * HW * JD;
    const int bm = yt * 128, bn = xt * 128;
    const int tid = threadIdx.x, lane = tid & 63, wid = tid >> 6;
    const int wr = wid >> 1, wc = wid & 1;
    const int srow = lane >> 3;
    const int scol = (lane & 7) * 8;

    f32x4 acc[4][4];
#pragma unroll
    for (int i = 0; i < 4; ++i)
#pragma unroll
        for (int j = 0; j < 4; ++j) acc[i][j] = (f32x4){0.f, 0.f, 0.f, 0.f};

    const u16* aG = A + (size_t)(bm + wid * 32 + srow) * L_PAD + scol;
    const u16* bG = B + (size_t)(bn + wid * 32 + srow) * L_PAD + scol;
    u16* aL = As + wid * 32 * 64;
    u16* bL = Bs + wid * 32 * 64;

    for (int t = 0; t < CHUNK_TILES; ++t) {
#pragma unroll
        for (int q = 0; q < 4; ++q) {
            GLOAD16(aG + (size_t)q * 8 * L_PAD, aL + q * 8 * 64);
            GLOAD16(bG + (size_t)q * 8 * L_PAD, bL + q * 8 * 64);
        }
        aG += 64;
        bG += 64;
        __syncthreads();
#pragma unroll
        for (int kc = 0; kc < 64; kc += 32) {
            bf16x8 af[4], bf[4];
#pragma unroll
            for (int m = 0; m < 4; ++m)
                af[m] = *(const bf16x8*)&As[(wr * 64 + m * 16 + (lane & 15)) * 64 + kc + (lane >> 4) * 8];
#pragma unroll
            for (int n = 0; n < 4; ++n)
                bf[n] = *(const bf16x8*)&Bs[(wc * 64 + n * 16 + (lane & 15)) * 64 + kc + (lane >> 4) * 8];
#pragma unroll
            for (int m = 0; m < 4; ++m)
#pragma unroll
                for (int n = 0; n < 4; ++n)
                    acc[m][n] = __builtin_amdgcn_mfma_f32_16x16x32_bf16(af[m], bf[n], acc[m][n], 0, 0, 0);
        }
        __syncthreads();
    }
    const int crow0 = bm + wr * 64 + (lane >> 4) * 4;
    const int ccol = bn + wc * 64 + (lane & 15);
#pragma unroll
    for (int m = 0; m < 4; ++m)
#pragma unroll
        for (int n = 0; n < 4; ++n)
#pragma unroll
            for (int r = 0; r < 4; ++r)
                C[(size_t)(crow0 + m * 16 + r) * JD + ccol + n * 16] = f2b(acc[m][n][r]);
}

// --------------------------- final: gather + normalize + residual ----------
__global__ void final_kernel(const u16* __restrict__ Z, const float* __restrict__ fac,
                             const float* __restrict__ x, float* __restrict__ out) {
    int idx = blockIdx.x * 256 + threadIdx.x;
    if (idx >= 4 * 50 * HW) return;
    int p = idx % HW;
    int t = idx / HW;
    int c = t % 50;
    int b = t / 50;
    int y = p / 48, xx = p % 48;
    float s = 0.f;
#pragma unroll
    for (int ky = 0; ky < 3; ++ky) {
#pragma unroll
        for (int kx = 0; kx < 3; ++kx) {
            int yy = y + ky - 1, xv = xx + kx - 1;
            if (yy < 0 || yy >= 48 || xv < 0 || xv >= 48) continue;
            int pp = yy * 48 + xv;
            int j = c * 9 + (2 - ky) * 3 + (2 - kx);
            float g = 0.f;
#pragma unroll
            for (int ch = 0; ch < NCHUNK; ++ch)
                g += fac[(size_t)(ch * 4 + b) * HW + pp]
                   * b2f(Z[((size_t)(b * 4 + ch) * HW + pp) * JD + j]);
            s += g;
        }
    }
    size_t o = ((size_t)b * 50 + c) * HW + p;
    out[o] = x[o] + 0.25f * s;
}

// ---------------------------------------------------------------------------
extern "C" void kernel_launch(void* const* d_in, const int* in_sizes, int n_in,
                              void* d_out, int out_size, void* d_ws, size_t ws_size,
                              hipStream_t stream) {
    const float* x       = (const float*)d_in[0];
    const float* w_base  = (const float*)d_in[1];
    const float* b_base  = (const float*)d_in[2];
    const float* a_base  = (const float*)d_in[3];
    const float* w_match = (const float*)d_in[4];
    const float* b_match = (const float*)d_in[5];
    const float* a_match = (const float*)d_in[6];
    const float* w_asm   = (const float*)d_in[7];
    const float* b_asm   = (const float*)d_in[8];
    const float* a_asm   = (const float*)d_in[9];
    float* out = (float*)d_out;
    float* ws = (float*)d_ws;
    (void)in_sizes; (void)n_in; (void)out_size; (void)ws_size;

    const int hs[5] = {48, 43, 38, 33, 28};
    const int loff[6] = {0, 2304, 4153, 5597, 6686, 7470};

    // ---- builder scratch (aliases head of A; dead before attn_score) ----
    size_t off = 0;
    auto alloc = [&](size_t n) { size_t o = off; off += (n + 63) & ~(size_t)63; return o; };
    size_t o_wm = alloc(142 * 48);
    size_t o_rtmp = alloc((size_t)200 * 43 * 48);
    size_t o_ref[5];
    o_ref[0] = 0;
    for (int si = 1; si < 5; ++si) o_ref[si] = alloc((size_t)200 * hs[si] * hs[si]);
    size_t o_base = alloc((size_t)200 * L_TOT);
    size_t o_refm = alloc((size_t)100 * L_TOT);
    size_t o_mb = alloc((size_t)100 * HW);
    size_t o_norms = alloc((size_t)4 * L_TOT);

    // ---- persistent layout (floats) ----
    size_t o_A = 0;                                       // bf16 [4][HW][L_PAD]
    size_t o_Q = (size_t)4 * HW * L_PAD / 2;              // 35,389,440
    size_t o_K = o_Q + (size_t)4 * HW * KD / 2;
    size_t o_VT = o_K + (size_t)4 * L_PAD * KD / 2;
    size_t o_Z = o_VT + (size_t)4 * JD * L_PAD / 2;       // bf16 [16][HW][JD]
    size_t o_mc = o_Z + (size_t)16 * HW * JD / 2;
    size_t o_dc = o_mc + (size_t)16 * HW;
    size_t o_fac = o_dc + (size_t)16 * HW;

    u16* Qb = (u16*)(ws + o_Q);
    u16* Kb = (u16*)(ws + o_K);
    u16* VTb = (u16*)(ws + o_VT);
    u16* Ab = (u16*)(ws + o_A);
    u16* Zb = (u16*)(ws + o_Z);

    // ---- resizes ----
    resize_weights_kernel<<<1, 256, 0, stream>>>(ws + o_wm);
    const int woff[5] = {0, 0, 43 * 48, (43 + 38) * 48, (43 + 38 + 33) * 48};
    for (int si = 1; si < 5; ++si) {
        int osz = hs[si];
        int n1 = 200 * osz * 48;
        resize_h<<<(n1 + 255) / 256, 256, 0, stream>>>(x, ws + o_wm + woff[si], ws + o_rtmp, osz);
        int n2 = 200 * osz * osz;
        resize_w<<<(n2 + 255) / 256, 256, 0, stream>>>(ws + o_rtmp, ws + o_wm + woff[si],
                                                       ws + o_ref[si], osz);
    }
    // ---- convs ----
    for (int si = 0; si < 5; ++si) {
        int P = hs[si] * hs[si];
        const float* in = (si == 0) ? x : ws + o_ref[si];
        int nb = 4 * 50 * P;
        conv1x1_prelu<<<(nb + 255) / 256, 256, 0, stream>>>(
            in, w_asm, b_asm, a_asm, ws + o_base + (size_t)200 * loff[si], P, 50);
        int nm = 4 * 25 * P;
        conv1x1_prelu<<<(nm + 255) / 256, 256, 0, stream>>>(
            in, w_match, b_match, a_match, ws + o_refm + (size_t)100 * loff[si], P, 25);
    }
    {
        int nmb = 4 * 25 * HW;
        conv1x1_prelu<<<(nmb + 255) / 256, 256, 0, stream>>>(x, w_base, b_base, a_base,
                                                             ws + o_mb, HW, 25);
    }
    // ---- operand builders ----
    {
        int n = 4 * HW * KD;
        q_build<<<(n + 255) / 256, 256, 0, stream>>>(ws + o_mb, Qb);
    }
    {
        int n = 4 * L_TOT;
        norms_kernel<<<(n + 255) / 256, 256, 0, stream>>>(ws + o_refm, ws + o_norms);
    }
    {
        int n = 4 * L_PAD * KD;
        kt_build<<<(n + 255) / 256, 256, 0, stream>>>(ws + o_refm, ws + o_norms, Kb);
    }
    {
        int n = 4 * JD * L_PAD;
        v_build<<<(n + 255) / 256, 256, 0, stream>>>(ws + o_base, VTb);
    }

    // ---- fused score + softmax (writes A bf16 + chunk stats) ----
    {
        dim3 g(8, 36, 1);
        attn_score<<<g, 256, 0, stream>>>(Qb, Kb, Ab, ws + o_mc, ws + o_dc);
    }
    combine_stats<<<(4 * HW + 255) / 256, 256, 0, stream>>>(ws + o_mc, ws + o_dc, ws + o_fac);

    // ---- GEMM2 (XCD-swizzled, chunk-aligned split-K) ----
    {
        dim3 g(8, 144, 1);
        gemm2_kernel<<<g, 256, 0, stream>>>(Ab, VTb, Zb);
    }
    final_kernel<<<(4 * 50 * HW + 255) / 256, 256, 0, stream>>>(Zb, ws + o_fac, x, out);
}

// Round 4
// 597.434 us; speedup vs baseline: 4.0146x; 1.4448x over previous
//
#include <hip/hip_runtime.h>
#include <hip/hip_bf16.h>
#include <math.h>

// ---------------------------------------------------------------------------
// RFDN panet attention, MI355X.  Round 4:
//   - fused score+softmax (chunked, 2-pass recompute, bf16 A out, stats m/d)
//   - GEMM2 swapped: Zt[j][pp] = VT . A^T  (j-major output, pp-contiguous)
//   - chunk_reduce: Zred[b][j][pp] = sum_ch fac * Zt   (coalesced, vectorized)
//   - final: 9-tap gather on j-major Zred (coalesced) + residual
// ---------------------------------------------------------------------------

#define L_TOT 7470
#define L_PAD 7680   // 64 * 120, 4 chunks of 1920
#define NCHUNK 4
#define CHUNK_TILES 30   // 64-key tiles per chunk
#define KD    256    // padded 225
#define JD    512    // padded 450 = 50*3*3
#define HW    2304   // 48*48

typedef unsigned short u16;
typedef __attribute__((ext_vector_type(8))) short bf16x8;
typedef __attribute__((ext_vector_type(4))) float f32x4;

__device__ inline u16 f2b(float f) {
    __hip_bfloat16 h = __float2bfloat16(f);
    return __builtin_bit_cast(u16, h);
}
__device__ inline float b2f(u16 u) {
    __hip_bfloat16 h = __builtin_bit_cast(__hip_bfloat16, u);
    return __bfloat162float(h);
}

__constant__ int c_hs[5]   = {48, 43, 38, 33, 28};
__constant__ int c_loff[6] = {0, 2304, 4153, 5597, 6686, 7470};

__device__ inline void decode_l(int l, int& si, int& hs, int& pos) {
    si = 0;
#pragma unroll
    for (int s = 0; s < 4; ++s)
        if (l >= c_loff[s + 1]) si = s + 1;
    pos = l - c_loff[si];
    hs = c_hs[si];
}

#define GLOAD16(g, l) __builtin_amdgcn_global_load_lds(                          \
        (__attribute__((address_space(1))) const void*)(g),                      \
        (__attribute__((address_space(3))) void*)(l), 16, 0, 0)

// --------------------------- bicubic resize --------------------------------
__global__ void resize_weights_kernel(float* __restrict__ wmall) {
    int r = blockIdx.x * blockDim.x + threadIdx.x;
    if (r >= 142) return;
    int sizes[4] = {43, 38, 33, 28};
    int si = 0, i = r, woffs = 0;
    for (si = 0; si < 4; ++si) {
        if (i < sizes[si]) break;
        i -= sizes[si];
        woffs += sizes[si] * 48;
    }
    int osz = sizes[si];
    float inv_scale = 48.0f / (float)osz;
    float kscale = inv_scale;
    float sample_f = ((float)i + 0.5f) * inv_scale - 0.5f;
    float w[48];
    float tot = 0.f;
    for (int j = 0; j < 48; ++j) {
        float t = fabsf(sample_f - (float)j) / kscale;
        float v;
        if (t >= 2.f)       v = 0.f;
        else if (t >= 1.f)  v = ((-0.5f * t + 2.5f) * t - 4.f) * t + 2.f;
        else                v = ((1.5f * t - 2.5f) * t) * t + 1.f;
        w[j] = v;
        tot += v;
    }
    float invt = 1.f / tot;
    for (int j = 0; j < 48; ++j) wmall[woffs + i * 48 + j] = w[j] * invt;
}

__global__ void resize_h(const float* __restrict__ in, const float* __restrict__ wm,
                         float* __restrict__ tmp, int osz) {
    int idx = blockIdx.x * 256 + threadIdx.x;
    int total = 200 * osz * 48;
    if (idx >= total) return;
    int xi = idx % 48;
    int t = idx / 48;
    int yo = t % osz;
    int bc = t / osz;
    const float* wr = wm + yo * 48;
    const float* ip = in + (size_t)bc * 2304 + xi;
    float s = 0.f;
#pragma unroll
    for (int yi = 0; yi < 48; ++yi) s += wr[yi] * ip[yi * 48];
    tmp[idx] = s;
}

__global__ void resize_w(const float* __restrict__ tmp, const float* __restrict__ wm,
                         float* __restrict__ refout, int osz) {
    int idx = blockIdx.x * 256 + threadIdx.x;
    int total = 200 * osz * osz;
    if (idx >= total) return;
    int xo = idx % osz;
    int t = idx / osz;
    int yo = t % osz;
    int bc = t / osz;
    const float* wr = wm + xo * 48;
    const float* ip = tmp + ((size_t)bc * osz + yo) * 48;
    float s = 0.f;
#pragma unroll
    for (int xi = 0; xi < 48; ++xi) s += wr[xi] * ip[xi];
    refout[idx] = s;
}

// --------------------------- 1x1 conv + PReLU ------------------------------
__global__ void conv1x1_prelu(const float* __restrict__ in, const float* __restrict__ w,
                              const float* __restrict__ bias, const float* __restrict__ a,
                              float* __restrict__ outp, int P, int Co) {
    int idx = blockIdx.x * 256 + threadIdx.x;
    int total = 4 * Co * P;
    if (idx >= total) return;
    int p = idx % P;
    int t = idx / P;
    int co = t % Co;
    int b = t / Co;
    const float* ip = in + (size_t)b * 50 * P + p;
    const float* wr = w + co * 50;
    float s = bias[co];
#pragma unroll
    for (int ci = 0; ci < 50; ++ci) s += wr[ci] * ip[(size_t)ci * P];
    float av = a[0];
    outp[idx] = (s >= 0.f) ? s : av * s;
}

// --------------------------- builders (bf16) -------------------------------
__global__ void q_build(const float* __restrict__ mb, u16* __restrict__ Q) {
    int idx = blockIdx.x * 256 + threadIdx.x;
    if (idx >= 4 * HW * KD) return;
    int k = idx % KD;
    int t = idx / KD;
    int p = t % HW;
    int b = t / HW;
    float v = 0.f;
    if (k < 225) {
        int c = k / 9, r = k % 9, ky = r / 3, kx = r % 3;
        int y = p / 48, xx = p % 48;
        int yy = y + ky - 1, xv = xx + kx - 1;
        if (yy >= 0 && yy < 48 && xv >= 0 && xv < 48)
            v = mb[((size_t)(b * 25 + c)) * HW + yy * 48 + xv];
    }
    Q[idx] = f2b(v);
}

__global__ void norms_kernel(const float* __restrict__ refm_all, float* __restrict__ norms) {
    int idx = blockIdx.x * 256 + threadIdx.x;
    if (idx >= 4 * L_TOT) return;
    int l = idx % L_TOT;
    int b = idx / L_TOT;
    int si, hs, pos;
    decode_l(l, si, hs, pos);
    int P = hs * hs;
    int ly = pos / hs, lx = pos % hs;
    const float* rb = refm_all + (size_t)100 * c_loff[si] + (size_t)(b * 25) * P;
    float ss = 0.f;
    for (int c = 0; c < 25; ++c) {
        const float* rc = rb + (size_t)c * P;
#pragma unroll
        for (int ky = 0; ky < 3; ++ky) {
#pragma unroll
            for (int kx = 0; kx < 3; ++kx) {
                int yy = ly + ky - 1, xv = lx + kx - 1;
                if (yy >= 0 && yy < hs && xv >= 0 && xv < hs) {
                    float v = rc[yy * hs + xv];
                    ss += v * v;
                }
            }
        }
    }
    norms[idx] = 10.0f / fmaxf(sqrtf(ss), 1e-4f);  // SM_SCALE folded
}

__global__ void kt_build(const float* __restrict__ refm_all, const float* __restrict__ norms,
                         u16* __restrict__ K) {
    int idx = blockIdx.x * 256 + threadIdx.x;
    if (idx >= 4 * L_PAD * KD) return;
    int k = idx % KD;
    int t = idx / KD;
    int l = t % L_PAD;
    int b = t / L_PAD;
    float v = 0.f;
    if (k < 225 && l < L_TOT) {
        int si, hs, pos;
        decode_l(l, si, hs, pos);
        int P = hs * hs;
        int ly = pos / hs, lx = pos % hs;
        int c = k / 9, r = k % 9, ky = r / 3, kx = r % 3;
        int yy = ly + ky - 1, xv = lx + kx - 1;
        if (yy >= 0 && yy < hs && xv >= 0 && xv < hs)
            v = refm_all[(size_t)100 * c_loff[si] + ((size_t)(b * 25 + c)) * P + yy * hs + xv]
                * norms[(size_t)b * L_TOT + l];
    }
    K[idx] = f2b(v);
}

__global__ void v_build(const float* __restrict__ base_all, u16* __restrict__ VT) {
    int idx = blockIdx.x * 256 + threadIdx.x;
    if (idx >= 4 * JD * L_PAD) return;
    int l = idx % L_PAD;
    int t = idx / L_PAD;
    int j = t % JD;
    int b = t / JD;
    float v = 0.f;
    if (j < 450 && l < L_TOT) {
        int si, hs, pos;
        decode_l(l, si, hs, pos);
        int P = hs * hs;
        int ly = pos / hs, lx = pos % hs;
        int c = j / 9, r = j % 9, ky = r / 3, kx = r % 3;
        int yy = ly + ky - 1, xv = lx + kx - 1;
        if (yy >= 0 && yy < hs && xv >= 0 && xv < hs)
            v = base_all[(size_t)200 * c_loff[si] + ((size_t)(b * 50 + c)) * P + yy * hs + xv];
    }
    VT[idx] = f2b(v);
}

// --------------------------- fused score + softmax -------------------------
__global__ __launch_bounds__(256, 2) void attn_score(
    const u16* __restrict__ Qg, const u16* __restrict__ Kg,
    u16* __restrict__ Ag, float* __restrict__ mC, float* __restrict__ dC) {
    __shared__ u16 smem[128 * KD];        // 64 KB: Q staging, then K tiles
    __shared__ float sm_m[2][128], sm_d[2][128];
    const int bx = blockIdx.x, by = blockIdx.y;
    const int b = bx >> 1;
    const int chunk = (bx & 1) + 2 * (by & 1);
    const int bm = (by >> 1) * 128;
    const u16* Q = Qg + (size_t)b * HW * KD;
    const u16* K = Kg + (size_t)b * L_PAD * KD;
    u16* A = Ag + (size_t)b * HW * L_PAD;
    const int tid = threadIdx.x, lane = tid & 63, wid = tid >> 6;
    const int wr = wid >> 1, wc = wid & 1;
    const int l15 = lane & 15, l16 = lane >> 4;

    {
        const u16* qsrc = Q + (size_t)(bm + wid * 32 + (lane >> 5)) * KD + (lane & 31) * 8;
        u16* qdst = smem + (size_t)(wid * 32) * KD;
#pragma unroll
        for (int q = 0; q < 16; ++q)
            GLOAD16(qsrc + (size_t)(q * 2) * KD, qdst + (q * 2) * KD);
    }
    __syncthreads();
    bf16x8 qf[4][8];
#pragma unroll
    for (int m = 0; m < 4; ++m)
#pragma unroll
        for (int k = 0; k < 8; ++k)
            qf[m][k] = *(const bf16x8*)&smem[(size_t)(wr * 64 + m * 16 + l15) * KD + k * 32 + l16 * 8];
    __syncthreads();

    float mrun[4][4], drun[4][4];
#pragma unroll
    for (int m = 0; m < 4; ++m)
#pragma unroll
        for (int r = 0; r < 4; ++r) { mrun[m][r] = -3e38f; drun[m][r] = 0.f; }

    const int t0 = chunk * CHUNK_TILES;
    const int colb_base = wc * 32 + l15;

    // ================= pass 1: stats =================
    for (int t = t0; t < t0 + CHUNK_TILES; ++t) {
        {
            const u16* ksrc = K + (size_t)(t * 64 + wid * 16 + (lane >> 5)) * KD + (lane & 31) * 8;
            u16* kdst = smem + (size_t)(wid * 16) * KD;
#pragma unroll
            for (int q = 0; q < 8; ++q)
                GLOAD16(ksrc + (size_t)(q * 2) * KD, kdst + (q * 2) * KD);
        }
        __syncthreads();
        f32x4 acc[4][2];
#pragma unroll
        for (int m = 0; m < 4; ++m)
#pragma unroll
            for (int n = 0; n < 2; ++n) acc[m][n] = (f32x4){0.f, 0.f, 0.f, 0.f};
#pragma unroll
        for (int k = 0; k < 8; ++k) {
            bf16x8 bfr[2];
#pragma unroll
            for (int n = 0; n < 2; ++n)
                bfr[n] = *(const bf16x8*)&smem[(size_t)(wc * 32 + n * 16 + l15) * KD + k * 32 + l16 * 8];
#pragma unroll
            for (int m = 0; m < 4; ++m)
#pragma unroll
                for (int n = 0; n < 2; ++n)
                    acc[m][n] = __builtin_amdgcn_mfma_f32_16x16x32_bf16(qf[m][k], bfr[n], acc[m][n], 0, 0, 0);
        }
        const int col0 = t * 64 + colb_base;
        const bool v0 = col0 < L_TOT, v1 = col0 + 16 < L_TOT;
#pragma unroll
        for (int m = 0; m < 4; ++m)
#pragma unroll
            for (int r = 0; r < 4; ++r) {
                float s0 = v0 ? acc[m][0][r] : -3e38f;
                float s1 = v1 ? acc[m][1][r] : -3e38f;
                float tmx = fmaxf(s0, s1);
                float mnew = fmaxf(mrun[m][r], tmx);
                float sc = __expf(mrun[m][r] - mnew);
                float ss = (v0 ? __expf(acc[m][0][r] - mnew) : 0.f)
                         + (v1 ? __expf(acc[m][1][r] - mnew) : 0.f);
                drun[m][r] = drun[m][r] * sc + ss;
                mrun[m][r] = mnew;
            }
        __syncthreads();
    }

#pragma unroll
    for (int m = 0; m < 4; ++m)
#pragma unroll
        for (int r = 0; r < 4; ++r) {
            float mv = mrun[m][r], dv = drun[m][r];
#pragma unroll
            for (int st = 1; st <= 8; st <<= 1) {
                float mo = __shfl_xor(mv, st);
                float dn = __shfl_xor(dv, st);
                float mn = fmaxf(mv, mo);
                dv = dv * __expf(mv - mn) + dn * __expf(mo - mn);
                mv = mn;
            }
            mrun[m][r] = mv; drun[m][r] = dv;
        }
    if (l15 == 0) {
#pragma unroll
        for (int m = 0; m < 4; ++m)
#pragma unroll
            for (int r = 0; r < 4; ++r) {
                int row = wr * 64 + m * 16 + l16 * 4 + r;
                sm_m[wc][row] = mrun[m][r];
                sm_d[wc][row] = drun[m][r];
            }
    }
    __syncthreads();
#pragma unroll
    for (int m = 0; m < 4; ++m)
#pragma unroll
        for (int r = 0; r < 4; ++r) {
            int row = wr * 64 + m * 16 + l16 * 4 + r;
            float m0 = sm_m[0][row], m1 = sm_m[1][row];
            float d0 = sm_d[0][row], d1 = sm_d[1][row];
            float mf = fmaxf(m0, m1);
            mrun[m][r] = mf;
            drun[m][r] = d0 * __expf(m0 - mf) + d1 * __expf(m1 - mf);
        }
    if (wc == 0 && l15 == 0) {
#pragma unroll
        for (int m = 0; m < 4; ++m)
#pragma unroll
            for (int r = 0; r < 4; ++r) {
                int row = wr * 64 + m * 16 + l16 * 4 + r;
                size_t o = (size_t)(chunk * 4 + b) * HW + bm + row;
                mC[o] = mrun[m][r];
                dC[o] = drun[m][r];
            }
    }
    __syncthreads();

    // ================= pass 2: recompute + write A =================
    for (int t = t0; t < t0 + CHUNK_TILES; ++t) {
        {
            const u16* ksrc = K + (size_t)(t * 64 + wid * 16 + (lane >> 5)) * KD + (lane & 31) * 8;
            u16* kdst = smem + (size_t)(wid * 16) * KD;
#pragma unroll
            for (int q = 0; q < 8; ++q)
                GLOAD16(ksrc + (size_t)(q * 2) * KD, kdst + (q * 2) * KD);
        }
        __syncthreads();
        f32x4 acc[4][2];
#pragma unroll
        for (int m = 0; m < 4; ++m)
#pragma unroll
            for (int n = 0; n < 2; ++n) acc[m][n] = (f32x4){0.f, 0.f, 0.f, 0.f};
#pragma unroll
        for (int k = 0; k < 8; ++k) {
            bf16x8 bfr[2];
#pragma unroll
            for (int n = 0; n < 2; ++n)
                bfr[n] = *(const bf16x8*)&smem[(size_t)(wc * 32 + n * 16 + l15) * KD + k * 32 + l16 * 8];
#pragma unroll
            for (int m = 0; m < 4; ++m)
#pragma unroll
                for (int n = 0; n < 2; ++n)
                    acc[m][n] = __builtin_amdgcn_mfma_f32_16x16x32_bf16(qf[m][k], bfr[n], acc[m][n], 0, 0, 0);
        }
        const int col0 = t * 64 + colb_base;
#pragma unroll
        for (int m = 0; m < 4; ++m) {
            const int row = bm + wr * 64 + m * 16 + l16 * 4;
#pragma unroll
            for (int n = 0; n < 2; ++n) {
                const int col = col0 + n * 16;
                const bool vld = col < L_TOT;
#pragma unroll
                for (int r = 0; r < 4; ++r) {
                    float w = vld ? __expf(acc[m][n][r] - mrun[m][r]) : 0.f;
                    A[(size_t)(row + r) * L_PAD + col] = f2b(w);
                }
            }
        }
        __syncthreads();
    }
}

// --------------------------- combine chunk stats ---------------------------
__global__ void combine_stats(const float* __restrict__ mC, const float* __restrict__ dC,
                              float* __restrict__ fac) {
    int idx = blockIdx.x * 256 + threadIdx.x;
    if (idx >= 4 * HW) return;
    int b = idx / HW, p = idx % HW;
    float m[NCHUNK], d[NCHUNK];
#pragma unroll
    for (int c = 0; c < NCHUNK; ++c) {
        size_t o = (size_t)(c * 4 + b) * HW + p;
        m[c] = mC[o]; d[c] = dC[o];
    }
    float mf = m[0];
#pragma unroll
    for (int c = 1; c < NCHUNK; ++c) mf = fmaxf(mf, m[c]);
    float w[NCHUNK], df = 0.f;
#pragma unroll
    for (int c = 0; c < NCHUNK; ++c) { w[c] = __expf(m[c] - mf); df += d[c] * w[c]; }
    float inv = 1.0f / df;
#pragma unroll
    for (int c = 0; c < NCHUNK; ++c) fac[(size_t)(c * 4 + b) * HW + p] = w[c] * inv;
}

// --------------------------- GEMM2: Zt_z[j][pp] = VT_chunk . A_chunk^T -----
// grid (8, 144): z = bx + 8*(by/72); within = by%72: mt = within&3 (JD tile),
// nt = within>>2 (HW tile).  C bf16 [16][JD][HW].
__global__ __launch_bounds__(256) void gemm2_kernel(
    const u16* __restrict__ VT0, const u16* __restrict__ A0, u16* __restrict__ C0) {
    __shared__ u16 As[128 * 64];
    __shared__ u16 Bs[128 * 64];
    const int bx = blockIdx.x, by = blockIdx.y;
    const int within = by % 72, zq = by / 72;
    const int mt = within & 3, nt = within >> 2;
    const int z = bx + 8 * zq;
    const int batch = z >> 2, chunk = z & 3;
    const u16* A = VT0 + (size_t)batch * JD * L_PAD + chunk * (CHUNK_TILES * 64);
    const u16* B = A0 + (size_t)batch * HW * L_PAD + chunk * (CHUNK_TILES * 64);
    u16* C = C0 + (size_t)z * JD * HW;
    const int bm = mt * 128, bn = nt * 128;
    const int tid = threadIdx.x, lane = tid & 63, wid = tid >> 6;
    const int wr = wid >> 1, wc = wid & 1;
    const int srow = lane >> 3;
    const int scol = (lane & 7) * 8;

    f32x4 acc[4][4];
#pragma unroll
    for (int i = 0; i < 4; ++i)
#pragma unroll
        for (int j = 0; j < 4; ++j) acc[i][j] = (f32x4){0.f, 0.f, 0.f, 0.f};

    const u16* aG = A + (size_t)(bm + wid * 32 + srow) * L_PAD + scol;
    const u16* bG = B + (size_t)(bn + wid * 32 + srow) * L_PAD + scol;
    u16* aL = As + wid * 32 * 64;
    u16* bL = Bs + wid * 32 * 64;

    for (int t = 0; t < CHUNK_TILES; ++t) {
#pragma unroll
        for (int q = 0; q < 4; ++q) {
            GLOAD16(aG + (size_t)q * 8 * L_PAD, aL + q * 8 * 64);
            GLOAD16(bG + (size_t)q * 8 * L_PAD, bL + q * 8 * 64);
        }
        aG += 64;
        bG += 64;
        __syncthreads();
#pragma unroll
        for (int kc = 0; kc < 64; kc += 32) {
            bf16x8 af[4], bf[4];
#pragma unroll
            for (int m = 0; m < 4; ++m)
                af[m] = *(const bf16x8*)&As[(wr * 64 + m * 16 + (lane & 15)) * 64 + kc + (lane >> 4) * 8];
#pragma unroll
            for (int n = 0; n < 4; ++n)
                bf[n] = *(const bf16x8*)&Bs[(wc * 64 + n * 16 + (lane & 15)) * 64 + kc + (lane >> 4) * 8];
#pragma unroll
            for (int m = 0; m < 4; ++m)
#pragma unroll
                for (int n = 0; n < 4; ++n)
                    acc[m][n] = __builtin_amdgcn_mfma_f32_16x16x32_bf16(af[m], bf[n], acc[m][n], 0, 0, 0);
        }
        __syncthreads();
    }
    const int crow0 = bm + wr * 64 + (lane >> 4) * 4;
    const int ccol = bn + wc * 64 + (lane & 15);
#pragma unroll
    for (int m = 0; m < 4; ++m)
#pragma unroll
        for (int n = 0; n < 4; ++n)
#pragma unroll
            for (int r = 0; r < 4; ++r)
                C[(size_t)(crow0 + m * 16 + r) * HW + ccol + n * 16] = f2b(acc[m][n][r]);
}

// --------------------------- chunk reduce (weighted sum over chunks) -------
// Zred[b][j][pp] = sum_ch fac[(ch*4+b)*HW+pp] * Zt[(b*4+ch)][j][pp]
__global__ void chunk_reduce(const u16* __restrict__ Zt, const float* __restrict__ fac,
                             u16* __restrict__ Zred) {
    int idx = blockIdx.x * 256 + threadIdx.x;
    int total = 4 * JD * HW / 8;
    if (idx >= total) return;
    int e8 = idx * 8;
    int pp = e8 % HW;
    int row = e8 / HW;          // row = b*JD + j
    int b = row / JD;
    float s[8] = {};
#pragma unroll
    for (int ch = 0; ch < NCHUNK; ++ch) {
        const float* fp = fac + (size_t)(ch * 4 + b) * HW + pp;
        bf16x8 zv = *(const bf16x8*)&Zt[((size_t)(b * 4 + ch) * JD + (row % JD)) * HW + pp];
#pragma unroll
        for (int u = 0; u < 8; ++u)
            s[u] += fp[u] * b2f((u16)zv[u]);
    }
    bf16x8 o;
#pragma unroll
    for (int u = 0; u < 8; ++u) o[u] = (short)f2b(s[u]);
    *(bf16x8*)&Zred[(size_t)row * HW + pp] = o;
}

// --------------------------- final: 9-tap gather + residual ----------------
__global__ void final_kernel(const u16* __restrict__ Zred, const float* __restrict__ x,
                             float* __restrict__ out) {
    int idx = blockIdx.x * 256 + threadIdx.x;
    if (idx >= 4 * 50 * HW) return;
    int p = idx % HW;
    int t = idx / HW;
    int c = t % 50;
    int b = t / 50;
    int y = p / 48, xx = p % 48;
    const u16* Zb = Zred + (size_t)b * JD * HW;
    float s = 0.f;
#pragma unroll
    for (int ky = 0; ky < 3; ++ky) {
        int yy = y + ky - 1;
        if (yy < 0 || yy >= 48) continue;
#pragma unroll
        for (int kx = 0; kx < 3; ++kx) {
            int xv = xx + kx - 1;
            if (xv < 0 || xv >= 48) continue;
            int pp = yy * 48 + xv;
            int j = c * 9 + (2 - ky) * 3 + (2 - kx);
            s += b2f(Zb[(size_t)j * HW + pp]);
        }
    }
    size_t o = ((size_t)b * 50 + c) * HW + p;
    out[o] = x[o] + 0.25f * s;
}

// ---------------------------------------------------------------------------
extern "C" void kernel_launch(void* const* d_in, const int* in_sizes, int n_in,
                              void* d_out, int out_size, void* d_ws, size_t ws_size,
                              hipStream_t stream) {
    const float* x       = (const float*)d_in[0];
    const float* w_base  = (const float*)d_in[1];
    const float* b_base  = (const float*)d_in[2];
    const float* a_base  = (const float*)d_in[3];
    const float* w_match = (const float*)d_in[4];
    const float* b_match = (const float*)d_in[5];
    const float* a_match = (const float*)d_in[6];
    const float* w_asm   = (const float*)d_in[7];
    const float* b_asm   = (const float*)d_in[8];
    const float* a_asm   = (const float*)d_in[9];
    float* out = (float*)d_out;
    float* ws = (float*)d_ws;
    (void)in_sizes; (void)n_in; (void)out_size; (void)ws_size;

    const int hs[5] = {48, 43, 38, 33, 28};
    const int loff[6] = {0, 2304, 4153, 5597, 6686, 7470};

    // ---- builder scratch (aliases head of A; dead before attn_score) ----
    size_t off = 0;
    auto alloc = [&](size_t n) { size_t o = off; off += (n + 63) & ~(size_t)63; return o; };
    size_t o_wm = alloc(142 * 48);
    size_t o_rtmp = alloc((size_t)200 * 43 * 48);
    size_t o_ref[5];
    o_ref[0] = 0;
    for (int si = 1; si < 5; ++si) o_ref[si] = alloc((size_t)200 * hs[si] * hs[si]);
    size_t o_base = alloc((size_t)200 * L_TOT);
    size_t o_refm = alloc((size_t)100 * L_TOT);
    size_t o_mb = alloc((size_t)100 * HW);
    size_t o_norms = alloc((size_t)4 * L_TOT);

    // ---- persistent layout (floats) ----
    size_t o_A = 0;                                       // bf16 [4][HW][L_PAD]
    size_t o_Q = (size_t)4 * HW * L_PAD / 2;
    size_t o_K = o_Q + (size_t)4 * HW * KD / 2;
    size_t o_VT = o_K + (size_t)4 * L_PAD * KD / 2;
    size_t o_Z = o_VT + (size_t)4 * JD * L_PAD / 2;       // bf16 [16][JD][HW]
    size_t o_mc = o_Z + (size_t)16 * JD * HW / 2;
    size_t o_dc = o_mc + (size_t)16 * HW;
    size_t o_fac = o_dc + (size_t)16 * HW;
    size_t o_zred = o_fac + (size_t)16 * HW;              // bf16 [4][JD][HW]

    u16* Qb = (u16*)(ws + o_Q);
    u16* Kb = (u16*)(ws + o_K);
    u16* VTb = (u16*)(ws + o_VT);
    u16* Ab = (u16*)(ws + o_A);
    u16* Zb = (u16*)(ws + o_Z);
    u16* Zrb = (u16*)(ws + o_zred);

    // ---- resizes ----
    resize_weights_kernel<<<1, 256, 0, stream>>>(ws + o_wm);
    const int woff[5] = {0, 0, 43 * 48, (43 + 38) * 48, (43 + 38 + 33) * 48};
    for (int si = 1; si < 5; ++si) {
        int osz = hs[si];
        int n1 = 200 * osz * 48;
        resize_h<<<(n1 + 255) / 256, 256, 0, stream>>>(x, ws + o_wm + woff[si], ws + o_rtmp, osz);
        int n2 = 200 * osz * osz;
        resize_w<<<(n2 + 255) / 256, 256, 0, stream>>>(ws + o_rtmp, ws + o_wm + woff[si],
                                                       ws + o_ref[si], osz);
    }
    // ---- convs ----
    for (int si = 0; si < 5; ++si) {
        int P = hs[si] * hs[si];
        const float* in = (si == 0) ? x : ws + o_ref[si];
        int nb = 4 * 50 * P;
        conv1x1_prelu<<<(nb + 255) / 256, 256, 0, stream>>>(
            in, w_asm, b_asm, a_asm, ws + o_base + (size_t)200 * loff[si], P, 50);
        int nm = 4 * 25 * P;
        conv1x1_prelu<<<(nm + 255) / 256, 256, 0, stream>>>(
            in, w_match, b_match, a_match, ws + o_refm + (size_t)100 * loff[si], P, 25);
    }
    {
        int nmb = 4 * 25 * HW;
        conv1x1_prelu<<<(nmb + 255) / 256, 256, 0, stream>>>(x, w_base, b_base, a_base,
                                                             ws + o_mb, HW, 25);
    }
    // ---- operand builders ----
    {
        int n = 4 * HW * KD;
        q_build<<<(n + 255) / 256, 256, 0, stream>>>(ws + o_mb, Qb);
    }
    {
        int n = 4 * L_TOT;
        norms_kernel<<<(n + 255) / 256, 256, 0, stream>>>(ws + o_refm, ws + o_norms);
    }
    {
        int n = 4 * L_PAD * KD;
        kt_build<<<(n + 255) / 256, 256, 0, stream>>>(ws + o_refm, ws + o_norms, Kb);
    }
    {
        int n = 4 * JD * L_PAD;
        v_build<<<(n + 255) / 256, 256, 0, stream>>>(ws + o_base, VTb);
    }

    // ---- fused score + softmax ----
    {
        dim3 g(8, 36, 1);
        attn_score<<<g, 256, 0, stream>>>(Qb, Kb, Ab, ws + o_mc, ws + o_dc);
    }
    combine_stats<<<(4 * HW + 255) / 256, 256, 0, stream>>>(ws + o_mc, ws + o_dc, ws + o_fac);

    // ---- GEMM2 (swapped: Zt[j][pp]) ----
    {
        dim3 g(8, 144, 1);
        gemm2_kernel<<<g, 256, 0, stream>>>(VTb, Ab, Zb);
    }
    // ---- weighted chunk reduction ----
    {
        int n = 4 * JD * HW / 8;
        chunk_reduce<<<(n + 255) / 256, 256, 0, stream>>>(Zb, ws + o_fac, Zrb);
    }
    final_kernel<<<(4 * 50 * HW + 255) / 256, 256, 0, stream>>>(Zrb, x, out);
}

// Round 5
// 558.702 us; speedup vs baseline: 4.2929x; 1.0693x over previous
//
#include <hip/hip_runtime.h>
#include <hip/hip_bf16.h>
#include <math.h>

// ---------------------------------------------------------------------------
// RFDN panet attention, MI355X.  Round 5:
//   attn_score rework: 64-row M-tiles (576 blocks, 4 blocks/CU), LDS
//   XOR-swizzle (unit ^= row&7, source-side pre-swizzle for global_load_lds),
//   pass1 = max only, denominator accumulated in pass2.
//   Rest unchanged from round 4.
// ---------------------------------------------------------------------------

#define L_TOT 7470
#define L_PAD 7680   // 64 * 120, 4 chunks of 1920
#define NCHUNK 4
#define CHUNK_TILES 30   // 64-key tiles per chunk
#define KD    256    // padded 225
#define JD    512    // padded 450 = 50*3*3
#define HW    2304   // 48*48

typedef unsigned short u16;
typedef __attribute__((ext_vector_type(8))) short bf16x8;
typedef __attribute__((ext_vector_type(4))) float f32x4;

__device__ inline u16 f2b(float f) {
    __hip_bfloat16 h = __float2bfloat16(f);
    return __builtin_bit_cast(u16, h);
}
__device__ inline float b2f(u16 u) {
    __hip_bfloat16 h = __builtin_bit_cast(__hip_bfloat16, u);
    return __bfloat162float(h);
}

__constant__ int c_hs[5]   = {48, 43, 38, 33, 28};
__constant__ int c_loff[6] = {0, 2304, 4153, 5597, 6686, 7470};

__device__ inline void decode_l(int l, int& si, int& hs, int& pos) {
    si = 0;
#pragma unroll
    for (int s = 0; s < 4; ++s)
        if (l >= c_loff[s + 1]) si = s + 1;
    pos = l - c_loff[si];
    hs = c_hs[si];
}

#define GLOAD16(g, l) __builtin_amdgcn_global_load_lds(                          \
        (__attribute__((address_space(1))) const void*)(g),                      \
        (__attribute__((address_space(3))) void*)(l), 16, 0, 0)

// --------------------------- bicubic resize --------------------------------
__global__ void resize_weights_kernel(float* __restrict__ wmall) {
    int r = blockIdx.x * blockDim.x + threadIdx.x;
    if (r >= 142) return;
    int sizes[4] = {43, 38, 33, 28};
    int si = 0, i = r, woffs = 0;
    for (si = 0; si < 4; ++si) {
        if (i < sizes[si]) break;
        i -= sizes[si];
        woffs += sizes[si] * 48;
    }
    int osz = sizes[si];
    float inv_scale = 48.0f / (float)osz;
    float kscale = inv_scale;
    float sample_f = ((float)i + 0.5f) * inv_scale - 0.5f;
    float w[48];
    float tot = 0.f;
    for (int j = 0; j < 48; ++j) {
        float t = fabsf(sample_f - (float)j) / kscale;
        float v;
        if (t >= 2.f)       v = 0.f;
        else if (t >= 1.f)  v = ((-0.5f * t + 2.5f) * t - 4.f) * t + 2.f;
        else                v = ((1.5f * t - 2.5f) * t) * t + 1.f;
        w[j] = v;
        tot += v;
    }
    float invt = 1.f / tot;
    for (int j = 0; j < 48; ++j) wmall[woffs + i * 48 + j] = w[j] * invt;
}

__global__ void resize_h(const float* __restrict__ in, const float* __restrict__ wm,
                         float* __restrict__ tmp, int osz) {
    int idx = blockIdx.x * 256 + threadIdx.x;
    int total = 200 * osz * 48;
    if (idx >= total) return;
    int xi = idx % 48;
    int t = idx / 48;
    int yo = t % osz;
    int bc = t / osz;
    const float* wr = wm + yo * 48;
    const float* ip = in + (size_t)bc * 2304 + xi;
    float s = 0.f;
#pragma unroll
    for (int yi = 0; yi < 48; ++yi) s += wr[yi] * ip[yi * 48];
    tmp[idx] = s;
}

__global__ void resize_w(const float* __restrict__ tmp, const float* __restrict__ wm,
                         float* __restrict__ refout, int osz) {
    int idx = blockIdx.x * 256 + threadIdx.x;
    int total = 200 * osz * osz;
    if (idx >= total) return;
    int xo = idx % osz;
    int t = idx / osz;
    int yo = t % osz;
    int bc = t / osz;
    const float* wr = wm + xo * 48;
    const float* ip = tmp + ((size_t)bc * osz + yo) * 48;
    float s = 0.f;
#pragma unroll
    for (int xi = 0; xi < 48; ++xi) s += wr[xi] * ip[xi];
    refout[idx] = s;
}

// --------------------------- 1x1 conv + PReLU ------------------------------
__global__ void conv1x1_prelu(const float* __restrict__ in, const float* __restrict__ w,
                              const float* __restrict__ bias, const float* __restrict__ a,
                              float* __restrict__ outp, int P, int Co) {
    int idx = blockIdx.x * 256 + threadIdx.x;
    int total = 4 * Co * P;
    if (idx >= total) return;
    int p = idx % P;
    int t = idx / P;
    int co = t % Co;
    int b = t / Co;
    const float* ip = in + (size_t)b * 50 * P + p;
    const float* wr = w + co * 50;
    float s = bias[co];
#pragma unroll
    for (int ci = 0; ci < 50; ++ci) s += wr[ci] * ip[(size_t)ci * P];
    float av = a[0];
    outp[idx] = (s >= 0.f) ? s : av * s;
}

// --------------------------- builders (bf16) -------------------------------
__global__ void q_build(const float* __restrict__ mb, u16* __restrict__ Q) {
    int idx = blockIdx.x * 256 + threadIdx.x;
    if (idx >= 4 * HW * KD) return;
    int k = idx % KD;
    int t = idx / KD;
    int p = t % HW;
    int b = t / HW;
    float v = 0.f;
    if (k < 225) {
        int c = k / 9, r = k % 9, ky = r / 3, kx = r % 3;
        int y = p / 48, xx = p % 48;
        int yy = y + ky - 1, xv = xx + kx - 1;
        if (yy >= 0 && yy < 48 && xv >= 0 && xv < 48)
            v = mb[((size_t)(b * 25 + c)) * HW + yy * 48 + xv];
    }
    Q[idx] = f2b(v);
}

__global__ void norms_kernel(const float* __restrict__ refm_all, float* __restrict__ norms) {
    int idx = blockIdx.x * 256 + threadIdx.x;
    if (idx >= 4 * L_TOT) return;
    int l = idx % L_TOT;
    int b = idx / L_TOT;
    int si, hs, pos;
    decode_l(l, si, hs, pos);
    int P = hs * hs;
    int ly = pos / hs, lx = pos % hs;
    const float* rb = refm_all + (size_t)100 * c_loff[si] + (size_t)(b * 25) * P;
    float ss = 0.f;
    for (int c = 0; c < 25; ++c) {
        const float* rc = rb + (size_t)c * P;
#pragma unroll
        for (int ky = 0; ky < 3; ++ky) {
#pragma unroll
            for (int kx = 0; kx < 3; ++kx) {
                int yy = ly + ky - 1, xv = lx + kx - 1;
                if (yy >= 0 && yy < hs && xv >= 0 && xv < hs) {
                    float v = rc[yy * hs + xv];
                    ss += v * v;
                }
            }
        }
    }
    norms[idx] = 10.0f / fmaxf(sqrtf(ss), 1e-4f);  // SM_SCALE folded
}

__global__ void kt_build(const float* __restrict__ refm_all, const float* __restrict__ norms,
                         u16* __restrict__ K) {
    int idx = blockIdx.x * 256 + threadIdx.x;
    if (idx >= 4 * L_PAD * KD) return;
    int k = idx % KD;
    int t = idx / KD;
    int l = t % L_PAD;
    int b = t / L_PAD;
    float v = 0.f;
    if (k < 225 && l < L_TOT) {
        int si, hs, pos;
        decode_l(l, si, hs, pos);
        int P = hs * hs;
        int ly = pos / hs, lx = pos % hs;
        int c = k / 9, r = k % 9, ky = r / 3, kx = r % 3;
        int yy = ly + ky - 1, xv = lx + kx - 1;
        if (yy >= 0 && yy < hs && xv >= 0 && xv < hs)
            v = refm_all[(size_t)100 * c_loff[si] + ((size_t)(b * 25 + c)) * P + yy * hs + xv]
                * norms[(size_t)b * L_TOT + l];
    }
    K[idx] = f2b(v);
}

__global__ void v_build(const float* __restrict__ base_all, u16* __restrict__ VT) {
    int idx = blockIdx.x * 256 + threadIdx.x;
    if (idx >= 4 * JD * L_PAD) return;
    int l = idx % L_PAD;
    int t = idx / L_PAD;
    int j = t % JD;
    int b = t / JD;
    float v = 0.f;
    if (j < 450 && l < L_TOT) {
        int si, hs, pos;
        decode_l(l, si, hs, pos);
        int P = hs * hs;
        int ly = pos / hs, lx = pos % hs;
        int c = j / 9, r = j % 9, ky = r / 3, kx = r % 3;
        int yy = ly + ky - 1, xv = lx + kx - 1;
        if (yy >= 0 && yy < hs && xv >= 0 && xv < hs)
            v = base_all[(size_t)200 * c_loff[si] + ((size_t)(b * 50 + c)) * P + yy * hs + xv];
    }
    VT[idx] = f2b(v);
}

// --------------------------- fused score + softmax -------------------------
// grid (8, 72): z16 = bx + 8*(by/36)  (b = z16>>2, chunk = z16&3; XCD-pinned),
//               mt = by%36 -> bm = mt*64 (64 query rows per block).
// LDS tile [64][KD] with 16B-unit XOR swizzle: unit' = unit ^ (row&7).
// global_load_lds keeps a LINEAR dest; the swizzle is applied to the per-lane
// GLOBAL source column, and again on every fragment read (rule #21).
// Pass1: row max only. Pass2: write A = exp(S-m) and accumulate denominator.
__global__ __launch_bounds__(256, 4) void attn_score(
    const u16* __restrict__ Qg, const u16* __restrict__ Kg,
    u16* __restrict__ Ag, float* __restrict__ mC, float* __restrict__ dC) {
    __shared__ u16 smem[64 * KD];         // 32 KB: Q staging, then K tiles
    __shared__ float sm_m[2][64], sm_d[2][64];
    const int bx = blockIdx.x, by = blockIdx.y;
    const int mt = by % 36, zq = by / 36;
    const int z16 = bx + 8 * zq;
    const int b = z16 >> 2, chunk = z16 & 3;
    const int bm = mt * 64;
    const u16* Q = Qg + (size_t)b * HW * KD;
    const u16* K = Kg + (size_t)b * L_PAD * KD;
    u16* A = Ag + (size_t)b * HW * L_PAD;
    const int tid = threadIdx.x, lane = tid & 63, wid = tid >> 6;
    const int wr = wid >> 1, wc = wid & 1;
    const int l15 = lane & 15, l16 = lane >> 4;
    const int l7 = lane & 7;
    const int r_lo = lane >> 5;           // staging: row parity within pair
    const int u_dst = lane & 31;          // staging: dest 16B unit

    // ---- stage Q tile (64 x KD) swizzled, load persistent fragments ----
    {
        const u16* qrow = Q + (size_t)(bm + wid * 16 + r_lo) * KD;
        u16* qdst = smem + (size_t)(wid * 16) * KD;
#pragma unroll
        for (int q = 0; q < 8; ++q) {
            int sw = (u_dst ^ ((q * 2 + r_lo) & 7)) * 8;
            GLOAD16(qrow + (size_t)(q * 2) * KD + sw, qdst + (q * 2) * KD);
        }
    }
    __syncthreads();
    bf16x8 qf[2][8];
#pragma unroll
    for (int m = 0; m < 2; ++m)
#pragma unroll
        for (int k = 0; k < 8; ++k)
            qf[m][k] = *(const bf16x8*)&smem[(size_t)(wr * 32 + m * 16 + l15) * KD
                                             + (((k * 4 + l16) ^ l7) * 8)];
    __syncthreads();

    float mrun[2][4];
#pragma unroll
    for (int m = 0; m < 2; ++m)
#pragma unroll
        for (int r = 0; r < 4; ++r) mrun[m][r] = -3e38f;

    const int t0 = chunk * CHUNK_TILES;
    const int colb_base = wc * 32 + l15;

    // ================= pass 1: row max =================
    for (int t = t0; t < t0 + CHUNK_TILES; ++t) {
        {
            const u16* krow = K + (size_t)(t * 64 + wid * 16 + r_lo) * KD;
            u16* kdst = smem + (size_t)(wid * 16) * KD;
#pragma unroll
            for (int q = 0; q < 8; ++q) {
                int sw = (u_dst ^ ((q * 2 + r_lo) & 7)) * 8;
                GLOAD16(krow + (size_t)(q * 2) * KD + sw, kdst + (q * 2) * KD);
            }
        }
        __syncthreads();
        f32x4 acc[2][2];
#pragma unroll
        for (int m = 0; m < 2; ++m)
#pragma unroll
            for (int n = 0; n < 2; ++n) acc[m][n] = (f32x4){0.f, 0.f, 0.f, 0.f};
#pragma unroll
        for (int k = 0; k < 8; ++k) {
            bf16x8 bfr[2];
#pragma unroll
            for (int n = 0; n < 2; ++n)
                bfr[n] = *(const bf16x8*)&smem[(size_t)(wc * 32 + n * 16 + l15) * KD
                                               + (((k * 4 + l16) ^ l7) * 8)];
#pragma unroll
            for (int m = 0; m < 2; ++m)
#pragma unroll
                for (int n = 0; n < 2; ++n)
                    acc[m][n] = __builtin_amdgcn_mfma_f32_16x16x32_bf16(qf[m][k], bfr[n], acc[m][n], 0, 0, 0);
        }
        const int col0 = t * 64 + colb_base;
        const bool v0 = col0 < L_TOT, v1 = col0 + 16 < L_TOT;
#pragma unroll
        for (int m = 0; m < 2; ++m)
#pragma unroll
            for (int r = 0; r < 4; ++r) {
                float s0 = v0 ? acc[m][0][r] : -3e38f;
                float s1 = v1 ? acc[m][1][r] : -3e38f;
                mrun[m][r] = fmaxf(mrun[m][r], fmaxf(s0, s1));
            }
        __syncthreads();
    }

    // ---- combine row max: butterfly over l15, then across wc via LDS ----
#pragma unroll
    for (int m = 0; m < 2; ++m)
#pragma unroll
        for (int r = 0; r < 4; ++r) {
            float mv = mrun[m][r];
#pragma unroll
            for (int st = 1; st <= 8; st <<= 1)
                mv = fmaxf(mv, __shfl_xor(mv, st));
            mrun[m][r] = mv;
        }
    if (l15 == 0) {
#pragma unroll
        for (int m = 0; m < 2; ++m)
#pragma unroll
            for (int r = 0; r < 4; ++r)
                sm_m[wc][wr * 32 + m * 16 + l16 * 4 + r] = mrun[m][r];
    }
    __syncthreads();
#pragma unroll
    for (int m = 0; m < 2; ++m)
#pragma unroll
        for (int r = 0; r < 4; ++r) {
            int row = wr * 32 + m * 16 + l16 * 4 + r;
            mrun[m][r] = fmaxf(sm_m[0][row], sm_m[1][row]);
        }

    // ================= pass 2: write A + accumulate denominator =================
    float drun[2][4];
#pragma unroll
    for (int m = 0; m < 2; ++m)
#pragma unroll
        for (int r = 0; r < 4; ++r) drun[m][r] = 0.f;

    for (int t = t0; t < t0 + CHUNK_TILES; ++t) {
        {
            const u16* krow = K + (size_t)(t * 64 + wid * 16 + r_lo) * KD;
            u16* kdst = smem + (size_t)(wid * 16) * KD;
#pragma unroll
            for (int q = 0; q < 8; ++q) {
                int sw = (u_dst ^ ((q * 2 + r_lo) & 7)) * 8;
                GLOAD16(krow + (size_t)(q * 2) * KD + sw, kdst + (q * 2) * KD);
            }
        }
        __syncthreads();
        f32x4 acc[2][2];
#pragma unroll
        for (int m = 0; m < 2; ++m)
#pragma unroll
            for (int n = 0; n < 2; ++n) acc[m][n] = (f32x4){0.f, 0.f, 0.f, 0.f};
#pragma unroll
        for (int k = 0; k < 8; ++k) {
            bf16x8 bfr[2];
#pragma unroll
            for (int n = 0; n < 2; ++n)
                bfr[n] = *(const bf16x8*)&smem[(size_t)(wc * 32 + n * 16 + l15) * KD
                                               + (((k * 4 + l16) ^ l7) * 8)];
#pragma unroll
            for (int m = 0; m < 2; ++m)
#pragma unroll
                for (int n = 0; n < 2; ++n)
                    acc[m][n] = __builtin_amdgcn_mfma_f32_16x16x32_bf16(qf[m][k], bfr[n], acc[m][n], 0, 0, 0);
        }
        const int col0 = t * 64 + colb_base;
#pragma unroll
        for (int m = 0; m < 2; ++m) {
            const int row = bm + wr * 32 + m * 16 + l16 * 4;
#pragma unroll
            for (int n = 0; n < 2; ++n) {
                const int col = col0 + n * 16;
                const bool vld = col < L_TOT;
#pragma unroll
                for (int r = 0; r < 4; ++r) {
                    float w = vld ? __expf(acc[m][n][r] - mrun[m][r]) : 0.f;
                    drun[m][r] += w;
                    A[(size_t)(row + r) * L_PAD + col] = f2b(w);
                }
            }
        }
        __syncthreads();
    }

    // ---- reduce denominator: butterfly add over l15, then across wc ----
#pragma unroll
    for (int m = 0; m < 2; ++m)
#pragma unroll
        for (int r = 0; r < 4; ++r) {
            float dv = drun[m][r];
#pragma unroll
            for (int st = 1; st <= 8; st <<= 1)
                dv += __shfl_xor(dv, st);
            drun[m][r] = dv;
        }
    if (l15 == 0) {
#pragma unroll
        for (int m = 0; m < 2; ++m)
#pragma unroll
            for (int r = 0; r < 4; ++r)
                sm_d[wc][wr * 32 + m * 16 + l16 * 4 + r] = drun[m][r];
    }
    __syncthreads();
    if (wc == 0 && l15 == 0) {
#pragma unroll
        for (int m = 0; m < 2; ++m)
#pragma unroll
            for (int r = 0; r < 4; ++r) {
                int row = wr * 32 + m * 16 + l16 * 4 + r;
                size_t o = (size_t)(chunk * 4 + b) * HW + bm + row;
                mC[o] = mrun[m][r];
                dC[o] = sm_d[0][row] + sm_d[1][row];
            }
    }
}

// --------------------------- combine chunk stats ---------------------------
__global__ void combine_stats(const float* __restrict__ mC, const float* __restrict__ dC,
                              float* __restrict__ fac) {
    int idx = blockIdx.x * 256 + threadIdx.x;
    if (idx >= 4 * HW) return;
    int b = idx / HW, p = idx % HW;
    float m[NCHUNK], d[NCHUNK];
#pragma unroll
    for (int c = 0; c < NCHUNK; ++c) {
        size_t o = (size_t)(c * 4 + b) * HW + p;
        m[c] = mC[o]; d[c] = dC[o];
    }
    float mf = m[0];
#pragma unroll
    for (int c = 1; c < NCHUNK; ++c) mf = fmaxf(mf, m[c]);
    float w[NCHUNK], df = 0.f;
#pragma unroll
    for (int c = 0; c < NCHUNK; ++c) { w[c] = __expf(m[c] - mf); df += d[c] * w[c]; }
    float inv = 1.0f / df;
#pragma unroll
    for (int c = 0; c < NCHUNK; ++c) fac[(size_t)(c * 4 + b) * HW + p] = w[c] * inv;
}

// --------------------------- GEMM2: Zt_z[j][pp] = VT_chunk . A_chunk^T -----
__global__ __launch_bounds__(256) void gemm2_kernel(
    const u16* __restrict__ VT0, const u16* __restrict__ A0, u16* __restrict__ C0) {
    __shared__ u16 As[128 * 64];
    __shared__ u16 Bs[128 * 64];
    const int bx = blockIdx.x, by = blockIdx.y;
    const int within = by % 72, zq = by / 72;
    const int mt = within & 3, nt = within >> 2;
    const int z = bx + 8 * zq;
    const int batch = z >> 2, chunk = z & 3;
    const u16* A = VT0 + (size_t)batch * JD * L_PAD + chunk * (CHUNK_TILES * 64);
    const u16* B = A0 + (size_t)batch * HW * L_PAD + chunk * (CHUNK_TILES * 64);
    u16* C = C0 + (size_t)z * JD * HW;
    const int bm = mt * 128, bn = nt * 128;
    const int tid = threadIdx.x, lane = tid & 63, wid = tid >> 6;
    const int wr = wid >> 1, wc = wid & 1;
    const int srow = lane >> 3;
    const int scol = (lane & 7) * 8;

    f32x4 acc[4][4];
#pragma unroll
    for (int i = 0; i < 4; ++i)
#pragma unroll
        for (int j = 0; j < 4; ++j) acc[i][j] = (f32x4){0.f, 0.f, 0.f, 0.f};

    const u16* aG = A + (size_t)(bm + wid * 32 + srow) * L_PAD + scol;
    const u16* bG = B + (size_t)(bn + wid * 32 + srow) * L_PAD + scol;
    u16* aL = As + wid * 32 * 64;
    u16* bL = Bs + wid * 32 * 64;

    for (int t = 0; t < CHUNK_TILES; ++t) {
#pragma unroll
        for (int q = 0; q < 4; ++q) {
            GLOAD16(aG + (size_t)q * 8 * L_PAD, aL + q * 8 * 64);
            GLOAD16(bG + (size_t)q * 8 * L_PAD, bL + q * 8 * 64);
        }
        aG += 64;
        bG += 64;
        __syncthreads();
#pragma unroll
        for (int kc = 0; kc < 64; kc += 32) {
            bf16x8 af[4], bf[4];
#pragma unroll
            for (int m = 0; m < 4; ++m)
                af[m] = *(const bf16x8*)&As[(wr * 64 + m * 16 + (lane & 15)) * 64 + kc + (lane >> 4) * 8];
#pragma unroll
            for (int n = 0; n < 4; ++n)
                bf[n] = *(const bf16x8*)&Bs[(wc * 64 + n * 16 + (lane & 15)) * 64 + kc + (lane >> 4) * 8];
#pragma unroll
            for (int m = 0; m < 4; ++m)
#pragma unroll
                for (int n = 0; n < 4; ++n)
                    acc[m][n] = __builtin_amdgcn_mfma_f32_16x16x32_bf16(af[m], bf[n], acc[m][n], 0, 0, 0);
        }
        __syncthreads();
    }
    const int crow0 = bm + wr * 64 + (lane >> 4) * 4;
    const int ccol = bn + wc * 64 + (lane & 15);
#pragma unroll
    for (int m = 0; m < 4; ++m)
#pragma unroll
        for (int n = 0; n < 4; ++n)
#pragma unroll
            for (int r = 0; r < 4; ++r)
                C[(size_t)(crow0 + m * 16 + r) * HW + ccol + n * 16] = f2b(acc[m][n][r]);
}

// --------------------------- chunk reduce (weighted sum over chunks) -------
__global__ void chunk_reduce(const u16* __restrict__ Zt, const float* __restrict__ fac,
                             u16* __restrict__ Zred) {
    int idx = blockIdx.x * 256 + threadIdx.x;
    int total = 4 * JD * HW / 8;
    if (idx >= total) return;
    int e8 = idx * 8;
    int pp = e8 % HW;
    int row = e8 / HW;          // row = b*JD + j
    int b = row / JD;
    float s[8] = {};
#pragma unroll
    for (int ch = 0; ch < NCHUNK; ++ch) {
        const float* fp = fac + (size_t)(ch * 4 + b) * HW + pp;
        bf16x8 zv = *(const bf16x8*)&Zt[((size_t)(b * 4 + ch) * JD + (row % JD)) * HW + pp];
#pragma unroll
        for (int u = 0; u < 8; ++u)
            s[u] += fp[u] * b2f((u16)zv[u]);
    }
    bf16x8 o;
#pragma unroll
    for (int u = 0; u < 8; ++u) o[u] = (short)f2b(s[u]);
    *(bf16x8*)&Zred[(size_t)row * HW + pp] = o;
}

// --------------------------- final: 9-tap gather + residual ----------------
__global__ void final_kernel(const u16* __restrict__ Zred, const float* __restrict__ x,
                             float* __restrict__ out) {
    int idx = blockIdx.x * 256 + threadIdx.x;
    if (idx >= 4 * 50 * HW) return;
    int p = idx % HW;
    int t = idx / HW;
    int c = t % 50;
    int b = t / 50;
    int y = p / 48, xx = p % 48;
    const u16* Zb = Zred + (size_t)b * JD * HW;
    float s = 0.f;
#pragma unroll
    for (int ky = 0; ky < 3; ++ky) {
        int yy = y + ky - 1;
        if (yy < 0 || yy >= 48) continue;
#pragma unroll
        for (int kx = 0; kx < 3; ++kx) {
            int xv = xx + kx - 1;
            if (xv < 0 || xv >= 48) continue;
            int pp = yy * 48 + xv;
            int j = c * 9 + (2 - ky) * 3 + (2 - kx);
            s += b2f(Zb[(size_t)j * HW + pp]);
        }
    }
    size_t o = ((size_t)b * 50 + c) * HW + p;
    out[o] = x[o] + 0.25f * s;
}

// ---------------------------------------------------------------------------
extern "C" void kernel_launch(void* const* d_in, const int* in_sizes, int n_in,
                              void* d_out, int out_size, void* d_ws, size_t ws_size,
                              hipStream_t stream) {
    const float* x       = (const float*)d_in[0];
    const float* w_base  = (const float*)d_in[1];
    const float* b_base  = (const float*)d_in[2];
    const float* a_base  = (const float*)d_in[3];
    const float* w_match = (const float*)d_in[4];
    const float* b_match = (const float*)d_in[5];
    const float* a_match = (const float*)d_in[6];
    const float* w_asm   = (const float*)d_in[7];
    const float* b_asm   = (const float*)d_in[8];
    const float* a_asm   = (const float*)d_in[9];
    float* out = (float*)d_out;
    float* ws = (float*)d_ws;
    (void)in_sizes; (void)n_in; (void)out_size; (void)ws_size;

    const int hs[5] = {48, 43, 38, 33, 28};
    const int loff[6] = {0, 2304, 4153, 5597, 6686, 7470};

    // ---- builder scratch (aliases head of A; dead before attn_score) ----
    size_t off = 0;
    auto alloc = [&](size_t n) { size_t o = off; off += (n + 63) & ~(size_t)63; return o; };
    size_t o_wm = alloc(142 * 48);
    size_t o_rtmp = alloc((size_t)200 * 43 * 48);
    size_t o_ref[5];
    o_ref[0] = 0;
    for (int si = 1; si < 5; ++si) o_ref[si] = alloc((size_t)200 * hs[si] * hs[si]);
    size_t o_base = alloc((size_t)200 * L_TOT);
    size_t o_refm = alloc((size_t)100 * L_TOT);
    size_t o_mb = alloc((size_t)100 * HW);
    size_t o_norms = alloc((size_t)4 * L_TOT);

    // ---- persistent layout (floats) ----
    size_t o_A = 0;                                       // bf16 [4][HW][L_PAD]
    size_t o_Q = (size_t)4 * HW * L_PAD / 2;
    size_t o_K = o_Q + (size_t)4 * HW * KD / 2;
    size_t o_VT = o_K + (size_t)4 * L_PAD * KD / 2;
    size_t o_Z = o_VT + (size_t)4 * JD * L_PAD / 2;       // bf16 [16][JD][HW]
    size_t o_mc = o_Z + (size_t)16 * JD * HW / 2;
    size_t o_dc = o_mc + (size_t)16 * HW;
    size_t o_fac = o_dc + (size_t)16 * HW;
    size_t o_zred = o_fac + (size_t)16 * HW;              // bf16 [4][JD][HW]

    u16* Qb = (u16*)(ws + o_Q);
    u16* Kb = (u16*)(ws + o_K);
    u16* VTb = (u16*)(ws + o_VT);
    u16* Ab = (u16*)(ws + o_A);
    u16* Zb = (u16*)(ws + o_Z);
    u16* Zrb = (u16*)(ws + o_zred);

    // ---- resizes ----
    resize_weights_kernel<<<1, 256, 0, stream>>>(ws + o_wm);
    const int woff[5] = {0, 0, 43 * 48, (43 + 38) * 48, (43 + 38 + 33) * 48};
    for (int si = 1; si < 5; ++si) {
        int osz = hs[si];
        int n1 = 200 * osz * 48;
        resize_h<<<(n1 + 255) / 256, 256, 0, stream>>>(x, ws + o_wm + woff[si], ws + o_rtmp, osz);
        int n2 = 200 * osz * osz;
        resize_w<<<(n2 + 255) / 256, 256, 0, stream>>>(ws + o_rtmp, ws + o_wm + woff[si],
                                                       ws + o_ref[si], osz);
    }
    // ---- convs ----
    for (int si = 0; si < 5; ++si) {
        int P = hs[si] * hs[si];
        const float* in = (si == 0) ? x : ws + o_ref[si];
        int nb = 4 * 50 * P;
        conv1x1_prelu<<<(nb + 255) / 256, 256, 0, stream>>>(
            in, w_asm, b_asm, a_asm, ws + o_base + (size_t)200 * loff[si], P, 50);
        int nm = 4 * 25 * P;
        conv1x1_prelu<<<(nm + 255) / 256, 256, 0, stream>>>(
            in, w_match, b_match, a_match, ws + o_refm + (size_t)100 * loff[si], P, 25);
    }
    {
        int nmb = 4 * 25 * HW;
        conv1x1_prelu<<<(nmb + 255) / 256, 256, 0, stream>>>(x, w_base, b_base, a_base,
                                                             ws + o_mb, HW, 25);
    }
    // ---- operand builders ----
    {
        int n = 4 * HW * KD;
        q_build<<<(n + 255) / 256, 256, 0, stream>>>(ws + o_mb, Qb);
    }
    {
        int n = 4 * L_TOT;
        norms_kernel<<<(n + 255) / 256, 256, 0, stream>>>(ws + o_refm, ws + o_norms);
    }
    {
        int n = 4 * L_PAD * KD;
        kt_build<<<(n + 255) / 256, 256, 0, stream>>>(ws + o_refm, ws + o_norms, Kb);
    }
    {
        int n = 4 * JD * L_PAD;
        v_build<<<(n + 255) / 256, 256, 0, stream>>>(ws + o_base, VTb);
    }

    // ---- fused score + softmax ----
    {
        dim3 g(8, 72, 1);
        attn_score<<<g, 256, 0, stream>>>(Qb, Kb, Ab, ws + o_mc, ws + o_dc);
    }
    combine_stats<<<(4 * HW + 255) / 256, 256, 0, stream>>>(ws + o_mc, ws + o_dc, ws + o_fac);

    // ---- GEMM2 (swapped: Zt[j][pp]) ----
    {
        dim3 g(8, 144, 1);
        gemm2_kernel<<<g, 256, 0, stream>>>(VTb, Ab, Zb);
    }
    // ---- weighted chunk reduction ----
    {
        int n = 4 * JD * HW / 8;
        chunk_reduce<<<(n + 255) / 256, 256, 0, stream>>>(Zb, ws + o_fac, Zrb);
    }
    final_kernel<<<(4 * 50 * HW + 255) / 256, 256, 0, stream>>>(Zrb, x, out);
}

// Round 7
// 534.065 us; speedup vs baseline: 4.4909x; 1.0461x over previous
//
#include <hip/hip_runtime.h>
#include <hip/hip_bf16.h>
#include <math.h>

// ---------------------------------------------------------------------------
// RFDN panet attention, MI355X.  Round 7:
//   - attn_score: two-sweep TRUE-max (round-5 proven; r6's C-S bound underflowed)
//   - builders rewritten: dtab decode table, per-(l,c) threads, bf16x8 stores
//   - fused launches: prep(weights+dtab), resize x2, conv_all(asm+match+base)
// ---------------------------------------------------------------------------

#define L_TOT 7470
#define L_PAD 7680   // 64 * 120, 4 chunks of 1920
#define NCHUNK 4
#define CHUNK_TILES 30   // 64-key tiles per chunk
#define KD    256    // padded 225
#define JD    512    // padded 450 = 50*3*3
#define HW    2304   // 48*48

typedef unsigned short u16;
typedef __attribute__((ext_vector_type(8))) short bf16x8;
typedef __attribute__((ext_vector_type(4))) float f32x4;

__device__ inline u16 f2b(float f) {
    __hip_bfloat16 h = __float2bfloat16(f);
    return __builtin_bit_cast(u16, h);
}
__device__ inline float b2f(u16 u) {
    __hip_bfloat16 h = __builtin_bit_cast(__hip_bfloat16, u);
    return __bfloat162float(h);
}

__constant__ int c_hs[5]   = {48, 43, 38, 33, 28};
__constant__ int c_loff[6] = {0, 2304, 4153, 5597, 6686, 7470};

#define GLOAD16(g, l) __builtin_amdgcn_global_load_lds(                          \
        (__attribute__((address_space(1))) const void*)(g),                      \
        (__attribute__((address_space(3))) void*)(l), 16, 0, 0)

// --------------------------- prep: resize weights + decode table -----------
__global__ void prep_kernel(float* __restrict__ wmall, int* __restrict__ dtab) {
    int r = blockIdx.x * 256 + threadIdx.x;
    if (r < 142) {
        int sizes[4] = {43, 38, 33, 28};
        int si = 0, i = r, woffs = 0;
        for (si = 0; si < 4; ++si) {
            if (i < sizes[si]) break;
            i -= sizes[si];
            woffs += sizes[si] * 48;
        }
        int osz = sizes[si];
        float inv_scale = 48.0f / (float)osz;
        float kscale = inv_scale;
        float sample_f = ((float)i + 0.5f) * inv_scale - 0.5f;
        float w[48];
        float tot = 0.f;
        for (int j = 0; j < 48; ++j) {
            float t = fabsf(sample_f - (float)j) / kscale;
            float v;
            if (t >= 2.f)       v = 0.f;
            else if (t >= 1.f)  v = ((-0.5f * t + 2.5f) * t - 4.f) * t + 2.f;
            else                v = ((1.5f * t - 2.5f) * t) * t + 1.f;
            w[j] = v;
            tot += v;
        }
        float invt = 1.f / tot;
        for (int j = 0; j < 48; ++j) wmall[woffs + i * 48 + j] = w[j] * invt;
    }
    if (r < L_PAD) {
        int v;
        if (r >= L_TOT) v = (int)0x80000000u;
        else {
            int si = 0;
#pragma unroll
            for (int s = 0; s < 4; ++s)
                if (r >= c_loff[s + 1]) si = s + 1;
            int pos = r - c_loff[si];
            int hs = c_hs[si];
            int ly = pos / hs, lx = pos % hs;
            v = si | (ly << 4) | (lx << 10);
        }
        dtab[r] = v;
    }
}

// --------------------------- fused resizes ---------------------------------
__global__ void resize_h_all(const float* __restrict__ in, const float* __restrict__ wm,
                             float* __restrict__ t1, float* __restrict__ t2,
                             float* __restrict__ t3, float* __restrict__ t4) {
    int idx = blockIdx.x * 256 + threadIdx.x;
    int rem = idx, osz, woffm;
    float* tmp;
    if (rem < 200 * 43 * 48) { osz = 43; tmp = t1; woffm = 0; }
    else {
        rem -= 200 * 43 * 48;
        if (rem < 200 * 38 * 48) { osz = 38; tmp = t2; woffm = 43 * 48; }
        else {
            rem -= 200 * 38 * 48;
            if (rem < 200 * 33 * 48) { osz = 33; tmp = t3; woffm = (43 + 38) * 48; }
            else {
                rem -= 200 * 33 * 48;
                if (rem >= 200 * 28 * 48) return;
                osz = 28; tmp = t4; woffm = (43 + 38 + 33) * 48;
            }
        }
    }
    int xi = rem % 48;
    int t = rem / 48;
    int yo = t % osz;
    int bc = t / osz;
    const float* wr = wm + (size_t)(woffm + yo * 48);
    const float* ip = in + (size_t)bc * 2304 + xi;
    float s = 0.f;
#pragma unroll
    for (int yi = 0; yi < 48; ++yi) s += wr[yi] * ip[yi * 48];
    tmp[rem] = s;
}

__global__ void resize_w_all(const float* __restrict__ t1, const float* __restrict__ t2,
                             const float* __restrict__ t3, const float* __restrict__ t4,
                             const float* __restrict__ wm,
                             float* __restrict__ r1, float* __restrict__ r2,
                             float* __restrict__ r3, float* __restrict__ r4) {
    int idx = blockIdx.x * 256 + threadIdx.x;
    int rem = idx, osz, woffm;
    const float* tmp;
    float* outp;
    if (rem < 200 * 43 * 43) { osz = 43; tmp = t1; outp = r1; woffm = 0; }
    else {
        rem -= 200 * 43 * 43;
        if (rem < 200 * 38 * 38) { osz = 38; tmp = t2; outp = r2; woffm = 43 * 48; }
        else {
            rem -= 200 * 38 * 38;
            if (rem < 200 * 33 * 33) { osz = 33; tmp = t3; outp = r3; woffm = (43 + 38) * 48; }
            else {
                rem -= 200 * 33 * 33;
                if (rem >= 200 * 28 * 28) return;
                osz = 28; tmp = t4; outp = r4; woffm = (43 + 38 + 33) * 48;
            }
        }
    }
    int xo = rem % osz;
    int t = rem / osz;
    int yo = t % osz;
    int bc = t / osz;
    const float* wr = wm + (size_t)(woffm + xo * 48);
    const float* ip = tmp + ((size_t)bc * osz + yo) * 48;
    float s = 0.f;
#pragma unroll
    for (int xi = 0; xi < 48; ++xi) s += wr[xi] * ip[xi];
    outp[rem] = s;
}

// ------------- fused 1x1 convs (asm+match all scales, base at scale 0) -----
__global__ void conv_all(const float* __restrict__ x,
                         const float* __restrict__ r1, const float* __restrict__ r2,
                         const float* __restrict__ r3, const float* __restrict__ r4,
                         const float* __restrict__ w_asm, const float* __restrict__ b_asm,
                         const float* __restrict__ a_asm,
                         const float* __restrict__ w_match, const float* __restrict__ b_match,
                         const float* __restrict__ a_match,
                         const float* __restrict__ w_base, const float* __restrict__ b_base,
                         const float* __restrict__ a_base,
                         float* __restrict__ base_out, float* __restrict__ refm_out,
                         float* __restrict__ mb_out) {
    int idx = blockIdx.x * 256 + threadIdx.x;
    int rem = idx, P, loffv, NCO;
    const float* in;
    if (rem < 400 * 2304) { P = 2304; in = x; loffv = 0; NCO = 100; }
    else {
        rem -= 400 * 2304;
        if (rem < 300 * 1849) { P = 1849; in = r1; loffv = 2304; NCO = 75; }
        else {
            rem -= 300 * 1849;
            if (rem < 300 * 1444) { P = 1444; in = r2; loffv = 4153; NCO = 75; }
            else {
                rem -= 300 * 1444;
                if (rem < 300 * 1089) { P = 1089; in = r3; loffv = 5597; NCO = 75; }
                else {
                    rem -= 300 * 1089;
                    if (rem >= 300 * 784) return;
                    P = 784; in = r4; loffv = 6686; NCO = 75;
                }
            }
        }
    }
    int p = rem % P;
    int t = rem / P;
    int co = t % NCO;
    int b = t / NCO;
    const float* ip = in + (size_t)b * 50 * P + p;
    const float* wr;
    float bias, av;
    float* outp;
    if (co < 50) {
        wr = w_asm + co * 50; bias = b_asm[co]; av = a_asm[0];
        outp = base_out + (size_t)200 * loffv + ((size_t)(b * 50 + co)) * P + p;
    } else if (co < 75) {
        int cm = co - 50;
        wr = w_match + cm * 50; bias = b_match[cm]; av = a_match[0];
        outp = refm_out + (size_t)100 * loffv + ((size_t)(b * 25 + cm)) * P + p;
    } else {
        int cm = co - 75;  // only reachable for scale 0 (NCO=100)
        wr = w_base + cm * 50; bias = b_base[cm]; av = a_base[0];
        outp = mb_out + ((size_t)(b * 25 + cm)) * P + p;
    }
    float s = bias;
#pragma unroll
    for (int ci = 0; ci < 50; ++ci) s += wr[ci] * ip[(size_t)ci * P];
    *outp = (s >= 0.f) ? s : av * s;
}

// --------------------------- builders (dtab-based) -------------------------
// Q: thread per (b,p,c): 9 contiguous u16 writes; c==24 zeroes k in [225,256)
__global__ void q_build(const float* __restrict__ mb, u16* __restrict__ Q) {
    int idx = blockIdx.x * 256 + threadIdx.x;
    if (idx >= 4 * HW * 25) return;
    int c = idx % 25;
    int t = idx / 25;
    int p = t % HW;
    int b = t / HW;
    int y = p / 48, xx = p % 48;
    const float* rc = mb + (size_t)(b * 25 + c) * HW;
    u16 ov[9];
#pragma unroll
    for (int ky = 0; ky < 3; ++ky)
#pragma unroll
        for (int kx = 0; kx < 3; ++kx) {
            int yy = y + ky - 1, xv = xx + kx - 1;
            float v = (yy >= 0 && yy < 48 && xv >= 0 && xv < 48) ? rc[yy * 48 + xv] : 0.f;
            ov[ky * 3 + kx] = f2b(v);
        }
    u16* dst = Q + (size_t)(b * HW + p) * KD + c * 9;
#pragma unroll
    for (int r = 0; r < 9; ++r) dst[r] = ov[r];
    if (c == 24) {
        u16* z = dst + 9;
#pragma unroll
        for (int i = 0; i < 31; ++i) z[i] = 0;
    }
}

__global__ void norms_kernel(const float* __restrict__ refm_all, const int* __restrict__ dtab,
                             float* __restrict__ norms) {
    int idx = blockIdx.x * 256 + threadIdx.x;
    if (idx >= 4 * L_PAD) return;
    int l = idx % L_PAD;
    int b = idx / L_PAD;
    int d = dtab[l];
    if (d < 0) return;
    int si = d & 15, ly = (d >> 4) & 63, lx = (d >> 10) & 63;
    int hs = c_hs[si], P = hs * hs;
    const float* rb = refm_all + (size_t)100 * c_loff[si] + (size_t)(b * 25) * P;
    float ss = 0.f;
    for (int c = 0; c < 25; ++c) {
        const float* rc = rb + (size_t)c * P;
#pragma unroll
        for (int ky = 0; ky < 3; ++ky)
#pragma unroll
            for (int kx = 0; kx < 3; ++kx) {
                int yy = ly + ky - 1, xv = lx + kx - 1;
                if (yy >= 0 && yy < hs && xv >= 0 && xv < hs) {
                    float v = rc[yy * hs + xv];
                    ss += v * v;
                }
            }
    }
    norms[(size_t)b * L_PAD + l] = 10.0f / fmaxf(sqrtf(ss), 1e-4f);  // SM_SCALE folded
}

// K: thread per (b,l,c): decode once, 9 reads, 9 contiguous u16 writes
__global__ void kt_build(const float* __restrict__ refm_all, const int* __restrict__ dtab,
                         const float* __restrict__ norms, u16* __restrict__ K) {
    int idx = blockIdx.x * 256 + threadIdx.x;
    if (idx >= 4 * L_PAD * 25) return;
    int c = idx % 25;
    int t = idx / 25;
    int l = t % L_PAD;
    int b = t / L_PAD;
    u16 ov[9] = {0, 0, 0, 0, 0, 0, 0, 0, 0};
    int d = dtab[l];
    if (d >= 0) {
        int si = d & 15, ly = (d >> 4) & 63, lx = (d >> 10) & 63;
        int hs = c_hs[si], P = hs * hs;
        float nrm = norms[(size_t)b * L_PAD + l];
        const float* rc = refm_all + (size_t)100 * c_loff[si] + (size_t)(b * 25 + c) * P;
#pragma unroll
        for (int ky = 0; ky < 3; ++ky)
#pragma unroll
            for (int kx = 0; kx < 3; ++kx) {
                int yy = ly + ky - 1, xv = lx + kx - 1;
                if (yy >= 0 && yy < hs && xv >= 0 && xv < hs)
                    ov[ky * 3 + kx] = f2b(rc[yy * hs + xv] * nrm);
            }
    }
    u16* dst = K + (size_t)(b * L_PAD + l) * KD + c * 9;
#pragma unroll
    for (int r = 0; r < 9; ++r) dst[r] = ov[r];
    if (c == 24) {
        u16* z = dst + 9;
#pragma unroll
        for (int i = 0; i < 31; ++i) z[i] = 0;
    }
}

// VT: thread per (b,j,l8): decode per l (dtab), vectorized bf16x8 store
__global__ void v_build(const float* __restrict__ base_all, const int* __restrict__ dtab,
                        u16* __restrict__ VT) {
    int idx = blockIdx.x * 256 + threadIdx.x;
    if (idx >= 4 * JD * (L_PAD / 8)) return;
    int l8 = idx % (L_PAD / 8);
    int t = idx / (L_PAD / 8);
    int j = t % JD;
    int b = t / JD;
    int l0 = l8 * 8;
    bf16x8 ov = (bf16x8){0, 0, 0, 0, 0, 0, 0, 0};
    if (j < 450) {
        int c = j / 9, r = j % 9, ky = r / 3, kx = r % 3;
#pragma unroll
        for (int u = 0; u < 8; ++u) {
            int d = dtab[l0 + u];
            float v = 0.f;
            if (d >= 0) {
                int si = d & 15, ly = (d >> 4) & 63, lx = (d >> 10) & 63;
                int hs = c_hs[si], P = hs * hs;
                int yy = ly + ky - 1, xv = lx + kx - 1;
                if (yy >= 0 && yy < hs && xv >= 0 && xv < hs)
                    v = base_all[(size_t)200 * c_loff[si] + (size_t)(b * 50 + c) * P + yy * hs + xv];
            }
            ov[u] = (short)f2b(v);
        }
    }
    *(bf16x8*)&VT[(size_t)(b * JD + j) * L_PAD + l0] = ov;
}

// --------------------------- fused score + softmax (two-sweep) -------------
// grid (8, 72): z16 = bx + 8*(by/36); b = z16>>2, chunk = z16&3; mt = by%36.
// LDS tile [64][KD] with 16B-unit XOR swizzle (source-side pre-swizzle).
// Pass1: row max. Pass2: A = exp(S - m) bf16 + denominator. Stats -> mC/dC.
__global__ __launch_bounds__(256, 4) void attn_score(
    const u16* __restrict__ Qg, const u16* __restrict__ Kg,
    u16* __restrict__ Ag, float* __restrict__ mC, float* __restrict__ dC) {
    __shared__ u16 smem[64 * KD];         // 32 KB
    __shared__ float sm_m[2][64], sm_d[2][64];
    const int bx = blockIdx.x, by = blockIdx.y;
    const int mt = by % 36, zq = by / 36;
    const int z16 = bx + 8 * zq;
    const int b = z16 >> 2, chunk = z16 & 3;
    const int bm = mt * 64;
    const u16* Q = Qg + (size_t)b * HW * KD;
    const u16* K = Kg + (size_t)b * L_PAD * KD;
    u16* A = Ag + (size_t)b * HW * L_PAD;
    const int tid = threadIdx.x, lane = tid & 63, wid = tid >> 6;
    const int wr = wid >> 1, wc = wid & 1;
    const int l15 = lane & 15, l16 = lane >> 4;
    const int l7 = lane & 7;
    const int r_lo = lane >> 5;
    const int u_dst = lane & 31;

    {
        const u16* qrow = Q + (size_t)(bm + wid * 16 + r_lo) * KD;
        u16* qdst = smem + (size_t)(wid * 16) * KD;
#pragma unroll
        for (int q = 0; q < 8; ++q) {
            int sw = (u_dst ^ ((q * 2 + r_lo) & 7)) * 8;
            GLOAD16(qrow + (size_t)(q * 2) * KD + sw, qdst + (q * 2) * KD);
        }
    }
    __syncthreads();
    bf16x8 qf[2][8];
#pragma unroll
    for (int m = 0; m < 2; ++m)
#pragma unroll
        for (int k = 0; k < 8; ++k)
            qf[m][k] = *(const bf16x8*)&smem[(size_t)(wr * 32 + m * 16 + l15) * KD
                                             + (((k * 4 + l16) ^ l7) * 8)];
    __syncthreads();

    float mrun[2][4];
#pragma unroll
    for (int m = 0; m < 2; ++m)
#pragma unroll
        for (int r = 0; r < 4; ++r) mrun[m][r] = -3e38f;

    const int t0 = chunk * CHUNK_TILES;
    const int colb_base = wc * 32 + l15;

    // ================= pass 1: row max =================
    for (int t = t0; t < t0 + CHUNK_TILES; ++t) {
        {
            const u16* krow = K + (size_t)(t * 64 + wid * 16 + r_lo) * KD;
            u16* kdst = smem + (size_t)(wid * 16) * KD;
#pragma unroll
            for (int q = 0; q < 8; ++q) {
                int sw = (u_dst ^ ((q * 2 + r_lo) & 7)) * 8;
                GLOAD16(krow + (size_t)(q * 2) * KD + sw, kdst + (q * 2) * KD);
            }
        }
        __syncthreads();
        f32x4 acc[2][2];
#pragma unroll
        for (int m = 0; m < 2; ++m)
#pragma unroll
            for (int n = 0; n < 2; ++n) acc[m][n] = (f32x4){0.f, 0.f, 0.f, 0.f};
#pragma unroll
        for (int k = 0; k < 8; ++k) {
            bf16x8 bfr[2];
#pragma unroll
            for (int n = 0; n < 2; ++n)
                bfr[n] = *(const bf16x8*)&smem[(size_t)(wc * 32 + n * 16 + l15) * KD
                                               + (((k * 4 + l16) ^ l7) * 8)];
#pragma unroll
            for (int m = 0; m < 2; ++m)
#pragma unroll
                for (int n = 0; n < 2; ++n)
                    acc[m][n] = __builtin_amdgcn_mfma_f32_16x16x32_bf16(qf[m][k], bfr[n], acc[m][n], 0, 0, 0);
        }
        const int col0 = t * 64 + colb_base;
        const bool v0 = col0 < L_TOT, v1 = col0 + 16 < L_TOT;
#pragma unroll
        for (int m = 0; m < 2; ++m)
#pragma unroll
            for (int r = 0; r < 4; ++r) {
                float s0 = v0 ? acc[m][0][r] : -3e38f;
                float s1 = v1 ? acc[m][1][r] : -3e38f;
                mrun[m][r] = fmaxf(mrun[m][r], fmaxf(s0, s1));
            }
        __syncthreads();
    }

    // combine max: butterfly over l15, then across wc via LDS
#pragma unroll
    for (int m = 0; m < 2; ++m)
#pragma unroll
        for (int r = 0; r < 4; ++r) {
            float mv = mrun[m][r];
#pragma unroll
            for (int st = 1; st <= 8; st <<= 1)
                mv = fmaxf(mv, __shfl_xor(mv, st));
            mrun[m][r] = mv;
        }
    if (l15 == 0) {
#pragma unroll
        for (int m = 0; m < 2; ++m)
#pragma unroll
            for (int r = 0; r < 4; ++r)
                sm_m[wc][wr * 32 + m * 16 + l16 * 4 + r] = mrun[m][r];
    }
    __syncthreads();
#pragma unroll
    for (int m = 0; m < 2; ++m)
#pragma unroll
        for (int r = 0; r < 4; ++r) {
            int row = wr * 32 + m * 16 + l16 * 4 + r;
            mrun[m][r] = fmaxf(sm_m[0][row], sm_m[1][row]);
        }

    // ================= pass 2: write A + denominator =================
    float drun[2][4];
#pragma unroll
    for (int m = 0; m < 2; ++m)
#pragma unroll
        for (int r = 0; r < 4; ++r) drun[m][r] = 0.f;

    for (int t = t0; t < t0 + CHUNK_TILES; ++t) {
        {
            const u16* krow = K + (size_t)(t * 64 + wid * 16 + r_lo) * KD;
            u16* kdst = smem + (size_t)(wid * 16) * KD;
#pragma unroll
            for (int q = 0; q < 8; ++q) {
                int sw = (u_dst ^ ((q * 2 + r_lo) & 7)) * 8;
                GLOAD16(krow + (size_t)(q * 2) * KD + sw, kdst + (q * 2) * KD);
            }
        }
        __syncthreads();
        f32x4 acc[2][2];
#pragma unroll
        for (int m = 0; m < 2; ++m)
#pragma unroll
            for (int n = 0; n < 2; ++n) acc[m][n] = (f32x4){0.f, 0.f, 0.f, 0.f};
#pragma unroll
        for (int k = 0; k < 8; ++k) {
            bf16x8 bfr[2];
#pragma unroll
            for (int n = 0; n < 2; ++n)
                bfr[n] = *(const bf16x8*)&smem[(size_t)(wc * 32 + n * 16 + l15) * KD
                                               + (((k * 4 + l16) ^ l7) * 8)];
#pragma unroll
            for (int m = 0; m < 2; ++m)
#pragma unroll
                for (int n = 0; n < 2; ++n)
                    acc[m][n] = __builtin_amdgcn_mfma_f32_16x16x32_bf16(qf[m][k], bfr[n], acc[m][n], 0, 0, 0);
        }
        const int col0 = t * 64 + colb_base;
#pragma unroll
        for (int m = 0; m < 2; ++m) {
            const int row = bm + wr * 32 + m * 16 + l16 * 4;
#pragma unroll
            for (int n = 0; n < 2; ++n) {
                const int col = col0 + n * 16;
                const bool vld = col < L_TOT;
#pragma unroll
                for (int r = 0; r < 4; ++r) {
                    float w = vld ? __expf(acc[m][n][r] - mrun[m][r]) : 0.f;
                    drun[m][r] += w;
                    A[(size_t)(row + r) * L_PAD + col] = f2b(w);
                }
            }
        }
        __syncthreads();
    }

    // reduce denominator
#pragma unroll
    for (int m = 0; m < 2; ++m)
#pragma unroll
        for (int r = 0; r < 4; ++r) {
            float dv = drun[m][r];
#pragma unroll
            for (int st = 1; st <= 8; st <<= 1)
                dv += __shfl_xor(dv, st);
            drun[m][r] = dv;
        }
    if (l15 == 0) {
#pragma unroll
        for (int m = 0; m < 2; ++m)
#pragma unroll
            for (int r = 0; r < 4; ++r)
                sm_d[wc][wr * 32 + m * 16 + l16 * 4 + r] = drun[m][r];
    }
    __syncthreads();
    if (wc == 0 && l15 == 0) {
#pragma unroll
        for (int m = 0; m < 2; ++m)
#pragma unroll
            for (int r = 0; r < 4; ++r) {
                int row = wr * 32 + m * 16 + l16 * 4 + r;
                size_t o = (size_t)(chunk * 4 + b) * HW + bm + row;
                mC[o] = mrun[m][r];
                dC[o] = sm_d[0][row] + sm_d[1][row];
            }
    }
}

// --------------------------- combine chunk stats ---------------------------
__global__ void combine_stats(const float* __restrict__ mC, const float* __restrict__ dC,
                              float* __restrict__ fac) {
    int idx = blockIdx.x * 256 + threadIdx.x;
    if (idx >= 4 * HW) return;
    int b = idx / HW, p = idx % HW;
    float m[NCHUNK], d[NCHUNK];
#pragma unroll
    for (int c = 0; c < NCHUNK; ++c) {
        size_t o = (size_t)(c * 4 + b) * HW + p;
        m[c] = mC[o]; d[c] = dC[o];
    }
    float mf = m[0];
#pragma unroll
    for (int c = 1; c < NCHUNK; ++c) mf = fmaxf(mf, m[c]);
    float w[NCHUNK], df = 0.f;
#pragma unroll
    for (int c = 0; c < NCHUNK; ++c) { w[c] = __expf(m[c] - mf); df += d[c] * w[c]; }
    float inv = 1.0f / df;
#pragma unroll
    for (int c = 0; c < NCHUNK; ++c) fac[(size_t)(c * 4 + b) * HW + p] = w[c] * inv;
}

// --------------------------- GEMM2: Zt_z[j][pp] = VT_chunk . A_chunk^T -----
__global__ __launch_bounds__(256) void gemm2_kernel(
    const u16* __restrict__ VT0, const u16* __restrict__ A0, u16* __restrict__ C0) {
    __shared__ u16 As[128 * 64];
    __shared__ u16 Bs[128 * 64];
    const int bx = blockIdx.x, by = blockIdx.y;
    const int within = by % 72, zq = by / 72;
    const int mt = within & 3, nt = within >> 2;
    const int z = bx + 8 * zq;
    const int batch = z >> 2, chunk = z & 3;
    const u16* A = VT0 + (size_t)batch * JD * L_PAD + chunk * (CHUNK_TILES * 64);
    const u16* B = A0 + (size_t)batch * HW * L_PAD + chunk * (CHUNK_TILES * 64);
    u16* C = C0 + (size_t)z * JD * HW;
    const int bm = mt * 128, bn = nt * 128;
    const int tid = threadIdx.x, lane = tid & 63, wid = tid >> 6;
    const int wr = wid >> 1, wc = wid & 1;
    const int srow = lane >> 3;
    const int scol = (lane & 7) * 8;

    f32x4 acc[4][4];
#pragma unroll
    for (int i = 0; i < 4; ++i)
#pragma unroll
        for (int j = 0; j < 4; ++j) acc[i][j] = (f32x4){0.f, 0.f, 0.f, 0.f};

    const u16* aG = A + (size_t)(bm + wid * 32 + srow) * L_PAD + scol;
    const u16* bG = B + (size_t)(bn + wid * 32 + srow) * L_PAD + scol;
    u16* aL = As + wid * 32 * 64;
    u16* bL = Bs + wid * 32 * 64;

    for (int t = 0; t < CHUNK_TILES; ++t) {
#pragma unroll
        for (int q = 0; q < 4; ++q) {
            GLOAD16(aG + (size_t)q * 8 * L_PAD, aL + q * 8 * 64);
            GLOAD16(bG + (size_t)q * 8 * L_PAD, bL + q * 8 * 64);
        }
        aG += 64;
        bG += 64;
        __syncthreads();
#pragma unroll
        for (int kc = 0; kc < 64; kc += 32) {
            bf16x8 af[4], bf[4];
#pragma unroll
            for (int m = 0; m < 4; ++m)
                af[m] = *(const bf16x8*)&As[(wr * 64 + m * 16 + (lane & 15)) * 64 + kc + (lane >> 4) * 8];
#pragma unroll
            for (int n = 0; n < 4; ++n)
                bf[n] = *(const bf16x8*)&Bs[(wc * 64 + n * 16 + (lane & 15)) * 64 + kc + (lane >> 4) * 8];
#pragma unroll
            for (int m = 0; m < 4; ++m)
#pragma unroll
                for (int n = 0; n < 4; ++n)
                    acc[m][n] = __builtin_amdgcn_mfma_f32_16x16x32_bf16(af[m], bf[n], acc[m][n], 0, 0, 0);
        }
        __syncthreads();
    }
    const int crow0 = bm + wr * 64 + (lane >> 4) * 4;
    const int ccol = bn + wc * 64 + (lane & 15);
#pragma unroll
    for (int m = 0; m < 4; ++m)
#pragma unroll
        for (int n = 0; n < 4; ++n)
#pragma unroll
            for (int r = 0; r < 4; ++r)
                C[(size_t)(crow0 + m * 16 + r) * HW + ccol + n * 16] = f2b(acc[m][n][r]);
}

// --------------------------- chunk reduce (weighted sum over chunks) -------
__global__ void chunk_reduce(const u16* __restrict__ Zt, const float* __restrict__ fac,
                             u16* __restrict__ Zred) {
    int idx = blockIdx.x * 256 + threadIdx.x;
    int total = 4 * JD * HW / 8;
    if (idx >= total) return;
    int e8 = idx * 8;
    int pp = e8 % HW;
    int row = e8 / HW;          // row = b*JD + j
    int b = row / JD;
    float s[8] = {};
#pragma unroll
    for (int ch = 0; ch < NCHUNK; ++ch) {
        const float* fp = fac + (size_t)(ch * 4 + b) * HW + pp;
        bf16x8 zv = *(const bf16x8*)&Zt[((size_t)(b * 4 + ch) * JD + (row % JD)) * HW + pp];
#pragma unroll
        for (int u = 0; u < 8; ++u)
            s[u] += fp[u] * b2f((u16)zv[u]);
    }
    bf16x8 o;
#pragma unroll
    for (int u = 0; u < 8; ++u) o[u] = (short)f2b(s[u]);
    *(bf16x8*)&Zred[(size_t)row * HW + pp] = o;
}

// --------------------------- final: 9-tap gather + residual ----------------
__global__ void final_kernel(const u16* __restrict__ Zred, const float* __restrict__ x,
                             float* __restrict__ out) {
    int idx = blockIdx.x * 256 + threadIdx.x;
    if (idx >= 4 * 50 * HW) return;
    int p = idx % HW;
    int t = idx / HW;
    int c = t % 50;
    int b = t / 50;
    int y = p / 48, xx = p % 48;
    const u16* Zb = Zred + (size_t)b * JD * HW;
    float s = 0.f;
#pragma unroll
    for (int ky = 0; ky < 3; ++ky) {
        int yy = y + ky - 1;
        if (yy < 0 || yy >= 48) continue;
#pragma unroll
        for (int kx = 0; kx < 3; ++kx) {
            int xv = xx + kx - 1;
            if (xv < 0 || xv >= 48) continue;
            int pp = yy * 48 + xv;
            int j = c * 9 + (2 - ky) * 3 + (2 - kx);
            s += b2f(Zb[(size_t)j * HW + pp]);
        }
    }
    size_t o = ((size_t)b * 50 + c) * HW + p;
    out[o] = x[o] + 0.25f * s;
}

// ---------------------------------------------------------------------------
extern "C" void kernel_launch(void* const* d_in, const int* in_sizes, int n_in,
                              void* d_out, int out_size, void* d_ws, size_t ws_size,
                              hipStream_t stream) {
    const float* x       = (const float*)d_in[0];
    const float* w_base  = (const float*)d_in[1];
    const float* b_base  = (const float*)d_in[2];
    const float* a_base  = (const float*)d_in[3];
    const float* w_match = (const float*)d_in[4];
    const float* b_match = (const float*)d_in[5];
    const float* a_match = (const float*)d_in[6];
    const float* w_asm   = (const float*)d_in[7];
    const float* b_asm   = (const float*)d_in[8];
    const float* a_asm   = (const float*)d_in[9];
    float* out = (float*)d_out;
    float* ws = (float*)d_ws;
    (void)in_sizes; (void)n_in; (void)out_size; (void)ws_size;

    // ---- builder scratch (aliases head of A; dead before attn_score) ----
    size_t off = 0;
    auto alloc = [&](size_t n) { size_t o = off; off += (n + 63) & ~(size_t)63; return o; };
    size_t o_wm = alloc(142 * 48);
    size_t o_dtab = alloc(L_PAD);                  // int table
    size_t o_t1 = alloc((size_t)200 * 43 * 48);
    size_t o_t2 = alloc((size_t)200 * 38 * 48);
    size_t o_t3 = alloc((size_t)200 * 33 * 48);
    size_t o_t4 = alloc((size_t)200 * 28 * 48);
    size_t o_r1 = alloc((size_t)200 * 43 * 43);
    size_t o_r2 = alloc((size_t)200 * 38 * 38);
    size_t o_r3 = alloc((size_t)200 * 33 * 33);
    size_t o_r4 = alloc((size_t)200 * 28 * 28);
    size_t o_base = alloc((size_t)200 * L_TOT);
    size_t o_refm = alloc((size_t)100 * L_TOT);
    size_t o_mb = alloc((size_t)100 * HW);
    size_t o_norms = alloc((size_t)4 * L_PAD);

    // ---- persistent layout (floats) ----
    size_t o_A = 0;                                       // bf16 [4][HW][L_PAD]
    size_t o_Q = (size_t)4 * HW * L_PAD / 2;
    size_t o_K = o_Q + (size_t)4 * HW * KD / 2;
    size_t o_VT = o_K + (size_t)4 * L_PAD * KD / 2;
    size_t o_Z = o_VT + (size_t)4 * JD * L_PAD / 2;       // bf16 [16][JD][HW]
    size_t o_mc = o_Z + (size_t)16 * JD * HW / 2;
    size_t o_dc = o_mc + (size_t)16 * HW;
    size_t o_fac = o_dc + (size_t)16 * HW;
    size_t o_zred = o_fac + (size_t)16 * HW;              // bf16 [4][JD][HW]

    u16* Qb = (u16*)(ws + o_Q);
    u16* Kb = (u16*)(ws + o_K);
    u16* VTb = (u16*)(ws + o_VT);
    u16* Ab = (u16*)(ws + o_A);
    u16* Zb = (u16*)(ws + o_Z);
    u16* Zrb = (u16*)(ws + o_zred);
    int* dtab = (int*)(ws + o_dtab);

    // ---- prep (weights + decode table) ----
    prep_kernel<<<(L_PAD + 255) / 256, 256, 0, stream>>>(ws + o_wm, dtab);
    // ---- resizes ----
    {
        int n = 200 * 48 * (43 + 38 + 33 + 28);
        resize_h_all<<<(n + 255) / 256, 256, 0, stream>>>(x, ws + o_wm, ws + o_t1,
                                                          ws + o_t2, ws + o_t3, ws + o_t4);
    }
    {
        int n = 200 * (43 * 43 + 38 * 38 + 33 * 33 + 28 * 28);
        resize_w_all<<<(n + 255) / 256, 256, 0, stream>>>(ws + o_t1, ws + o_t2, ws + o_t3,
                                                          ws + o_t4, ws + o_wm, ws + o_r1,
                                                          ws + o_r2, ws + o_r3, ws + o_r4);
    }
    // ---- convs (asm+match all scales, base at scale 0) ----
    {
        int n = 400 * 2304 + 300 * (1849 + 1444 + 1089 + 784);
        conv_all<<<(n + 255) / 256, 256, 0, stream>>>(
            x, ws + o_r1, ws + o_r2, ws + o_r3, ws + o_r4,
            w_asm, b_asm, a_asm, w_match, b_match, a_match, w_base, b_base, a_base,
            ws + o_base, ws + o_refm, ws + o_mb);
    }
    // ---- operand builders ----
    {
        int n = 4 * HW * 25;
        q_build<<<(n + 255) / 256, 256, 0, stream>>>(ws + o_mb, Qb);
    }
    {
        int n = 4 * L_PAD;
        norms_kernel<<<(n + 255) / 256, 256, 0, stream>>>(ws + o_refm, dtab, ws + o_norms);
    }
    {
        int n = 4 * L_PAD * 25;
        kt_build<<<(n + 255) / 256, 256, 0, stream>>>(ws + o_refm, dtab, ws + o_norms, Kb);
    }
    {
        int n = 4 * JD * (L_PAD / 8);
        v_build<<<(n + 255) / 256, 256, 0, stream>>>(ws + o_base, dtab, VTb);
    }

    // ---- fused score + softmax (two-sweep true max) ----
    {
        dim3 g(8, 72, 1);
        attn_score<<<g, 256, 0, stream>>>(Qb, Kb, Ab, ws + o_mc, ws + o_dc);
    }
    combine_stats<<<(4 * HW + 255) / 256, 256, 0, stream>>>(ws + o_mc, ws + o_dc, ws + o_fac);

    // ---- GEMM2 (swapped: Zt[j][pp]) ----
    {
        dim3 g(8, 144, 1);
        gemm2_kernel<<<g, 256, 0, stream>>>(VTb, Ab, Zb);
    }
    // ---- weighted chunk reduction ----
    {
        int n = 4 * JD * HW / 8;
        chunk_reduce<<<(n + 255) / 256, 256, 0, stream>>>(Zb, ws + o_fac, Zrb);
    }
    final_kernel<<<(4 * 50 * HW + 255) / 256, 256, 0, stream>>>(Zrb, x, out);
}

// Round 8
// 495.337 us; speedup vs baseline: 4.8421x; 1.0782x over previous
//
#include <hip/hip_runtime.h>
#include <hip/hip_bf16.h>
#include <hip/hip_fp16.h>
#include <math.h>

// ---------------------------------------------------------------------------
// RFDN panet attention, MI355X.  Round 8:
//   - attn_score SINGLE sweep: computes S = QK^T, writes raw fp16 S + true
//     per-chunk row max mC. 32-row M tiles, grid 1152, swizzled LDS.
//   - GEMM2 applies exp(S - m_c) during reg-staged B (T14 prefetch), ones
//     column j=450 in VT yields the softmax denominator for free.
//   - combine_stats (after GEMM2) builds fac from mC + Zt[.][450].
// ---------------------------------------------------------------------------

#define L_TOT 7470
#define L_PAD 7680   // 64 * 120, 4 chunks of 1920
#define NCHUNK 4
#define CHUNK_TILES 30   // 64-key tiles per chunk
#define KD    256    // padded 225
#define JD    512    // padded 450 = 50*3*3
#define HW    2304   // 48*48

typedef unsigned short u16;
typedef __attribute__((ext_vector_type(8))) short bf16x8;
typedef __attribute__((ext_vector_type(4))) float f32x4;

__device__ inline u16 f2b(float f) {
    __hip_bfloat16 h = __float2bfloat16(f);
    return __builtin_bit_cast(u16, h);
}
__device__ inline float b2f(u16 u) {
    __hip_bfloat16 h = __builtin_bit_cast(__hip_bfloat16, u);
    return __bfloat162float(h);
}
__device__ inline u16 f2h(float f) {
    __half h = __float2half(f);
    return __builtin_bit_cast(u16, h);
}
__device__ inline float h2f(u16 u) {
    __half h = __builtin_bit_cast(__half, u);
    return __half2float(h);
}

__constant__ int c_hs[5]   = {48, 43, 38, 33, 28};
__constant__ int c_loff[6] = {0, 2304, 4153, 5597, 6686, 7470};

#define GLOAD16(g, l) __builtin_amdgcn_global_load_lds(                          \
        (__attribute__((address_space(1))) const void*)(g),                      \
        (__attribute__((address_space(3))) void*)(l), 16, 0, 0)

// --------------------------- prep: resize weights + decode table -----------
__global__ void prep_kernel(float* __restrict__ wmall, int* __restrict__ dtab) {
    int r = blockIdx.x * 256 + threadIdx.x;
    if (r < 142) {
        int sizes[4] = {43, 38, 33, 28};
        int si = 0, i = r, woffs = 0;
        for (si = 0; si < 4; ++si) {
            if (i < sizes[si]) break;
            i -= sizes[si];
            woffs += sizes[si] * 48;
        }
        int osz = sizes[si];
        float inv_scale = 48.0f / (float)osz;
        float kscale = inv_scale;
        float sample_f = ((float)i + 0.5f) * inv_scale - 0.5f;
        float w[48];
        float tot = 0.f;
        for (int j = 0; j < 48; ++j) {
            float t = fabsf(sample_f - (float)j) / kscale;
            float v;
            if (t >= 2.f)       v = 0.f;
            else if (t >= 1.f)  v = ((-0.5f * t + 2.5f) * t - 4.f) * t + 2.f;
            else                v = ((1.5f * t - 2.5f) * t) * t + 1.f;
            w[j] = v;
            tot += v;
        }
        float invt = 1.f / tot;
        for (int j = 0; j < 48; ++j) wmall[woffs + i * 48 + j] = w[j] * invt;
    }
    if (r < L_PAD) {
        int v;
        if (r >= L_TOT) v = (int)0x80000000u;
        else {
            int si = 0;
#pragma unroll
            for (int s = 0; s < 4; ++s)
                if (r >= c_loff[s + 1]) si = s + 1;
            int pos = r - c_loff[si];
            int hs = c_hs[si];
            int ly = pos / hs, lx = pos % hs;
            v = si | (ly << 4) | (lx << 10);
        }
        dtab[r] = v;
    }
}

// --------------------------- fused resizes ---------------------------------
__global__ void resize_h_all(const float* __restrict__ in, const float* __restrict__ wm,
                             float* __restrict__ t1, float* __restrict__ t2,
                             float* __restrict__ t3, float* __restrict__ t4) {
    int idx = blockIdx.x * 256 + threadIdx.x;
    int rem = idx, osz, woffm;
    float* tmp;
    if (rem < 200 * 43 * 48) { osz = 43; tmp = t1; woffm = 0; }
    else {
        rem -= 200 * 43 * 48;
        if (rem < 200 * 38 * 48) { osz = 38; tmp = t2; woffm = 43 * 48; }
        else {
            rem -= 200 * 38 * 48;
            if (rem < 200 * 33 * 48) { osz = 33; tmp = t3; woffm = (43 + 38) * 48; }
            else {
                rem -= 200 * 33 * 48;
                if (rem >= 200 * 28 * 48) return;
                osz = 28; tmp = t4; woffm = (43 + 38 + 33) * 48;
            }
        }
    }
    int xi = rem % 48;
    int t = rem / 48;
    int yo = t % osz;
    int bc = t / osz;
    const float* wr = wm + (size_t)(woffm + yo * 48);
    const float* ip = in + (size_t)bc * 2304 + xi;
    float s = 0.f;
#pragma unroll
    for (int yi = 0; yi < 48; ++yi) s += wr[yi] * ip[yi * 48];
    tmp[rem] = s;
}

__global__ void resize_w_all(const float* __restrict__ t1, const float* __restrict__ t2,
                             const float* __restrict__ t3, const float* __restrict__ t4,
                             const float* __restrict__ wm,
                             float* __restrict__ r1, float* __restrict__ r2,
                             float* __restrict__ r3, float* __restrict__ r4) {
    int idx = blockIdx.x * 256 + threadIdx.x;
    int rem = idx, osz, woffm;
    const float* tmp;
    float* outp;
    if (rem < 200 * 43 * 43) { osz = 43; tmp = t1; outp = r1; woffm = 0; }
    else {
        rem -= 200 * 43 * 43;
        if (rem < 200 * 38 * 38) { osz = 38; tmp = t2; outp = r2; woffm = 43 * 48; }
        else {
            rem -= 200 * 38 * 38;
            if (rem < 200 * 33 * 33) { osz = 33; tmp = t3; outp = r3; woffm = (43 + 38) * 48; }
            else {
                rem -= 200 * 33 * 33;
                if (rem >= 200 * 28 * 28) return;
                osz = 28; tmp = t4; outp = r4; woffm = (43 + 38 + 33) * 48;
            }
        }
    }
    int xo = rem % osz;
    int t = rem / osz;
    int yo = t % osz;
    int bc = t / osz;
    const float* wr = wm + (size_t)(woffm + xo * 48);
    const float* ip = tmp + ((size_t)bc * osz + yo) * 48;
    float s = 0.f;
#pragma unroll
    for (int xi = 0; xi < 48; ++xi) s += wr[xi] * ip[xi];
    outp[rem] = s;
}

// ------------- fused 1x1 convs (asm+match all scales, base at scale 0) -----
__global__ void conv_all(const float* __restrict__ x,
                         const float* __restrict__ r1, const float* __restrict__ r2,
                         const float* __restrict__ r3, const float* __restrict__ r4,
                         const float* __restrict__ w_asm, const float* __restrict__ b_asm,
                         const float* __restrict__ a_asm,
                         const float* __restrict__ w_match, const float* __restrict__ b_match,
                         const float* __restrict__ a_match,
                         const float* __restrict__ w_base, const float* __restrict__ b_base,
                         const float* __restrict__ a_base,
                         float* __restrict__ base_out, float* __restrict__ refm_out,
                         float* __restrict__ mb_out) {
    int idx = blockIdx.x * 256 + threadIdx.x;
    int rem = idx, P, loffv, NCO;
    const float* in;
    if (rem < 400 * 2304) { P = 2304; in = x; loffv = 0; NCO = 100; }
    else {
        rem -= 400 * 2304;
        if (rem < 300 * 1849) { P = 1849; in = r1; loffv = 2304; NCO = 75; }
        else {
            rem -= 300 * 1849;
            if (rem < 300 * 1444) { P = 1444; in = r2; loffv = 4153; NCO = 75; }
            else {
                rem -= 300 * 1444;
                if (rem < 300 * 1089) { P = 1089; in = r3; loffv = 5597; NCO = 75; }
                else {
                    rem -= 300 * 1089;
                    if (rem >= 300 * 784) return;
                    P = 784; in = r4; loffv = 6686; NCO = 75;
                }
            }
        }
    }
    int p = rem % P;
    int t = rem / P;
    int co = t % NCO;
    int b = t / NCO;
    const float* ip = in + (size_t)b * 50 * P + p;
    const float* wr;
    float bias, av;
    float* outp;
    if (co < 50) {
        wr = w_asm + co * 50; bias = b_asm[co]; av = a_asm[0];
        outp = base_out + (size_t)200 * loffv + ((size_t)(b * 50 + co)) * P + p;
    } else if (co < 75) {
        int cm = co - 50;
        wr = w_match + cm * 50; bias = b_match[cm]; av = a_match[0];
        outp = refm_out + (size_t)100 * loffv + ((size_t)(b * 25 + cm)) * P + p;
    } else {
        int cm = co - 75;
        wr = w_base + cm * 50; bias = b_base[cm]; av = a_base[0];
        outp = mb_out + ((size_t)(b * 25 + cm)) * P + p;
    }
    float s = bias;
#pragma unroll
    for (int ci = 0; ci < 50; ++ci) s += wr[ci] * ip[(size_t)ci * P];
    *outp = (s >= 0.f) ? s : av * s;
}

// --------------------------- builders (dtab-based) -------------------------
__global__ void q_build(const float* __restrict__ mb, u16* __restrict__ Q) {
    int idx = blockIdx.x * 256 + threadIdx.x;
    if (idx >= 4 * HW * 25) return;
    int c = idx % 25;
    int t = idx / 25;
    int p = t % HW;
    int b = t / HW;
    int y = p / 48, xx = p % 48;
    const float* rc = mb + (size_t)(b * 25 + c) * HW;
    u16 ov[9];
#pragma unroll
    for (int ky = 0; ky < 3; ++ky)
#pragma unroll
        for (int kx = 0; kx < 3; ++kx) {
            int yy = y + ky - 1, xv = xx + kx - 1;
            float v = (yy >= 0 && yy < 48 && xv >= 0 && xv < 48) ? rc[yy * 48 + xv] : 0.f;
            ov[ky * 3 + kx] = f2b(v);
        }
    u16* dst = Q + (size_t)(b * HW + p) * KD + c * 9;
#pragma unroll
    for (int r = 0; r < 9; ++r) dst[r] = ov[r];
    if (c == 24) {
        u16* z = dst + 9;
#pragma unroll
        for (int i = 0; i < 31; ++i) z[i] = 0;
    }
}

__global__ void norms_kernel(const float* __restrict__ refm_all, const int* __restrict__ dtab,
                             float* __restrict__ norms) {
    int idx = blockIdx.x * 256 + threadIdx.x;
    if (idx >= 4 * L_PAD) return;
    int l = idx % L_PAD;
    int b = idx / L_PAD;
    int d = dtab[l];
    if (d < 0) return;
    int si = d & 15, ly = (d >> 4) & 63, lx = (d >> 10) & 63;
    int hs = c_hs[si], P = hs * hs;
    const float* rb = refm_all + (size_t)100 * c_loff[si] + (size_t)(b * 25) * P;
    float ss = 0.f;
    for (int c = 0; c < 25; ++c) {
        const float* rc = rb + (size_t)c * P;
#pragma unroll
        for (int ky = 0; ky < 3; ++ky)
#pragma unroll
            for (int kx = 0; kx < 3; ++kx) {
                int yy = ly + ky - 1, xv = lx + kx - 1;
                if (yy >= 0 && yy < hs && xv >= 0 && xv < hs) {
                    float v = rc[yy * hs + xv];
                    ss += v * v;
                }
            }
    }
    norms[(size_t)b * L_PAD + l] = 10.0f / fmaxf(sqrtf(ss), 1e-4f);  // SM_SCALE folded
}

__global__ void kt_build(const float* __restrict__ refm_all, const int* __restrict__ dtab,
                         const float* __restrict__ norms, u16* __restrict__ K) {
    int idx = blockIdx.x * 256 + threadIdx.x;
    if (idx >= 4 * L_PAD * 25) return;
    int c = idx % 25;
    int t = idx / 25;
    int l = t % L_PAD;
    int b = t / L_PAD;
    u16 ov[9] = {0, 0, 0, 0, 0, 0, 0, 0, 0};
    int d = dtab[l];
    if (d >= 0) {
        int si = d & 15, ly = (d >> 4) & 63, lx = (d >> 10) & 63;
        int hs = c_hs[si], P = hs * hs;
        float nrm = norms[(size_t)b * L_PAD + l];
        const float* rc = refm_all + (size_t)100 * c_loff[si] + (size_t)(b * 25 + c) * P;
#pragma unroll
        for (int ky = 0; ky < 3; ++ky)
#pragma unroll
            for (int kx = 0; kx < 3; ++kx) {
                int yy = ly + ky - 1, xv = lx + kx - 1;
                if (yy >= 0 && yy < hs && xv >= 0 && xv < hs)
                    ov[ky * 3 + kx] = f2b(rc[yy * hs + xv] * nrm);
            }
    }
    u16* dst = K + (size_t)(b * L_PAD + l) * KD + c * 9;
#pragma unroll
    for (int r = 0; r < 9; ++r) dst[r] = ov[r];
    if (c == 24) {
        u16* z = dst + 9;
#pragma unroll
        for (int i = 0; i < 31; ++i) z[i] = 0;
    }
}

// VT: thread per (b,j,l8); j==450 is the all-ones denominator column.
__global__ void v_build(const float* __restrict__ base_all, const int* __restrict__ dtab,
                        u16* __restrict__ VT) {
    int idx = blockIdx.x * 256 + threadIdx.x;
    if (idx >= 4 * JD * (L_PAD / 8)) return;
    int l8 = idx % (L_PAD / 8);
    int t = idx / (L_PAD / 8);
    int j = t % JD;
    int b = t / JD;
    int l0 = l8 * 8;
    bf16x8 ov = (bf16x8){0, 0, 0, 0, 0, 0, 0, 0};
    if (j < 450) {
        int c = j / 9, r = j % 9, ky = r / 3, kx = r % 3;
#pragma unroll
        for (int u = 0; u < 8; ++u) {
            int d = dtab[l0 + u];
            float v = 0.f;
            if (d >= 0) {
                int si = d & 15, ly = (d >> 4) & 63, lx = (d >> 10) & 63;
                int hs = c_hs[si], P = hs * hs;
                int yy = ly + ky - 1, xv = lx + kx - 1;
                if (yy >= 0 && yy < hs && xv >= 0 && xv < hs)
                    v = base_all[(size_t)200 * c_loff[si] + (size_t)(b * 50 + c) * P + yy * hs + xv];
            }
            ov[u] = (short)f2b(v);
        }
    } else if (j == 450) {
        const u16 one = f2b(1.0f);
#pragma unroll
        for (int u = 0; u < 8; ++u)
            ov[u] = (short)(dtab[l0 + u] >= 0 ? one : 0);
    }
    *(bf16x8*)&VT[(size_t)(b * JD + j) * L_PAD + l0] = ov;
}

// --------------------------- score pass (single sweep) ---------------------
// grid (8, 144): z16 = bx + 8*(by/72) -> b = z16>>2, chunk = z16&3 (XCD pin);
// mt = by%72 -> bm = mt*32 (32 query rows per block).
// Writes raw fp16 S to SR (padded cols get -inf) and per-chunk true row max.
__global__ __launch_bounds__(256, 4) void attn_score(
    const u16* __restrict__ Qg, const u16* __restrict__ Kg,
    u16* __restrict__ SRg, float* __restrict__ mC) {
    __shared__ u16 smem[64 * KD];         // 32 KB (Q stage uses first half)
    __shared__ float sm_m[2][32];
    const int bx = blockIdx.x, by = blockIdx.y;
    const int mt = by % 72, zq = by / 72;
    const int z16 = bx + 8 * zq;
    const int b = z16 >> 2, chunk = z16 & 3;
    const int bm = mt * 32;
    const u16* Q = Qg + (size_t)b * HW * KD;
    const u16* K = Kg + (size_t)b * L_PAD * KD;
    u16* SR = SRg + (size_t)b * HW * L_PAD;
    const int tid = threadIdx.x, lane = tid & 63, wid = tid >> 6;
    const int wr = wid >> 1, wc = wid & 1;
    const int l15 = lane & 15, l16 = lane >> 4, l7 = lane & 7;
    const int r_lo = lane >> 5;           // row parity (2 rows per wave pass)
    const int u_dst = lane & 31;          // 16B dest unit

    // ---- stage Q tile (32 x KD) swizzled ----
    {
        const u16* qrow = Q + (size_t)(bm + wid * 8 + r_lo) * KD;
        u16* qdst = smem + (size_t)(wid * 8) * KD;
#pragma unroll
        for (int q = 0; q < 4; ++q) {
            int sw = (u_dst ^ ((q * 2 + r_lo) & 7)) * 8;
            GLOAD16(qrow + (size_t)(q * 2) * KD + sw, qdst + (q * 2) * KD);
        }
    }
    __syncthreads();
    bf16x8 qf[8];
#pragma unroll
    for (int k = 0; k < 8; ++k)
        qf[k] = *(const bf16x8*)&smem[(size_t)(wr * 16 + l15) * KD + (((k * 4 + l16) ^ l7) * 8)];
    __syncthreads();

    float mrun[4] = {-3e38f, -3e38f, -3e38f, -3e38f};
    const int t0 = chunk * CHUNK_TILES;

    for (int t = t0; t < t0 + CHUNK_TILES; ++t) {
        {
            const u16* krow = K + (size_t)(t * 64 + wid * 16 + r_lo) * KD;
            u16* kdst = smem + (size_t)(wid * 16) * KD;
#pragma unroll
            for (int q = 0; q < 8; ++q) {
                int sw = (u_dst ^ ((q * 2 + r_lo) & 7)) * 8;
                GLOAD16(krow + (size_t)(q * 2) * KD + sw, kdst + (q * 2) * KD);
            }
        }
        __syncthreads();
        f32x4 acc[2];
#pragma unroll
        for (int n = 0; n < 2; ++n) acc[n] = (f32x4){0.f, 0.f, 0.f, 0.f};
#pragma unroll
        for (int k = 0; k < 8; ++k) {
            bf16x8 bfr[2];
#pragma unroll
            for (int n = 0; n < 2; ++n)
                bfr[n] = *(const bf16x8*)&smem[(size_t)(wc * 32 + n * 16 + l15) * KD
                                               + (((k * 4 + l16) ^ l7) * 8)];
#pragma unroll
            for (int n = 0; n < 2; ++n)
                acc[n] = __builtin_amdgcn_mfma_f32_16x16x32_bf16(qf[k], bfr[n], acc[n], 0, 0, 0);
        }
        const int col0 = t * 64 + wc * 32 + l15;
        const int row0 = bm + wr * 16 + l16 * 4;
#pragma unroll
        for (int n = 0; n < 2; ++n) {
            const int col = col0 + n * 16;
            const bool vld = col < L_TOT;
#pragma unroll
            for (int r = 0; r < 4; ++r) {
                float s = acc[n][r];
                if (vld) mrun[r] = fmaxf(mrun[r], s);
                SR[(size_t)(row0 + r) * L_PAD + col] = vld ? f2h(s) : (u16)0xFC00;
            }
        }
        __syncthreads();
    }

    // ---- reduce row max: butterfly over l15, combine wc halves via LDS ----
#pragma unroll
    for (int r = 0; r < 4; ++r) {
        float mv = mrun[r];
#pragma unroll
        for (int st = 1; st <= 8; st <<= 1)
            mv = fmaxf(mv, __shfl_xor(mv, st));
        mrun[r] = mv;
    }
    if (l15 == 0) {
#pragma unroll
        for (int r = 0; r < 4; ++r)
            sm_m[wc][wr * 16 + l16 * 4 + r] = mrun[r];
    }
    __syncthreads();
    if (wc == 0 && l15 == 0) {
#pragma unroll
        for (int r = 0; r < 4; ++r) {
            int row = wr * 16 + l16 * 4 + r;
            mC[(size_t)(chunk * 4 + b) * HW + bm + row] = fmaxf(sm_m[0][row], sm_m[1][row]);
        }
    }
}

// --------------------------- GEMM2 with fused exp --------------------------
// Zt_z[j][pp] = sum_l VT[j][l] * exp(SR[pp][l] - mC[pp,chunk])
// A-operand (VT) via global_load_lds; B (raw S) reg-staged with exp,
// next tile prefetched before the MFMA phase (T14).
__global__ __launch_bounds__(256) void gemm2_kernel(
    const u16* __restrict__ VT0, const u16* __restrict__ SR0,
    const float* __restrict__ mC, u16* __restrict__ C0) {
    __shared__ u16 As[128 * 64];
    __shared__ u16 Bs[128 * 64];
    const int bx = blockIdx.x, by = blockIdx.y;
    const int within = by % 72, zq = by / 72;
    const int mt = within & 3, nt = within >> 2;
    const int z = bx + 8 * zq;
    const int batch = z >> 2, chunk = z & 3;
    const u16* A = VT0 + (size_t)batch * JD * L_PAD + chunk * (CHUNK_TILES * 64);
    const u16* B = SR0 + (size_t)batch * HW * L_PAD + chunk * (CHUNK_TILES * 64);
    u16* C = C0 + (size_t)z * JD * HW;
    const int bm = mt * 128, bn = nt * 128;
    const int tid = threadIdx.x, lane = tid & 63, wid = tid >> 6;
    const int wr = wid >> 1, wc = wid & 1;
    const int srow = lane >> 3;
    const int scol = (lane & 7) * 8;

    // per-thread B-row maxima (rows constant across tiles)
    float mrow[4];
    {
        const float* mp = mC + (size_t)(chunk * 4 + batch) * HW;
#pragma unroll
        for (int q = 0; q < 4; ++q)
            mrow[q] = mp[bn + wid * 32 + srow + q * 8];
    }

    f32x4 acc[4][4];
#pragma unroll
    for (int i = 0; i < 4; ++i)
#pragma unroll
        for (int j = 0; j < 4; ++j) acc[i][j] = (f32x4){0.f, 0.f, 0.f, 0.f};

    const u16* aG = A + (size_t)(bm + wid * 32 + srow) * L_PAD + scol;
    const u16* bG = B + (size_t)(bn + wid * 32 + srow) * L_PAD + scol;
    u16* aL = As + wid * 32 * 64;

    union U8 { uint4 v; u16 h[8]; };
    uint4 bv[4];
#pragma unroll
    for (int q = 0; q < 4; ++q)
        bv[q] = *(const uint4*)(bG + (size_t)q * 8 * L_PAD);
    bG += 64;

    for (int t = 0; t < CHUNK_TILES; ++t) {
#pragma unroll
        for (int q = 0; q < 4; ++q)
            GLOAD16(aG + (size_t)q * 8 * L_PAD, aL + q * 8 * 64);
        aG += 64;
        uint4 bnext[4];
        if (t < CHUNK_TILES - 1) {
#pragma unroll
            for (int q = 0; q < 4; ++q)
                bnext[q] = *(const uint4*)(bG + (size_t)q * 8 * L_PAD);
            bG += 64;
        }
        // exp-process current B tile -> LDS (bf16)
#pragma unroll
        for (int q = 0; q < 4; ++q) {
            U8 uu; uu.v = bv[q];
            bf16x8 ob;
#pragma unroll
            for (int u = 0; u < 8; ++u) {
                float e = __expf(h2f(uu.h[u]) - mrow[q]);
                ob[u] = (short)f2b(e);
            }
            *(bf16x8*)&Bs[(size_t)(wid * 32 + srow + q * 8) * 64 + scol] = ob;
        }
        __syncthreads();
#pragma unroll
        for (int kc = 0; kc < 64; kc += 32) {
            bf16x8 af[4], bf[4];
#pragma unroll
            for (int m = 0; m < 4; ++m)
                af[m] = *(const bf16x8*)&As[(wr * 64 + m * 16 + (lane & 15)) * 64 + kc + (lane >> 4) * 8];
#pragma unroll
            for (int n = 0; n < 4; ++n)
                bf[n] = *(const bf16x8*)&Bs[(wc * 64 + n * 16 + (lane & 15)) * 64 + kc + (lane >> 4) * 8];
#pragma unroll
            for (int m = 0; m < 4; ++m)
#pragma unroll
                for (int n = 0; n < 4; ++n)
                    acc[m][n] = __builtin_amdgcn_mfma_f32_16x16x32_bf16(af[m], bf[n], acc[m][n], 0, 0, 0);
        }
        __syncthreads();
#pragma unroll
        for (int q = 0; q < 4; ++q) bv[q] = bnext[q];
    }
    const int crow0 = bm + wr * 64 + (lane >> 4) * 4;
    const int ccol = bn + wc * 64 + (lane & 15);
#pragma unroll
    for (int m = 0; m < 4; ++m)
#pragma unroll
        for (int n = 0; n < 4; ++n)
#pragma unroll
            for (int r = 0; r < 4; ++r)
                C[(size_t)(crow0 + m * 16 + r) * HW + ccol + n * 16] = f2b(acc[m][n][r]);
}

// --------------------------- combine chunk stats (after GEMM2) -------------
// d_c comes from the ones-column: Zt[(b*4+c)][450][p]
__global__ void combine_stats(const float* __restrict__ mC, const u16* __restrict__ Zt,
                              float* __restrict__ fac) {
    int idx = blockIdx.x * 256 + threadIdx.x;
    if (idx >= 4 * HW) return;
    int b = idx / HW, p = idx % HW;
    float m[NCHUNK], d[NCHUNK];
#pragma unroll
    for (int c = 0; c < NCHUNK; ++c) {
        m[c] = mC[(size_t)(c * 4 + b) * HW + p];
        d[c] = b2f(Zt[((size_t)(b * 4 + c) * JD + 450) * HW + p]);
    }
    float mf = m[0];
#pragma unroll
    for (int c = 1; c < NCHUNK; ++c) mf = fmaxf(mf, m[c]);
    float w[NCHUNK], df = 0.f;
#pragma unroll
    for (int c = 0; c < NCHUNK; ++c) { w[c] = __expf(m[c] - mf); df += d[c] * w[c]; }
    float inv = 1.0f / df;
#pragma unroll
    for (int c = 0; c < NCHUNK; ++c) fac[(size_t)(c * 4 + b) * HW + p] = w[c] * inv;
}

// --------------------------- chunk reduce (weighted sum over chunks) -------
__global__ void chunk_reduce(const u16* __restrict__ Zt, const float* __restrict__ fac,
                             u16* __restrict__ Zred) {
    int idx = blockIdx.x * 256 + threadIdx.x;
    int total = 4 * JD * HW / 8;
    if (idx >= total) return;
    int e8 = idx * 8;
    int pp = e8 % HW;
    int row = e8 / HW;          // row = b*JD + j
    int b = row / JD;
    float s[8] = {};
#pragma unroll
    for (int ch = 0; ch < NCHUNK; ++ch) {
        const float* fp = fac + (size_t)(ch * 4 + b) * HW + pp;
        bf16x8 zv = *(const bf16x8*)&Zt[((size_t)(b * 4 + ch) * JD + (row % JD)) * HW + pp];
#pragma unroll
        for (int u = 0; u < 8; ++u)
            s[u] += fp[u] * b2f((u16)zv[u]);
    }
    bf16x8 o;
#pragma unroll
    for (int u = 0; u < 8; ++u) o[u] = (short)f2b(s[u]);
    *(bf16x8*)&Zred[(size_t)row * HW + pp] = o;
}

// --------------------------- final: 9-tap gather + residual ----------------
__global__ void final_kernel(const u16* __restrict__ Zred, const float* __restrict__ x,
                             float* __restrict__ out) {
    int idx = blockIdx.x * 256 + threadIdx.x;
    if (idx >= 4 * 50 * HW) return;
    int p = idx % HW;
    int t = idx / HW;
    int c = t % 50;
    int b = t / 50;
    int y = p / 48, xx = p % 48;
    const u16* Zb = Zred + (size_t)b * JD * HW;
    float s = 0.f;
#pragma unroll
    for (int ky = 0; ky < 3; ++ky) {
        int yy = y + ky - 1;
        if (yy < 0 || yy >= 48) continue;
#pragma unroll
        for (int kx = 0; kx < 3; ++kx) {
            int xv = xx + kx - 1;
            if (xv < 0 || xv >= 48) continue;
            int pp = yy * 48 + xv;
            int j = c * 9 + (2 - ky) * 3 + (2 - kx);
            s += b2f(Zb[(size_t)j * HW + pp]);
        }
    }
    size_t o = ((size_t)b * 50 + c) * HW + p;
    out[o] = x[o] + 0.25f * s;
}

// ---------------------------------------------------------------------------
extern "C" void kernel_launch(void* const* d_in, const int* in_sizes, int n_in,
                              void* d_out, int out_size, void* d_ws, size_t ws_size,
                              hipStream_t stream) {
    const float* x       = (const float*)d_in[0];
    const float* w_base  = (const float*)d_in[1];
    const float* b_base  = (const float*)d_in[2];
    const float* a_base  = (const float*)d_in[3];
    const float* w_match = (const float*)d_in[4];
    const float* b_match = (const float*)d_in[5];
    const float* a_match = (const float*)d_in[6];
    const float* w_asm   = (const float*)d_in[7];
    const float* b_asm   = (const float*)d_in[8];
    const float* a_asm   = (const float*)d_in[9];
    float* out = (float*)d_out;
    float* ws = (float*)d_ws;
    (void)in_sizes; (void)n_in; (void)out_size; (void)ws_size;

    // ---- builder scratch (aliases head of SR; dead before attn_score) ----
    size_t off = 0;
    auto alloc = [&](size_t n) { size_t o = off; off += (n + 63) & ~(size_t)63; return o; };
    size_t o_wm = alloc(142 * 48);
    size_t o_dtab = alloc(L_PAD);
    size_t o_t1 = alloc((size_t)200 * 43 * 48);
    size_t o_t2 = alloc((size_t)200 * 38 * 48);
    size_t o_t3 = alloc((size_t)200 * 33 * 48);
    size_t o_t4 = alloc((size_t)200 * 28 * 48);
    size_t o_r1 = alloc((size_t)200 * 43 * 43);
    size_t o_r2 = alloc((size_t)200 * 38 * 38);
    size_t o_r3 = alloc((size_t)200 * 33 * 33);
    size_t o_r4 = alloc((size_t)200 * 28 * 28);
    size_t o_base = alloc((size_t)200 * L_TOT);
    size_t o_refm = alloc((size_t)100 * L_TOT);
    size_t o_mb = alloc((size_t)100 * HW);
    size_t o_norms = alloc((size_t)4 * L_PAD);

    // ---- persistent layout (floats) ----
    size_t o_SR = 0;                                      // fp16 [4][HW][L_PAD]
    size_t o_Q = (size_t)4 * HW * L_PAD / 2;
    size_t o_K = o_Q + (size_t)4 * HW * KD / 2;
    size_t o_VT = o_K + (size_t)4 * L_PAD * KD / 2;
    size_t o_Z = o_VT + (size_t)4 * JD * L_PAD / 2;       // bf16 [16][JD][HW]
    size_t o_mc = o_Z + (size_t)16 * JD * HW / 2;         // f32 [16][HW]
    size_t o_fac = o_mc + (size_t)16 * HW;                // f32 [16][HW]
    size_t o_zred = o_fac + (size_t)16 * HW;              // bf16 [4][JD][HW]

    u16* Qb = (u16*)(ws + o_Q);
    u16* Kb = (u16*)(ws + o_K);
    u16* VTb = (u16*)(ws + o_VT);
    u16* SRb = (u16*)(ws + o_SR);
    u16* Zb = (u16*)(ws + o_Z);
    u16* Zrb = (u16*)(ws + o_zred);
    int* dtab = (int*)(ws + o_dtab);

    // ---- prep ----
    prep_kernel<<<(L_PAD + 255) / 256, 256, 0, stream>>>(ws + o_wm, dtab);
    // ---- resizes ----
    {
        int n = 200 * 48 * (43 + 38 + 33 + 28);
        resize_h_all<<<(n + 255) / 256, 256, 0, stream>>>(x, ws + o_wm, ws + o_t1,
                                                          ws + o_t2, ws + o_t3, ws + o_t4);
    }
    {
        int n = 200 * (43 * 43 + 38 * 38 + 33 * 33 + 28 * 28);
        resize_w_all<<<(n + 255) / 256, 256, 0, stream>>>(ws + o_t1, ws + o_t2, ws + o_t3,
                                                          ws + o_t4, ws + o_wm, ws + o_r1,
                                                          ws + o_r2, ws + o_r3, ws + o_r4);
    }
    // ---- convs ----
    {
        int n = 400 * 2304 + 300 * (1849 + 1444 + 1089 + 784);
        conv_all<<<(n + 255) / 256, 256, 0, stream>>>(
            x, ws + o_r1, ws + o_r2, ws + o_r3, ws + o_r4,
            w_asm, b_asm, a_asm, w_match, b_match, a_match, w_base, b_base, a_base,
            ws + o_base, ws + o_refm, ws + o_mb);
    }
    // ---- operand builders ----
    {
        int n = 4 * HW * 25;
        q_build<<<(n + 255) / 256, 256, 0, stream>>>(ws + o_mb, Qb);
    }
    {
        int n = 4 * L_PAD;
        norms_kernel<<<(n + 255) / 256, 256, 0, stream>>>(ws + o_refm, dtab, ws + o_norms);
    }
    {
        int n = 4 * L_PAD * 25;
        kt_build<<<(n + 255) / 256, 256, 0, stream>>>(ws + o_refm, dtab, ws + o_norms, Kb);
    }
    {
        int n = 4 * JD * (L_PAD / 8);
        v_build<<<(n + 255) / 256, 256, 0, stream>>>(ws + o_base, dtab, VTb);
    }

    // ---- score pass (raw S + chunk max) ----
    {
        dim3 g(8, 144, 1);
        attn_score<<<g, 256, 0, stream>>>(Qb, Kb, SRb, ws + o_mc);
    }
    // ---- GEMM2 with fused exp (denominator via ones column) ----
    {
        dim3 g(8, 144, 1);
        gemm2_kernel<<<g, 256, 0, stream>>>(VTb, SRb, ws + o_mc, Zb);
    }
    combine_stats<<<(4 * HW + 255) / 256, 256, 0, stream>>>(ws + o_mc, Zb, ws + o_fac);
    // ---- weighted chunk reduction ----
    {
        int n = 4 * JD * HW / 8;
        chunk_reduce<<<(n + 255) / 256, 256, 0, stream>>>(Zb, ws + o_fac, Zrb);
    }
    final_kernel<<<(4 * 50 * HW + 255) / 256, 256, 0, stream>>>(Zrb, x, out);
}